// Round 1
// baseline (453.962 us; speedup 1.0000x reference)
//
#include <hip/hip_runtime.h>
#include <stdint.h>

// Problem dims (fixed): S=1024, B=4, E=1024, H=16, D=64, M=S*B=4096
// scaling = D^-0.5 = 0.125

typedef short bf16x8 __attribute__((ext_vector_type(8)));
typedef float f32x4 __attribute__((ext_vector_type(4)));

#define MFMA_BF16(a, b, c) __builtin_amdgcn_mfma_f32_16x16x32_bf16((a), (b), (c), 0, 0, 0)

__device__ __forceinline__ unsigned short f2bf(float x) {
  union { float f; unsigned u; } v; v.f = x;
  unsigned r = v.u + 0x7fffu + ((v.u >> 16) & 1u);  // RNE
  return (unsigned short)(r >> 16);
}
__device__ __forceinline__ float bf2f(unsigned short u) {
  union { unsigned u; float f; } v; v.u = ((unsigned)u) << 16;
  return v.f;
}

// ---------------- conversion kernels ----------------
__global__ __launch_bounds__(256) void cvt_bf16_kernel(const float* __restrict__ src,
                                                       unsigned short* __restrict__ dst, int n) {
  int i = blockIdx.x * 256 + threadIdx.x;
  if (i < n) dst[i] = f2bf(src[i]);
}

__global__ __launch_bounds__(256) void split_bf16_kernel(const float* __restrict__ src,
                                                         unsigned short* __restrict__ hi,
                                                         unsigned short* __restrict__ lo, int n) {
  int i = blockIdx.x * 256 + threadIdx.x;
  if (i < n) {
    float x = src[i];
    unsigned short h = f2bf(x);
    hi[i] = h;
    lo[i] = f2bf(x - bf2f(h));  // residual; exponent range fine in bf16 (no denormal risk)
  }
}

// ---------------- relative-position bias table ----------------
// bucket depends only on delta = j - i in [-1023, 1023]; bias_d[h][delta+1023]
__global__ __launch_bounds__(256) void relbias_kernel(const float* __restrict__ rel_emb,
                                                      float* __restrict__ bias_d) {
  int idx = blockIdx.x * 256 + threadIdx.x;
  if (idx >= 2047) return;
  int rel = idx - 1023;
  int n = rel < 0 ? -rel : rel;
  int ret = rel > 0 ? 16 : 0;
  int bucket;
  if (n < 8) {
    bucket = ret + n;
  } else {
    int large = 8 + (int)(logf((float)n / 8.0f) / logf(16.0f) * 8.0f);
    if (large > 15) large = 15;
    bucket = ret + large;
  }
#pragma unroll
  for (int h = 0; h < 16; ++h)
    bias_d[h * 2048 + idx] = rel_emb[bucket * 16 + h];
}

// ---------------- fused QKV projection GEMM ----------------
// C[m,n] = sum_k A[m,k] * W[n,k]  (B^T GEMM), m = s*4+b, n = e (per matrix)
// 128x128 block tile, BK=32, 4 waves each 64x64 (4x4 of 16x16 MFMA)
__global__ __launch_bounds__(256, 2) void qkv_gemm_kernel(
    const unsigned short* __restrict__ A, const unsigned short* __restrict__ Wq,
    const unsigned short* __restrict__ Wk, const unsigned short* __restrict__ Wv,
    const float* __restrict__ qb, const float* __restrict__ kb, const float* __restrict__ vb,
    unsigned short* __restrict__ qh,   // (B,H,S,D) scaled q
    unsigned short* __restrict__ kh,   // (B,H,S,D)
    unsigned short* __restrict__ vT)   // (B,H,D,S)
{
  __shared__ __align__(16) unsigned short As[128 * 32];
  __shared__ __align__(16) unsigned short Bs[128 * 32];
  const int tid = threadIdx.x, lane = tid & 63;
  const int wv_ = tid >> 6;
  const int nt = blockIdx.x;  // 0..23 (3 matrices x 8 n-tiles)
  const int mt = blockIdx.y;  // 0..31
  const int mat = nt >> 3;
  const unsigned short* W = mat == 0 ? Wq : (mat == 1 ? Wk : Wv);
  const int n0 = (nt & 7) * 128;
  const int m0 = mt * 128;
  const int moff = (wv_ & 1) * 64;
  const int noff = (wv_ >> 1) * 64;

  f32x4 acc[4][4] = {};
  const char* Ab = (const char*)A;
  const char* Wb = (const char*)W;

  for (int kt = 0; kt < 32; ++kt) {
    uint4 areg[2], breg[2];
#pragma unroll
    for (int c = 0; c < 2; ++c) {
      int o = (tid * 2 + c) * 16;  // byte offset in 8KB tile
      int row = o >> 6, colb = o & 63;
      areg[c] = *(const uint4*)(Ab + (size_t)(m0 + row) * 2048 + (size_t)kt * 64 + colb);
      breg[c] = *(const uint4*)(Wb + (size_t)(n0 + row) * 2048 + (size_t)kt * 64 + colb);
    }
    __syncthreads();  // previous iteration's reads done
#pragma unroll
    for (int c = 0; c < 2; ++c) {
      int o = (tid * 2 + c) * 16;
      *(uint4*)((char*)As + o) = areg[c];
      *(uint4*)((char*)Bs + o) = breg[c];
    }
    __syncthreads();
    bf16x8 af[4], bfr[4];
#pragma unroll
    for (int i = 0; i < 4; ++i) {
      af[i] = *(const bf16x8*)&As[(moff + i * 16 + (lane & 15)) * 32 + ((lane >> 4) << 3)];
      bfr[i] = *(const bf16x8*)&Bs[(noff + i * 16 + (lane & 15)) * 32 + ((lane >> 4) << 3)];
    }
#pragma unroll
    for (int i = 0; i < 4; ++i)
#pragma unroll
      for (int j = 0; j < 4; ++j) acc[i][j] = MFMA_BF16(af[i], bfr[j], acc[i][j]);
  }

  // epilogue: bias (+scale for q), scatter into head layouts
  const int r0 = m0 + moff + ((lane >> 4) << 2);
  const int c0 = n0 + noff + (lane & 15);
#pragma unroll
  for (int j = 0; j < 4; ++j) {
    int col = c0 + j * 16;           // e within this matrix
    int hh = col >> 6, dd = col & 63;
    float bias = (mat == 0 ? qb[col] : (mat == 1 ? kb[col] : vb[col]));
#pragma unroll
    for (int i = 0; i < 4; ++i) {
#pragma unroll
      for (int r = 0; r < 4; ++r) {
        int row = r0 + i * 16 + r;   // m = s*4+b
        int s = row >> 2, bidx = row & 3;
        int bh = bidx * 16 + hh;
        float v = acc[i][j][r] + bias;
        if (mat == 0) {
          qh[(size_t)(bh * 1024 + s) * 64 + dd] = f2bf(v * 0.125f);
        } else if (mat == 1) {
          kh[(size_t)(bh * 1024 + s) * 64 + dd] = f2bf(v);
        } else {
          vT[(size_t)(bh * 64 + dd) * 1024 + s] = f2bf(v);
        }
      }
    }
  }
}

// ---------------- gate kernel ----------------
// gate[bh,s] = sig(sum g0..3) * (sig(sum g4..7)*grep_a[h] - 1) + 2,  g = q4 . grep_w^T + grep_b
__global__ __launch_bounds__(256) void gate_kernel(const unsigned short* __restrict__ qh,
                                                   const float* __restrict__ grep_w,
                                                   const float* __restrict__ grep_b,
                                                   const float* __restrict__ grep_a,
                                                   float* __restrict__ gate) {
  __shared__ float gw[512];
  __shared__ float gbb[8];
  __shared__ float gaa[16];
  int tid = threadIdx.x;
  for (int i = tid; i < 512; i += 256) gw[i] = grep_w[i];
  if (tid < 8) gbb[tid] = grep_b[tid];
  if (tid < 16) gaa[tid] = grep_a[tid];
  __syncthreads();
  int idx = blockIdx.x * 256 + tid;  // bh*1024 + s
  int h = (idx >> 10) & 15;
  const unsigned short* q = qh + (size_t)idx * 64;
  float a[8] = {0.f, 0.f, 0.f, 0.f, 0.f, 0.f, 0.f, 0.f};
  for (int d = 0; d < 64; ++d) {
    float qv = bf2f(q[d]);
#pragma unroll
    for (int e = 0; e < 8; ++e) a[e] += qv * gw[e * 64 + d];
  }
  float sa = a[0] + a[1] + a[2] + a[3] + gbb[0] + gbb[1] + gbb[2] + gbb[3];
  float sb = a[4] + a[5] + a[6] + a[7] + gbb[4] + gbb[5] + gbb[6] + gbb[7];
  float siga = 1.f / (1.f + __expf(-sa));
  float sigb = 1.f / (1.f + __expf(-sb));
  gate[idx] = siga * (sigb * gaa[h] - 1.f) + 2.f;
}

// ---------------- flash attention ----------------
// block = (bh, q-tile of 64). 4 waves, wave w owns q rows [s0+w*16, +16).
// K/V staged in LDS 64 keys at a time with XOR swizzle (rows are 128B -> would be
// 16-way bank conflict unswizzled). P goes C-layout -> A-layout via per-wave LDS.
__global__ __launch_bounds__(256, 2) void attn_kernel(
    const unsigned short* __restrict__ qh, const unsigned short* __restrict__ kh,
    const unsigned short* __restrict__ vT, const float* __restrict__ gate,
    const float* __restrict__ bias_d, unsigned short* __restrict__ ctx_hi,
    unsigned short* __restrict__ ctx_lo) {
  __shared__ __align__(16) unsigned short Ks[64 * 64];
  __shared__ __align__(16) unsigned short Vs[64 * 64];
  __shared__ __align__(16) float biasrow[2048];
  __shared__ __align__(16) unsigned short Ps[4 * 512];
  const int tid = threadIdx.x, lane = tid & 63, w = tid >> 6;
  const int bh = blockIdx.x;  // b*16+h
  const int h = bh & 15;
  const int s0 = blockIdx.y * 64;
  const int sqb = s0 + w * 16;

  for (int i = tid; i < 2047; i += 256) biasrow[i] = bias_d[h * 2048 + i];
  if (tid == 0) biasrow[2047] = 0.f;

  // Q fragments for this wave's 16 rows (A-layout: m=lane&15, k=(lane>>4)*8+j)
  const unsigned short* qbase =
      qh + ((size_t)bh * 1024 + sqb + (lane & 15)) * 64 + ((lane >> 4) << 3);
  bf16x8 qf0 = *(const bf16x8*)(qbase);
  bf16x8 qf1 = *(const bf16x8*)(qbase + 32);

  float gate_r[4];
#pragma unroll
  for (int r = 0; r < 4; ++r) gate_r[r] = gate[bh * 1024 + sqb + ((lane >> 4) << 2) + r];

  float m_r[4], l_r[4];
  f32x4 acc_o[4] = {};
#pragma unroll
  for (int r = 0; r < 4; ++r) { m_r[r] = -3.0e38f; l_r[r] = 0.f; }

  const char* kbase = (const char*)(kh + (size_t)bh * 65536);
  const char* vbase = (const char*)(vT + (size_t)bh * 65536);

  for (int kc = 0; kc < 16; ++kc) {
    uint4 kreg[2], vreg[2];
#pragma unroll
    for (int c = 0; c < 2; ++c) {
      int o = c * 4096 + tid * 16;
      int row = o >> 7;           // K: key row; V: d row
      int pch = (o >> 4) & 7;     // physical 16B chunk in row
      int gch = pch ^ (row & 7);  // XOR swizzle: pick swizzled source chunk
      kreg[c] = *(const uint4*)(kbase + (size_t)(kc * 64 + row) * 128 + gch * 16);
      vreg[c] = *(const uint4*)(vbase + (size_t)row * 2048 + (size_t)kc * 128 + gch * 16);
    }
    __syncthreads();
#pragma unroll
    for (int c = 0; c < 2; ++c) {
      int o = c * 4096 + tid * 16;
      *(uint4*)((char*)Ks + o) = kreg[c];
      *(uint4*)((char*)Vs + o) = vreg[c];
    }
    __syncthreads();

#pragma unroll
    for (int sub = 0; sub < 2; ++sub) {
      // ---- S = Q K^T (16 q x 32 keys) ----
      f32x4 sacc[2] = {};
#pragma unroll
      for (int jn = 0; jn < 2; ++jn) {
#pragma unroll
        for (int kk = 0; kk < 2; ++kk) {
          int key = sub * 32 + jn * 16 + (lane & 15);
          int lch = kk * 4 + (lane >> 4);
          bf16x8 bk = *(const bf16x8*)&Ks[key * 64 + ((lch ^ (key & 7)) << 3)];
          sacc[jn] = MFMA_BF16(kk ? qf1 : qf0, bk, sacc[jn]);
        }
      }
      // ---- + gate * pbias, online softmax ----
      int sq0 = sqb + ((lane >> 4) << 2);
      int skey0 = kc * 64 + sub * 32 + (lane & 15);
      float p0[4], p1[4], mx[4];
#pragma unroll
      for (int r = 0; r < 4; ++r) {
        float v0 = sacc[0][r] + gate_r[r] * biasrow[skey0 - (sq0 + r) + 1023];
        float v1 = sacc[1][r] + gate_r[r] * biasrow[skey0 + 16 - (sq0 + r) + 1023];
        p0[r] = v0; p1[r] = v1;
        mx[r] = fmaxf(v0, v1);
      }
#pragma unroll
      for (int r = 0; r < 4; ++r)
#pragma unroll
        for (int off = 1; off < 16; off <<= 1) mx[r] = fmaxf(mx[r], __shfl_xor(mx[r], off, 64));
      float alpha[4], rs[4];
#pragma unroll
      for (int r = 0; r < 4; ++r) {
        float mnew = fmaxf(m_r[r], mx[r]);
        alpha[r] = __expf(m_r[r] - mnew);
        m_r[r] = mnew;
        p0[r] = __expf(p0[r] - mnew);
        p1[r] = __expf(p1[r] - mnew);
        rs[r] = p0[r] + p1[r];
      }
#pragma unroll
      for (int r = 0; r < 4; ++r) {
#pragma unroll
        for (int off = 1; off < 16; off <<= 1) rs[r] += __shfl_xor(rs[r], off, 64);
        l_r[r] = l_r[r] * alpha[r] + rs[r];
      }
#pragma unroll
      for (int nt = 0; nt < 4; ++nt)
#pragma unroll
        for (int r = 0; r < 4; ++r) acc_o[nt][r] *= alpha[r];
      // ---- P: C-layout -> A-layout via per-wave LDS ----
      unsigned short* pw = &Ps[w * 512];
#pragma unroll
      for (int r = 0; r < 4; ++r) {
        int prow = ((lane >> 4) << 2) + r;
        pw[prow * 32 + (lane & 15)] = f2bf(p0[r]);
        pw[prow * 32 + 16 + (lane & 15)] = f2bf(p1[r]);
      }
      __syncthreads();
      bf16x8 pf = *(const bf16x8*)&Ps[w * 512 + (lane & 15) * 32 + ((lane >> 4) << 3)];
      // ---- O += P V ----
#pragma unroll
      for (int nt = 0; nt < 4; ++nt) {
        int d = nt * 16 + (lane & 15);
        int lch = sub * 4 + (lane >> 4);
        bf16x8 bv = *(const bf16x8*)&Vs[d * 64 + ((lch ^ (d & 7)) << 3)];
        acc_o[nt] = MFMA_BF16(pf, bv, acc_o[nt]);
      }
    }
  }

  // epilogue: normalize, hi/lo split, scatter to (S*B, E) layout
#pragma unroll
  for (int r = 0; r < 4; ++r) {
    int s = sqb + ((lane >> 4) << 2) + r;
    float inv = 1.0f / l_r[r];
#pragma unroll
    for (int nt = 0; nt < 4; ++nt) {
      int d = nt * 16 + (lane & 15);
      float v = acc_o[nt][r] * inv;
      unsigned short hi_us = f2bf(v);
      size_t idx = (size_t)(s * 4 + (bh >> 4)) * 1024 + h * 64 + d;
      ctx_hi[idx] = hi_us;
      ctx_lo[idx] = f2bf(v - bf2f(hi_us));
    }
  }
}

// ---------------- output projection, split-bf16 (3 MFMA products) ----------------
__global__ __launch_bounds__(256, 2) void outproj_kernel(
    const unsigned short* __restrict__ Ahi, const unsigned short* __restrict__ Alo,
    const unsigned short* __restrict__ Bhi, const unsigned short* __restrict__ Blo,
    const float* __restrict__ ob, float* __restrict__ out) {
  __shared__ __align__(16) unsigned short Ahs[128 * 32];
  __shared__ __align__(16) unsigned short Als[128 * 32];
  __shared__ __align__(16) unsigned short Bhs[128 * 32];
  __shared__ __align__(16) unsigned short Bls[128 * 32];
  const int tid = threadIdx.x, lane = tid & 63;
  const int wv_ = tid >> 6;
  const int n0 = blockIdx.x * 128;
  const int m0 = blockIdx.y * 128;
  const int moff = (wv_ & 1) * 64;
  const int noff = (wv_ >> 1) * 64;

  f32x4 acc[4][4] = {};
  for (int kt = 0; kt < 32; ++kt) {
    uint4 r0[2], r1[2], r2[2], r3[2];
#pragma unroll
    for (int c = 0; c < 2; ++c) {
      int o = (tid * 2 + c) * 16;
      int row = o >> 6, colb = o & 63;
      size_t ga = (size_t)(m0 + row) * 2048 + (size_t)kt * 64 + colb;
      size_t gb = (size_t)(n0 + row) * 2048 + (size_t)kt * 64 + colb;
      r0[c] = *(const uint4*)((const char*)Ahi + ga);
      r1[c] = *(const uint4*)((const char*)Alo + ga);
      r2[c] = *(const uint4*)((const char*)Bhi + gb);
      r3[c] = *(const uint4*)((const char*)Blo + gb);
    }
    __syncthreads();
#pragma unroll
    for (int c = 0; c < 2; ++c) {
      int o = (tid * 2 + c) * 16;
      *(uint4*)((char*)Ahs + o) = r0[c];
      *(uint4*)((char*)Als + o) = r1[c];
      *(uint4*)((char*)Bhs + o) = r2[c];
      *(uint4*)((char*)Bls + o) = r3[c];
    }
    __syncthreads();
    bf16x8 ah[4], al[4], bhf[4], blf[4];
#pragma unroll
    for (int i = 0; i < 4; ++i) {
      int ra = (moff + i * 16 + (lane & 15)) * 32 + ((lane >> 4) << 3);
      int rb = (noff + i * 16 + (lane & 15)) * 32 + ((lane >> 4) << 3);
      ah[i] = *(const bf16x8*)&Ahs[ra];
      al[i] = *(const bf16x8*)&Als[ra];
      bhf[i] = *(const bf16x8*)&Bhs[rb];
      blf[i] = *(const bf16x8*)&Bls[rb];
    }
#pragma unroll
    for (int i = 0; i < 4; ++i)
#pragma unroll
      for (int j = 0; j < 4; ++j) {
        f32x4 t = MFMA_BF16(al[i], bhf[j], acc[i][j]);
        t = MFMA_BF16(ah[i], blf[j], t);
        acc[i][j] = MFMA_BF16(ah[i], bhf[j], t);
      }
  }
  const int rr0 = m0 + moff + ((lane >> 4) << 2);
  const int c0 = n0 + noff + (lane & 15);
#pragma unroll
  for (int j = 0; j < 4; ++j) {
    int col = c0 + j * 16;
    float bias = ob[col];
#pragma unroll
    for (int i = 0; i < 4; ++i)
#pragma unroll
      for (int r = 0; r < 4; ++r)
        out[(size_t)(rr0 + i * 16 + r) * 1024 + col] = acc[i][j][r] + bias;
  }
}

// ---------------- launcher ----------------
extern "C" void kernel_launch(void* const* d_in, const int* in_sizes, int n_in,
                              void* d_out, int out_size, void* d_ws, size_t ws_size,
                              hipStream_t stream) {
  const float* query = (const float*)d_in[0];
  const float* q_w = (const float*)d_in[1];
  const float* q_b = (const float*)d_in[2];
  const float* k_w = (const float*)d_in[3];
  const float* k_b = (const float*)d_in[4];
  const float* v_w = (const float*)d_in[5];
  const float* v_b = (const float*)d_in[6];
  const float* out_w = (const float*)d_in[7];
  const float* out_b = (const float*)d_in[8];
  const float* rel_emb = (const float*)d_in[9];
  const float* grep_w = (const float*)d_in[10];
  const float* grep_b = (const float*)d_in[11];
  const float* grep_a = (const float*)d_in[12];
  float* out = (float*)d_out;

  const size_t MB = 1u << 20;
  char* ws = (char*)d_ws;
  unsigned short* q_bf = (unsigned short*)(ws);            // (4096,1024) bf16, 8 MB
  unsigned short* wq_bf = (unsigned short*)(ws + 8 * MB);  // 2 MB each
  unsigned short* wk_bf = (unsigned short*)(ws + 10 * MB);
  unsigned short* wv_bf = (unsigned short*)(ws + 12 * MB);
  unsigned short* ow_hi = (unsigned short*)(ws + 14 * MB);
  unsigned short* ow_lo = (unsigned short*)(ws + 16 * MB);
  unsigned short* qhp = (unsigned short*)(ws + 18 * MB);   // (B,H,S,D) 8 MB
  unsigned short* khp = (unsigned short*)(ws + 26 * MB);   // (B,H,S,D) 8 MB
  unsigned short* vTp = (unsigned short*)(ws + 34 * MB);   // (B,H,D,S) 8 MB
  unsigned short* ctxh = (unsigned short*)(ws + 42 * MB);  // (4096,1024) 8 MB
  unsigned short* ctxl = (unsigned short*)(ws + 50 * MB);  // 8 MB
  float* gatep = (float*)(ws + 58 * MB);                   // 256 KB
  float* biasp = (float*)(ws + 58 * MB + 256 * 1024);      // 128 KB

  cvt_bf16_kernel<<<16384, 256, 0, stream>>>(query, q_bf, 4194304);
  cvt_bf16_kernel<<<4096, 256, 0, stream>>>(q_w, wq_bf, 1048576);
  cvt_bf16_kernel<<<4096, 256, 0, stream>>>(k_w, wk_bf, 1048576);
  cvt_bf16_kernel<<<4096, 256, 0, stream>>>(v_w, wv_bf, 1048576);
  split_bf16_kernel<<<4096, 256, 0, stream>>>(out_w, ow_hi, ow_lo, 1048576);
  relbias_kernel<<<8, 256, 0, stream>>>(rel_emb, biasp);
  qkv_gemm_kernel<<<dim3(24, 32), 256, 0, stream>>>(q_bf, wq_bf, wk_bf, wv_bf, q_b, k_b, v_b,
                                                    qhp, khp, vTp);
  gate_kernel<<<256, 256, 0, stream>>>(qhp, grep_w, grep_b, grep_a, gatep);
  attn_kernel<<<dim3(64, 16), 256, 0, stream>>>(qhp, khp, vTp, gatep, biasp, ctxh, ctxl);
  outproj_kernel<<<dim3(8, 32), 256, 0, stream>>>(ctxh, ctxl, ow_hi, ow_lo, out_b, out);
}

// Round 2
// 288.544 us; speedup vs baseline: 1.5733x; 1.5733x over previous
//
#include <hip/hip_runtime.h>
#include <stdint.h>

// Problem dims (fixed): S=1024, B=4, E=1024, H=16, D=64, M=S*B=4096
// scaling = D^-0.5 = 0.125

typedef short bf16x8 __attribute__((ext_vector_type(8)));
typedef float f32x4 __attribute__((ext_vector_type(4)));

#define MFMA_BF16(a, b, c) __builtin_amdgcn_mfma_f32_16x16x32_bf16((a), (b), (c), 0, 0, 0)

__device__ __forceinline__ unsigned short f2bf(float x) {
  union { float f; unsigned u; } v; v.f = x;
  unsigned r = v.u + 0x7fffu + ((v.u >> 16) & 1u);  // RNE
  return (unsigned short)(r >> 16);
}
__device__ __forceinline__ float bf2f(unsigned short u) {
  union { unsigned u; float f; } v; v.u = ((unsigned)u) << 16;
  return v.f;
}

// async global->LDS 16B: lane's data lands at (wave-uniform base) + lane*16;
// we pass base+o where o = uniform + lane*16, matching the HW pattern.
__device__ __forceinline__ void gload_lds16(const void* g, void* l) {
  __builtin_amdgcn_global_load_lds(
      (const __attribute__((address_space(1))) unsigned int*)g,
      (__attribute__((address_space(3))) unsigned int*)l, 16, 0, 0);
}

// LDS chunk swizzle: 4 chunks of 16B per 64B row; spreads 16-row frag reads
// across banks (max 2-way aliasing = free).
__device__ __forceinline__ int swz(int row) { return (row ^ (row >> 2)) & 3; }

// ---------------- conversion kernels ----------------
// query (S,B,E) fp32 -> q_bf (B,S,E) bf16  (deinterleaves batch so GEMM tile
// rows are consecutive s within one b -> coalescible epilogue stores)
__global__ __launch_bounds__(256) void cvtq_kernel(const float* __restrict__ src,
                                                   unsigned short* __restrict__ dst) {
  int i = blockIdx.x * 256 + threadIdx.x;  // 4M
  int e = i & 1023;
  int sb = i >> 10;
  int s = sb >> 2, b = sb & 3;
  dst[((size_t)(b * 1024 + s) << 10) | e] = f2bf(src[i]);
}

// all weight prep in one launch: wq/wk/wv cvt + out_w hi/lo split
__global__ __launch_bounds__(256) void weights_kernel(
    const float* __restrict__ q_w, const float* __restrict__ k_w, const float* __restrict__ v_w,
    const float* __restrict__ out_w, unsigned short* __restrict__ wq,
    unsigned short* __restrict__ wk, unsigned short* __restrict__ wv,
    unsigned short* __restrict__ ohi, unsigned short* __restrict__ olo) {
  int i = blockIdx.x * 256 + threadIdx.x;  // 1M
  wq[i] = f2bf(q_w[i]);
  wk[i] = f2bf(k_w[i]);
  wv[i] = f2bf(v_w[i]);
  float x = out_w[i];
  unsigned short h = f2bf(x);
  ohi[i] = h;
  olo[i] = f2bf(x - bf2f(h));
}

// ---------------- relative-position bias table ----------------
__global__ __launch_bounds__(256) void relbias_kernel(const float* __restrict__ rel_emb,
                                                      float* __restrict__ bias_d) {
  int idx = blockIdx.x * 256 + threadIdx.x;
  if (idx >= 2047) return;
  int rel = idx - 1023;
  int n = rel < 0 ? -rel : rel;
  int ret = rel > 0 ? 16 : 0;
  int bucket;
  if (n < 8) {
    bucket = ret + n;
  } else {
    int large = 8 + (int)(logf((float)n / 8.0f) / logf(16.0f) * 8.0f);
    if (large > 15) large = 15;
    bucket = ret + large;
  }
#pragma unroll
  for (int h = 0; h < 16; ++h)
    bias_d[h * 2048 + idx] = rel_emb[bucket * 16 + h];
}

// ---------------- fused QKV projection GEMM ----------------
// A is (B,S,E) bf16; C[m,n] = sum_k A[m,k]*W[n,k]. 128x128 tile, BK=32,
// global_load_lds staging + source-side XOR swizzle.
__global__ __launch_bounds__(256, 2) void qkv_gemm_kernel(
    const unsigned short* __restrict__ A, const unsigned short* __restrict__ Wq,
    const unsigned short* __restrict__ Wk, const unsigned short* __restrict__ Wv,
    const float* __restrict__ qb, const float* __restrict__ kb, const float* __restrict__ vb,
    unsigned short* __restrict__ qh,   // (B,H,S,D) scaled q
    unsigned short* __restrict__ kh,   // (B,H,S,D)
    unsigned short* __restrict__ vT)   // (B,H,D,S)
{
  __shared__ __align__(16) unsigned short As[128 * 32];
  __shared__ __align__(16) unsigned short Bs[128 * 32];
  const int tid = threadIdx.x, lane = tid & 63;
  const int wv_ = tid >> 6;
  const int nt = blockIdx.x;  // 0..23 (3 matrices x 8 n-tiles)
  const int mt = blockIdx.y;  // 0..31
  const int mat = nt >> 3;
  const unsigned short* W = mat == 0 ? Wq : (mat == 1 ? Wk : Wv);
  const int n0 = (nt & 7) * 128;
  const int m0 = mt * 128;
  const int moff = (wv_ & 1) * 64;
  const int noff = (wv_ >> 1) * 64;

  f32x4 acc[4][4] = {};
  const char* Ab = (const char*)A;
  const char* Wb = (const char*)W;

  // precompute staging geometry (per thread, loop-invariant)
  int st_row[2], st_g[2];
#pragma unroll
  for (int c = 0; c < 2; ++c) {
    int o = c * 4096 + tid * 16;
    int row = o >> 6, p = (o >> 4) & 3;
    st_row[c] = row;
    st_g[c] = p ^ swz(row);
  }

  for (int kt = 0; kt < 32; ++kt) {
    __syncthreads();  // previous tile fully consumed
#pragma unroll
    for (int c = 0; c < 2; ++c) {
      int o = c * 4096 + tid * 16;
      size_t ga = (size_t)(m0 + st_row[c]) * 2048 + (size_t)kt * 64 + st_g[c] * 16;
      size_t gb = (size_t)(n0 + st_row[c]) * 2048 + (size_t)kt * 64 + st_g[c] * 16;
      gload_lds16(Ab + ga, (char*)As + o);
      gload_lds16(Wb + gb, (char*)Bs + o);
    }
    __syncthreads();  // drains vmcnt before barrier

    bf16x8 af[4], bfr[4];
#pragma unroll
    for (int i = 0; i < 4; ++i) {
      int ra = moff + i * 16 + (lane & 15);
      int rb = noff + i * 16 + (lane & 15);
      int q = lane >> 4;
      af[i] = *(const bf16x8*)((const char*)As + ra * 64 + (q ^ swz(ra)) * 16);
      bfr[i] = *(const bf16x8*)((const char*)Bs + rb * 64 + (q ^ swz(rb)) * 16);
    }
#pragma unroll
    for (int i = 0; i < 4; ++i)
#pragma unroll
      for (int j = 0; j < 4; ++j) acc[i][j] = MFMA_BF16(af[i], bfr[j], acc[i][j]);
  }

  // epilogue: rows are consecutive s within one batch -> coalescible stores
  const int bidx = m0 >> 10;
  const int s00 = (m0 & 1023) + moff + ((lane >> 4) << 2);
  const int c0 = n0 + noff + (lane & 15);
  if (mat < 2) {
    const float* barr = mat == 0 ? qb : kb;
    unsigned short* dst = mat == 0 ? qh : kh;
    const float scale = mat == 0 ? 0.125f : 1.0f;
#pragma unroll
    for (int j = 0; j < 4; ++j) {
      int col = c0 + j * 16;
      int hh = col >> 6, dd = col & 63;
      float bias = barr[col];
#pragma unroll
      for (int i = 0; i < 4; ++i)
#pragma unroll
        for (int r = 0; r < 4; ++r) {
          int s = s00 + i * 16 + r;
          dst[((size_t)(bidx * 16 + hh) * 1024 + s) * 64 + dd] =
              f2bf((acc[i][j][r] + bias) * scale);
        }
    }
  } else {
#pragma unroll
    for (int j = 0; j < 4; ++j) {
      int col = c0 + j * 16;
      int hh = col >> 6, dd = col & 63;
      float bias = vb[col];
#pragma unroll
      for (int i = 0; i < 4; ++i) {
        int s = s00 + i * 16;
        ushort4 pk;
        pk.x = f2bf(acc[i][j][0] + bias);
        pk.y = f2bf(acc[i][j][1] + bias);
        pk.z = f2bf(acc[i][j][2] + bias);
        pk.w = f2bf(acc[i][j][3] + bias);
        *(ushort4*)&vT[((size_t)(bidx * 16 + hh) * 64 + dd) * 1024 + s] = pk;
      }
    }
  }
}

// ---------------- gate kernel ----------------
__global__ __launch_bounds__(256) void gate_kernel(const unsigned short* __restrict__ qh,
                                                   const float* __restrict__ grep_w,
                                                   const float* __restrict__ grep_b,
                                                   const float* __restrict__ grep_a,
                                                   float* __restrict__ gate) {
  __shared__ float gw[512];
  __shared__ float gbb[8];
  __shared__ float gaa[16];
  int tid = threadIdx.x;
  for (int i = tid; i < 512; i += 256) gw[i] = grep_w[i];
  if (tid < 8) gbb[tid] = grep_b[tid];
  if (tid < 16) gaa[tid] = grep_a[tid];
  __syncthreads();
  int idx = blockIdx.x * 256 + tid;  // bh*1024 + s
  int h = (idx >> 10) & 15;
  const unsigned short* qrow = qh + (size_t)idx * 64;
  float a[8] = {0.f, 0.f, 0.f, 0.f, 0.f, 0.f, 0.f, 0.f};
#pragma unroll
  for (int c = 0; c < 8; ++c) {
    bf16x8 v = *(const bf16x8*)(qrow + c * 8);
#pragma unroll
    for (int jj = 0; jj < 8; ++jj) {
      float qv = bf2f((unsigned short)v[jj]);
      int d = c * 8 + jj;
#pragma unroll
      for (int e = 0; e < 8; ++e) a[e] += qv * gw[e * 64 + d];
    }
  }
  float sa = a[0] + a[1] + a[2] + a[3] + gbb[0] + gbb[1] + gbb[2] + gbb[3];
  float sb = a[4] + a[5] + a[6] + a[7] + gbb[4] + gbb[5] + gbb[6] + gbb[7];
  float siga = 1.f / (1.f + __expf(-sa));
  float sigb = 1.f / (1.f + __expf(-sb));
  gate[idx] = siga * (sigb * gaa[h] - 1.f) + 2.f;
}

// ---------------- flash attention ----------------
__global__ __launch_bounds__(256, 2) void attn_kernel(
    const unsigned short* __restrict__ qh, const unsigned short* __restrict__ kh,
    const unsigned short* __restrict__ vT, const float* __restrict__ gate,
    const float* __restrict__ bias_d, unsigned short* __restrict__ ctx_hi,
    unsigned short* __restrict__ ctx_lo) {
  __shared__ __align__(16) unsigned short Ks[64 * 64];
  __shared__ __align__(16) unsigned short Vs[64 * 64];
  __shared__ __align__(16) float biasrow[2048];
  __shared__ __align__(16) unsigned short Ps[4 * 512];
  const int tid = threadIdx.x, lane = tid & 63, w = tid >> 6;
  const int bh = blockIdx.x;  // b*16+h
  const int h = bh & 15;
  const int s0 = blockIdx.y * 64;
  const int sqb = s0 + w * 16;

  for (int i = tid; i < 2047; i += 256) biasrow[i] = bias_d[h * 2048 + i];
  if (tid == 0) biasrow[2047] = 0.f;

  const unsigned short* qbase =
      qh + ((size_t)bh * 1024 + sqb + (lane & 15)) * 64 + ((lane >> 4) << 3);
  bf16x8 qf0 = *(const bf16x8*)(qbase);
  bf16x8 qf1 = *(const bf16x8*)(qbase + 32);

  float gate_r[4];
#pragma unroll
  for (int r = 0; r < 4; ++r) gate_r[r] = gate[bh * 1024 + sqb + ((lane >> 4) << 2) + r];

  float m_r[4], l_r[4];
  f32x4 acc_o[4] = {};
#pragma unroll
  for (int r = 0; r < 4; ++r) { m_r[r] = -3.0e38f; l_r[r] = 0.f; }

  const char* kbase = (const char*)(kh + (size_t)bh * 65536);
  const char* vbase = (const char*)(vT + (size_t)bh * 65536);

  for (int kc = 0; kc < 16; ++kc) {
    uint4 kreg[2], vreg[2];
#pragma unroll
    for (int c = 0; c < 2; ++c) {
      int o = c * 4096 + tid * 16;
      int row = o >> 7;
      int pch = (o >> 4) & 7;
      int gch = pch ^ (row & 7);
      kreg[c] = *(const uint4*)(kbase + (size_t)(kc * 64 + row) * 128 + gch * 16);
      vreg[c] = *(const uint4*)(vbase + (size_t)row * 2048 + (size_t)kc * 128 + gch * 16);
    }
    __syncthreads();
#pragma unroll
    for (int c = 0; c < 2; ++c) {
      int o = c * 4096 + tid * 16;
      *(uint4*)((char*)Ks + o) = kreg[c];
      *(uint4*)((char*)Vs + o) = vreg[c];
    }
    __syncthreads();

#pragma unroll
    for (int sub = 0; sub < 2; ++sub) {
      f32x4 sacc[2] = {};
#pragma unroll
      for (int jn = 0; jn < 2; ++jn) {
#pragma unroll
        for (int kk = 0; kk < 2; ++kk) {
          int key = sub * 32 + jn * 16 + (lane & 15);
          int lch = kk * 4 + (lane >> 4);
          bf16x8 bk = *(const bf16x8*)&Ks[key * 64 + ((lch ^ (key & 7)) << 3)];
          sacc[jn] = MFMA_BF16(kk ? qf1 : qf0, bk, sacc[jn]);
        }
      }
      int sq0 = sqb + ((lane >> 4) << 2);
      int skey0 = kc * 64 + sub * 32 + (lane & 15);
      float p0[4], p1[4], mx[4];
#pragma unroll
      for (int r = 0; r < 4; ++r) {
        float v0 = sacc[0][r] + gate_r[r] * biasrow[skey0 - (sq0 + r) + 1023];
        float v1 = sacc[1][r] + gate_r[r] * biasrow[skey0 + 16 - (sq0 + r) + 1023];
        p0[r] = v0; p1[r] = v1;
        mx[r] = fmaxf(v0, v1);
      }
#pragma unroll
      for (int r = 0; r < 4; ++r)
#pragma unroll
        for (int off = 1; off < 16; off <<= 1) mx[r] = fmaxf(mx[r], __shfl_xor(mx[r], off, 64));
      float alpha[4], rs[4];
#pragma unroll
      for (int r = 0; r < 4; ++r) {
        float mnew = fmaxf(m_r[r], mx[r]);
        alpha[r] = __expf(m_r[r] - mnew);
        m_r[r] = mnew;
        p0[r] = __expf(p0[r] - mnew);
        p1[r] = __expf(p1[r] - mnew);
        rs[r] = p0[r] + p1[r];
      }
#pragma unroll
      for (int r = 0; r < 4; ++r) {
#pragma unroll
        for (int off = 1; off < 16; off <<= 1) rs[r] += __shfl_xor(rs[r], off, 64);
        l_r[r] = l_r[r] * alpha[r] + rs[r];
      }
#pragma unroll
      for (int nt = 0; nt < 4; ++nt)
#pragma unroll
        for (int r = 0; r < 4; ++r) acc_o[nt][r] *= alpha[r];
      unsigned short* pw = &Ps[w * 512];
#pragma unroll
      for (int r = 0; r < 4; ++r) {
        int prow = ((lane >> 4) << 2) + r;
        pw[prow * 32 + (lane & 15)] = f2bf(p0[r]);
        pw[prow * 32 + 16 + (lane & 15)] = f2bf(p1[r]);
      }
      __syncthreads();
      bf16x8 pf = *(const bf16x8*)&Ps[w * 512 + (lane & 15) * 32 + ((lane >> 4) << 3)];
#pragma unroll
      for (int nt = 0; nt < 4; ++nt) {
        int d = nt * 16 + (lane & 15);
        int lch = sub * 4 + (lane >> 4);
        bf16x8 bv = *(const bf16x8*)&Vs[d * 64 + ((lch ^ (d & 7)) << 3)];
        acc_o[nt] = MFMA_BF16(pf, bv, acc_o[nt]);
      }
    }
  }

#pragma unroll
  for (int r = 0; r < 4; ++r) {
    int s = sqb + ((lane >> 4) << 2) + r;
    float inv = 1.0f / l_r[r];
#pragma unroll
    for (int nt = 0; nt < 4; ++nt) {
      int d = nt * 16 + (lane & 15);
      float v = acc_o[nt][r] * inv;
      unsigned short hi_us = f2bf(v);
      size_t idx = (size_t)(s * 4 + (bh >> 4)) * 1024 + h * 64 + d;
      ctx_hi[idx] = hi_us;
      ctx_lo[idx] = f2bf(v - bf2f(hi_us));
    }
  }
}

// ---------------- output projection, split-bf16 (3 MFMA products) ----------------
__global__ __launch_bounds__(256, 2) void outproj_kernel(
    const unsigned short* __restrict__ Ahi, const unsigned short* __restrict__ Alo,
    const unsigned short* __restrict__ Bhi, const unsigned short* __restrict__ Blo,
    const float* __restrict__ ob, float* __restrict__ out) {
  __shared__ __align__(16) unsigned short Ahs[128 * 32];
  __shared__ __align__(16) unsigned short Als[128 * 32];
  __shared__ __align__(16) unsigned short Bhs[128 * 32];
  __shared__ __align__(16) unsigned short Bls[128 * 32];
  const int tid = threadIdx.x, lane = tid & 63;
  const int wv_ = tid >> 6;
  const int n0 = blockIdx.x * 128;
  const int m0 = blockIdx.y * 128;
  const int moff = (wv_ & 1) * 64;
  const int noff = (wv_ >> 1) * 64;

  int st_row[2], st_g[2];
#pragma unroll
  for (int c = 0; c < 2; ++c) {
    int o = c * 4096 + tid * 16;
    int row = o >> 6, p = (o >> 4) & 3;
    st_row[c] = row;
    st_g[c] = p ^ swz(row);
  }

  f32x4 acc[4][4] = {};
  for (int kt = 0; kt < 32; ++kt) {
    __syncthreads();
#pragma unroll
    for (int c = 0; c < 2; ++c) {
      int o = c * 4096 + tid * 16;
      size_t ga = (size_t)(m0 + st_row[c]) * 2048 + (size_t)kt * 64 + st_g[c] * 16;
      size_t gb = (size_t)(n0 + st_row[c]) * 2048 + (size_t)kt * 64 + st_g[c] * 16;
      gload_lds16((const char*)Ahi + ga, (char*)Ahs + o);
      gload_lds16((const char*)Alo + ga, (char*)Als + o);
      gload_lds16((const char*)Bhi + gb, (char*)Bhs + o);
      gload_lds16((const char*)Blo + gb, (char*)Bls + o);
    }
    __syncthreads();

    bf16x8 ah[4], al[4], bhf[4], blf[4];
#pragma unroll
    for (int i = 0; i < 4; ++i) {
      int ra = moff + i * 16 + (lane & 15);
      int rb = noff + i * 16 + (lane & 15);
      int q = lane >> 4;
      int pa = (q ^ swz(ra)) * 16, pb = (q ^ swz(rb)) * 16;
      ah[i] = *(const bf16x8*)((const char*)Ahs + ra * 64 + pa);
      al[i] = *(const bf16x8*)((const char*)Als + ra * 64 + pa);
      bhf[i] = *(const bf16x8*)((const char*)Bhs + rb * 64 + pb);
      blf[i] = *(const bf16x8*)((const char*)Bls + rb * 64 + pb);
    }
#pragma unroll
    for (int i = 0; i < 4; ++i)
#pragma unroll
      for (int j = 0; j < 4; ++j) {
        f32x4 t = MFMA_BF16(al[i], bhf[j], acc[i][j]);
        t = MFMA_BF16(ah[i], blf[j], t);
        acc[i][j] = MFMA_BF16(ah[i], bhf[j], t);
      }
  }
  const int rr0 = m0 + moff + ((lane >> 4) << 2);
  const int c0 = n0 + noff + (lane & 15);
#pragma unroll
  for (int j = 0; j < 4; ++j) {
    int col = c0 + j * 16;
    float bias = ob[col];
#pragma unroll
    for (int i = 0; i < 4; ++i)
#pragma unroll
      for (int r = 0; r < 4; ++r)
        out[(size_t)(rr0 + i * 16 + r) * 1024 + col] = acc[i][j][r] + bias;
  }
}

// ---------------- launcher ----------------
extern "C" void kernel_launch(void* const* d_in, const int* in_sizes, int n_in,
                              void* d_out, int out_size, void* d_ws, size_t ws_size,
                              hipStream_t stream) {
  const float* query = (const float*)d_in[0];
  const float* q_w = (const float*)d_in[1];
  const float* q_b = (const float*)d_in[2];
  const float* k_w = (const float*)d_in[3];
  const float* k_b = (const float*)d_in[4];
  const float* v_w = (const float*)d_in[5];
  const float* v_b = (const float*)d_in[6];
  const float* out_w = (const float*)d_in[7];
  const float* out_b = (const float*)d_in[8];
  const float* rel_emb = (const float*)d_in[9];
  const float* grep_w = (const float*)d_in[10];
  const float* grep_b = (const float*)d_in[11];
  const float* grep_a = (const float*)d_in[12];
  float* out = (float*)d_out;

  const size_t MB = 1u << 20;
  char* ws = (char*)d_ws;
  unsigned short* q_bf = (unsigned short*)(ws);            // (B,S,E) bf16, 8 MB
  unsigned short* wq_bf = (unsigned short*)(ws + 8 * MB);
  unsigned short* wk_bf = (unsigned short*)(ws + 10 * MB);
  unsigned short* wv_bf = (unsigned short*)(ws + 12 * MB);
  unsigned short* ow_hi = (unsigned short*)(ws + 14 * MB);
  unsigned short* ow_lo = (unsigned short*)(ws + 16 * MB);
  unsigned short* qhp = (unsigned short*)(ws + 18 * MB);   // (B,H,S,D)
  unsigned short* khp = (unsigned short*)(ws + 26 * MB);   // (B,H,S,D)
  unsigned short* vTp = (unsigned short*)(ws + 34 * MB);   // (B,H,D,S)
  unsigned short* ctxh = (unsigned short*)(ws + 42 * MB);  // (S*B, E)
  unsigned short* ctxl = (unsigned short*)(ws + 50 * MB);
  float* gatep = (float*)(ws + 58 * MB);
  float* biasp = (float*)(ws + 58 * MB + 256 * 1024);

  cvtq_kernel<<<16384, 256, 0, stream>>>(query, q_bf);
  weights_kernel<<<4096, 256, 0, stream>>>(q_w, k_w, v_w, out_w, wq_bf, wk_bf, wv_bf, ow_hi,
                                           ow_lo);
  relbias_kernel<<<8, 256, 0, stream>>>(rel_emb, biasp);
  qkv_gemm_kernel<<<dim3(24, 32), 256, 0, stream>>>(q_bf, wq_bf, wk_bf, wv_bf, q_b, k_b, v_b,
                                                    qhp, khp, vTp);
  gate_kernel<<<256, 256, 0, stream>>>(qhp, grep_w, grep_b, grep_a, gatep);
  attn_kernel<<<dim3(64, 16), 256, 0, stream>>>(qhp, khp, vTp, gatep, biasp, ctxh, ctxl);
  outproj_kernel<<<dim3(8, 32), 256, 0, stream>>>(ctxh, ctxl, ow_hi, ow_lo, out_b, out);
}

// Round 3
// 231.054 us; speedup vs baseline: 1.9647x; 1.2488x over previous
//
#include <hip/hip_runtime.h>
#include <stdint.h>

// Problem dims (fixed): S=1024, B=4, E=1024, H=16, D=64, M=S*B=4096
// scaling = D^-0.5 = 0.125

typedef short bf16x8 __attribute__((ext_vector_type(8)));
typedef float f32x4 __attribute__((ext_vector_type(4)));

#define MFMA_BF16(a, b, c) __builtin_amdgcn_mfma_f32_16x16x32_bf16((a), (b), (c), 0, 0, 0)

__device__ __forceinline__ unsigned short f2bf(float x) {
  union { float f; unsigned u; } v; v.f = x;
  unsigned r = v.u + 0x7fffu + ((v.u >> 16) & 1u);  // RNE
  return (unsigned short)(r >> 16);
}
__device__ __forceinline__ float bf2f(unsigned short u) {
  union { unsigned u; float f; } v; v.u = ((unsigned)u) << 16;
  return v.f;
}

// async global->LDS 16B: lane's data lands at (wave-uniform base) + lane*16.
__device__ __forceinline__ void gload_lds16(const void* g, void* l) {
  __builtin_amdgcn_global_load_lds(
      (const __attribute__((address_space(1))) unsigned int*)g,
      (__attribute__((address_space(3))) unsigned int*)l, 16, 0, 0);
}

// LDS chunk swizzle for 64B rows (4 chunks of 16B)
__device__ __forceinline__ int swz(int row) { return (row ^ (row >> 2)) & 3; }

// ---------------- conversion kernels ----------------
// query (S,B,E) fp32 -> q_bf (B,S,E) bf16
__global__ __launch_bounds__(256) void cvtq_kernel(const float* __restrict__ src,
                                                   unsigned short* __restrict__ dst) {
  int i = blockIdx.x * 256 + threadIdx.x;  // 4M
  int e = i & 1023;
  int sb = i >> 10;
  int s = sb >> 2, b = sb & 3;
  dst[((size_t)(b * 1024 + s) << 10) | e] = f2bf(src[i]);
}

__global__ __launch_bounds__(256) void weights_kernel(
    const float* __restrict__ q_w, const float* __restrict__ k_w, const float* __restrict__ v_w,
    const float* __restrict__ out_w, unsigned short* __restrict__ wq,
    unsigned short* __restrict__ wk, unsigned short* __restrict__ wv,
    unsigned short* __restrict__ ohi, unsigned short* __restrict__ olo) {
  int i = blockIdx.x * 256 + threadIdx.x;  // 1M
  wq[i] = f2bf(q_w[i]);
  wk[i] = f2bf(k_w[i]);
  wv[i] = f2bf(v_w[i]);
  float x = out_w[i];
  unsigned short h = f2bf(x);
  ohi[i] = h;
  olo[i] = f2bf(x - bf2f(h));
}

// ---------------- relative-position bias table ----------------
__global__ __launch_bounds__(256) void relbias_kernel(const float* __restrict__ rel_emb,
                                                      float* __restrict__ bias_d) {
  int idx = blockIdx.x * 256 + threadIdx.x;
  if (idx >= 2047) return;
  int rel = idx - 1023;
  int n = rel < 0 ? -rel : rel;
  int ret = rel > 0 ? 16 : 0;
  int bucket;
  if (n < 8) {
    bucket = ret + n;
  } else {
    int large = 8 + (int)(logf((float)n / 8.0f) / logf(16.0f) * 8.0f);
    if (large > 15) large = 15;
    bucket = ret + large;
  }
#pragma unroll
  for (int h = 0; h < 16; ++h)
    bias_d[h * 2048 + idx] = rel_emb[bucket * 16 + h];
}

// ---------------- fused QKV projection GEMM (unchanged from R2) ----------------
__global__ __launch_bounds__(256, 2) void qkv_gemm_kernel(
    const unsigned short* __restrict__ A, const unsigned short* __restrict__ Wq,
    const unsigned short* __restrict__ Wk, const unsigned short* __restrict__ Wv,
    const float* __restrict__ qb, const float* __restrict__ kb, const float* __restrict__ vb,
    unsigned short* __restrict__ qh,   // (B,H,S,D) scaled q
    unsigned short* __restrict__ kh,   // (B,H,S,D)
    unsigned short* __restrict__ vT)   // (B,H,D,S)
{
  __shared__ __align__(16) unsigned short As[128 * 32];
  __shared__ __align__(16) unsigned short Bs[128 * 32];
  const int tid = threadIdx.x, lane = tid & 63;
  const int wv_ = tid >> 6;
  const int nt = blockIdx.x;
  const int mt = blockIdx.y;
  const int mat = nt >> 3;
  const unsigned short* W = mat == 0 ? Wq : (mat == 1 ? Wk : Wv);
  const int n0 = (nt & 7) * 128;
  const int m0 = mt * 128;
  const int moff = (wv_ & 1) * 64;
  const int noff = (wv_ >> 1) * 64;

  f32x4 acc[4][4] = {};
  const char* Ab = (const char*)A;
  const char* Wb = (const char*)W;

  int st_row[2], st_g[2];
#pragma unroll
  for (int c = 0; c < 2; ++c) {
    int o = c * 4096 + tid * 16;
    int row = o >> 6, p = (o >> 4) & 3;
    st_row[c] = row;
    st_g[c] = p ^ swz(row);
  }

  for (int kt = 0; kt < 32; ++kt) {
    __syncthreads();
#pragma unroll
    for (int c = 0; c < 2; ++c) {
      int o = c * 4096 + tid * 16;
      size_t ga = (size_t)(m0 + st_row[c]) * 2048 + (size_t)kt * 64 + st_g[c] * 16;
      size_t gb = (size_t)(n0 + st_row[c]) * 2048 + (size_t)kt * 64 + st_g[c] * 16;
      gload_lds16(Ab + ga, (char*)As + o);
      gload_lds16(Wb + gb, (char*)Bs + o);
    }
    __syncthreads();

    bf16x8 af[4], bfr[4];
#pragma unroll
    for (int i = 0; i < 4; ++i) {
      int ra = moff + i * 16 + (lane & 15);
      int rb = noff + i * 16 + (lane & 15);
      int q = lane >> 4;
      af[i] = *(const bf16x8*)((const char*)As + ra * 64 + (q ^ swz(ra)) * 16);
      bfr[i] = *(const bf16x8*)((const char*)Bs + rb * 64 + (q ^ swz(rb)) * 16);
    }
#pragma unroll
    for (int i = 0; i < 4; ++i)
#pragma unroll
      for (int j = 0; j < 4; ++j) acc[i][j] = MFMA_BF16(af[i], bfr[j], acc[i][j]);
  }

  const int bidx = m0 >> 10;
  const int s00 = (m0 & 1023) + moff + ((lane >> 4) << 2);
  const int c0 = n0 + noff + (lane & 15);
  if (mat < 2) {
    const float* barr = mat == 0 ? qb : kb;
    unsigned short* dst = mat == 0 ? qh : kh;
    const float scale = mat == 0 ? 0.125f : 1.0f;
#pragma unroll
    for (int j = 0; j < 4; ++j) {
      int col = c0 + j * 16;
      int hh = col >> 6, dd = col & 63;
      float bias = barr[col];
#pragma unroll
      for (int i = 0; i < 4; ++i)
#pragma unroll
        for (int r = 0; r < 4; ++r) {
          int s = s00 + i * 16 + r;
          dst[((size_t)(bidx * 16 + hh) * 1024 + s) * 64 + dd] =
              f2bf((acc[i][j][r] + bias) * scale);
        }
    }
  } else {
#pragma unroll
    for (int j = 0; j < 4; ++j) {
      int col = c0 + j * 16;
      int hh = col >> 6, dd = col & 63;
      float bias = vb[col];
#pragma unroll
      for (int i = 0; i < 4; ++i) {
        int s = s00 + i * 16;
        ushort4 pk;
        pk.x = f2bf(acc[i][j][0] + bias);
        pk.y = f2bf(acc[i][j][1] + bias);
        pk.z = f2bf(acc[i][j][2] + bias);
        pk.w = f2bf(acc[i][j][3] + bias);
        *(ushort4*)&vT[((size_t)(bidx * 16 + hh) * 64 + dd) * 1024 + s] = pk;
      }
    }
  }
}

// ---------------- gate kernel ----------------
__global__ __launch_bounds__(256) void gate_kernel(const unsigned short* __restrict__ qh,
                                                   const float* __restrict__ grep_w,
                                                   const float* __restrict__ grep_b,
                                                   const float* __restrict__ grep_a,
                                                   float* __restrict__ gate) {
  __shared__ float gw[512];
  __shared__ float gbb[8];
  __shared__ float gaa[16];
  int tid = threadIdx.x;
  for (int i = tid; i < 512; i += 256) gw[i] = grep_w[i];
  if (tid < 8) gbb[tid] = grep_b[tid];
  if (tid < 16) gaa[tid] = grep_a[tid];
  __syncthreads();
  int idx = blockIdx.x * 256 + tid;  // bh*1024 + s
  int h = (idx >> 10) & 15;
  const unsigned short* qrow = qh + (size_t)idx * 64;
  float a[8] = {0.f, 0.f, 0.f, 0.f, 0.f, 0.f, 0.f, 0.f};
#pragma unroll
  for (int c = 0; c < 8; ++c) {
    bf16x8 v = *(const bf16x8*)(qrow + c * 8);
#pragma unroll
    for (int jj = 0; jj < 8; ++jj) {
      float qv = bf2f((unsigned short)v[jj]);
      int d = c * 8 + jj;
#pragma unroll
      for (int e = 0; e < 8; ++e) a[e] += qv * gw[e * 64 + d];
    }
  }
  float sa = a[0] + a[1] + a[2] + a[3] + gbb[0] + gbb[1] + gbb[2] + gbb[3];
  float sb = a[4] + a[5] + a[6] + a[7] + gbb[4] + gbb[5] + gbb[6] + gbb[7];
  float siga = 1.f / (1.f + __expf(-sa));
  float sigb = 1.f / (1.f + __expf(-sb));
  gate[idx] = siga * (sigb * gaa[h] - 1.f) + 2.f;
}

// ---------------- flash attention (transposed-S design) ----------------
// S^T = K Q^T: C-layout col = q (lane&15), row = key (quad*4+reg). Softmax is
// in-lane over 16 keys + 2 cross-quad shuffles; alpha/m/l are per-lane scalars.
// P^T is written wave-private to Ps[q][key] (B-operand orientation, no barrier),
// O^T = V^T P^T accumulated in C-layout (col=q,row=d), transposed via LDS at
// the epilogue for dense 16B/lane ctx stores.
__global__ __launch_bounds__(256, 4) void attn_kernel(
    const unsigned short* __restrict__ qh, const unsigned short* __restrict__ kh,
    const unsigned short* __restrict__ vT, const float* __restrict__ gate,
    const float* __restrict__ bias_d, unsigned short* __restrict__ ctx_hi,
    unsigned short* __restrict__ ctx_lo) {
  // LDS map (bytes): Ks [0,8192) Vs [8192,16384) Ps [16384,25600) bias [25600,33792)
  // Epilogue reuses [0,16640) as Ot fp32[64][65].
  __shared__ __align__(16) char smem[33792];
  unsigned short* Ks = (unsigned short*)smem;            // [key][d] chunk-swizzled
  unsigned short* Vs = (unsigned short*)(smem + 8192);   // [d][key] chunk-swizzled
  unsigned short* Ps = (unsigned short*)(smem + 16384);  // per-wave [16 q][72]
  float* biasrow = (float*)(smem + 25600);

  const int tid = threadIdx.x, lane = tid & 63, w = tid >> 6;
  const int bh = blockIdx.x;  // b*16+h
  const int h = bh & 15;
  const int s0 = blockIdx.y * 64;
  const int sqb = s0 + w * 16;
  const int q15 = lane & 15, quad = lane >> 4;

  for (int i = tid; i < 2048; i += 256) biasrow[i] = (i < 2047) ? bias_d[h * 2048 + i] : 0.f;

  // Q fragments: B-operand layout B[k=d][n=q]: n=lane&15 -> q row, k=quad*8+j -> d
  const unsigned short* qbase =
      qh + ((size_t)bh * 1024 + sqb + q15) * 64 + (quad << 3);
  bf16x8 qf0 = *(const bf16x8*)(qbase);
  bf16x8 qf1 = *(const bf16x8*)(qbase + 32);

  const int sq = sqb + q15;                       // this lane's absolute q row
  const float gate_lane = gate[bh * 1024 + sq];   // scalar per lane

  float m_run = -3.0e38f, l_run = 0.f;
  f32x4 acc_o[4] = {};

  const char* kbase = (const char*)(kh + (size_t)bh * 65536);
  const char* vbase = (const char*)(vT + (size_t)bh * 65536);

  unsigned short* pw = Ps + w * 1152 + q15 * 72;  // wave-private P^T rows

  for (int kc = 0; kc < 16; ++kc) {
    __syncthreads();  // previous tile consumed by all waves (also fences biasrow on kc=0)
#pragma unroll
    for (int c = 0; c < 2; ++c) {
      int o = c * 4096 + tid * 16;
      int row = o >> 7;
      int pch = (o >> 4) & 7;
      int gch = pch ^ (row & 7);
      gload_lds16(kbase + (size_t)(kc * 64 + row) * 128 + gch * 16, (char*)Ks + o);
      gload_lds16(vbase + (size_t)row * 2048 + (size_t)kc * 128 + gch * 16, (char*)Vs + o);
    }
    __syncthreads();  // loads landed

    // ---- S^T = K Q^T : 4 key-tiles x 16 q ----
    f32x4 sacc[4] = {};
#pragma unroll
    for (int t = 0; t < 4; ++t) {
#pragma unroll
      for (int dc = 0; dc < 2; ++dc) {
        int key = t * 16 + q15;
        int c16 = dc * 4 + quad;
        bf16x8 ak = *(const bf16x8*)((const char*)Ks + key * 128 + ((c16 ^ (key & 7)) << 4));
        sacc[t] = MFMA_BF16(ak, dc ? qf1 : qf0, sacc[t]);
      }
    }

    // ---- bias + in-lane online softmax ----
    float p[16];
    float pmax = -3.0e38f;
#pragma unroll
    for (int t = 0; t < 4; ++t)
#pragma unroll
      for (int r = 0; r < 4; ++r) {
        int key = kc * 64 + t * 16 + (quad << 2) + r;
        float v = sacc[t][r] + gate_lane * biasrow[key - sq + 1023];
        p[t * 4 + r] = v;
        pmax = fmaxf(pmax, v);
      }
    pmax = fmaxf(pmax, __shfl_xor(pmax, 16, 64));
    pmax = fmaxf(pmax, __shfl_xor(pmax, 32, 64));
    float mnew = fmaxf(m_run, pmax);
    float alpha = __expf(m_run - mnew);
    m_run = mnew;
    float psum = 0.f;
#pragma unroll
    for (int i = 0; i < 16; ++i) {
      p[i] = __expf(p[i] - mnew);
      psum += p[i];
    }
    psum += __shfl_xor(psum, 16, 64);
    psum += __shfl_xor(psum, 32, 64);
    l_run = l_run * alpha + psum;
#pragma unroll
    for (int t = 0; t < 4; ++t)
#pragma unroll
      for (int r = 0; r < 4; ++r) acc_o[t][r] *= alpha;

    // ---- P^T -> Ps[q][key] (wave-private, no barrier) ----
#pragma unroll
    for (int t = 0; t < 4; ++t) {
      ushort4 pk;
      pk.x = f2bf(p[t * 4 + 0]);
      pk.y = f2bf(p[t * 4 + 1]);
      pk.z = f2bf(p[t * 4 + 2]);
      pk.w = f2bf(p[t * 4 + 3]);
      *(ushort4*)(pw + t * 16 + (quad << 2)) = pk;
    }

    // ---- O^T += V^T P^T ----
#pragma unroll
    for (int ch = 0; ch < 2; ++ch) {
      bf16x8 pb = *(const bf16x8*)(pw + ch * 32 + (quad << 3));
#pragma unroll
      for (int t = 0; t < 4; ++t) {
        int d = t * 16 + q15;
        int c16 = ch * 4 + quad;
        bf16x8 av = *(const bf16x8*)((const char*)Vs + d * 128 + ((c16 ^ (d & 7)) << 4));
        acc_o[t] = MFMA_BF16(av, pb, acc_o[t]);
      }
    }
  }

  // ---- epilogue: O^T -> LDS -> dense ctx stores ----
  __syncthreads();  // everyone done with Ks/Vs/Ps
  float* Ot = (float*)smem;  // [64][65]
  {
    float inv = 1.0f / l_run;
    float* ow = Ot + (w * 16 + q15) * 65;
#pragma unroll
    for (int t = 0; t < 4; ++t)
#pragma unroll
      for (int r = 0; r < 4; ++r) ow[t * 16 + (quad << 2) + r] = acc_o[t][r] * inv;
  }
  __syncthreads();
  {
    int row = tid >> 2, dg = tid & 3;  // 64 rows x 4 d-groups of 16
    int s = s0 + row;
    const float* src = Ot + row * 65 + dg * 16;
    unsigned short hibuf[16], lobuf[16];
#pragma unroll
    for (int j = 0; j < 16; ++j) {
      float v = src[j];
      unsigned short hu = f2bf(v);
      hibuf[j] = hu;
      lobuf[j] = f2bf(v - bf2f(hu));
    }
    size_t base = (size_t)(s * 4 + (bh >> 4)) * 1024 + h * 64 + dg * 16;
#pragma unroll
    for (int half = 0; half < 2; ++half) {
      *(uint4*)(ctx_hi + base + half * 8) = *(const uint4*)(hibuf + half * 8);
      *(uint4*)(ctx_lo + base + half * 8) = *(const uint4*)(lobuf + half * 8);
    }
  }
}

// ---------------- output projection, split-bf16 (unchanged from R2) ----------------
__global__ __launch_bounds__(256, 2) void outproj_kernel(
    const unsigned short* __restrict__ Ahi, const unsigned short* __restrict__ Alo,
    const unsigned short* __restrict__ Bhi, const unsigned short* __restrict__ Blo,
    const float* __restrict__ ob, float* __restrict__ out) {
  __shared__ __align__(16) unsigned short Ahs[128 * 32];
  __shared__ __align__(16) unsigned short Als[128 * 32];
  __shared__ __align__(16) unsigned short Bhs[128 * 32];
  __shared__ __align__(16) unsigned short Bls[128 * 32];
  const int tid = threadIdx.x, lane = tid & 63;
  const int wv_ = tid >> 6;
  const int n0 = blockIdx.x * 128;
  const int m0 = blockIdx.y * 128;
  const int moff = (wv_ & 1) * 64;
  const int noff = (wv_ >> 1) * 64;

  int st_row[2], st_g[2];
#pragma unroll
  for (int c = 0; c < 2; ++c) {
    int o = c * 4096 + tid * 16;
    int row = o >> 6, p = (o >> 4) & 3;
    st_row[c] = row;
    st_g[c] = p ^ swz(row);
  }

  f32x4 acc[4][4] = {};
  for (int kt = 0; kt < 32; ++kt) {
    __syncthreads();
#pragma unroll
    for (int c = 0; c < 2; ++c) {
      int o = c * 4096 + tid * 16;
      size_t ga = (size_t)(m0 + st_row[c]) * 2048 + (size_t)kt * 64 + st_g[c] * 16;
      size_t gb = (size_t)(n0 + st_row[c]) * 2048 + (size_t)kt * 64 + st_g[c] * 16;
      gload_lds16((const char*)Ahi + ga, (char*)Ahs + o);
      gload_lds16((const char*)Alo + ga, (char*)Als + o);
      gload_lds16((const char*)Bhi + gb, (char*)Bhs + o);
      gload_lds16((const char*)Blo + gb, (char*)Bls + o);
    }
    __syncthreads();

    bf16x8 ah[4], al[4], bhf[4], blf[4];
#pragma unroll
    for (int i = 0; i < 4; ++i) {
      int ra = moff + i * 16 + (lane & 15);
      int rb = noff + i * 16 + (lane & 15);
      int q = lane >> 4;
      int pa = (q ^ swz(ra)) * 16, pb = (q ^ swz(rb)) * 16;
      ah[i] = *(const bf16x8*)((const char*)Ahs + ra * 64 + pa);
      al[i] = *(const bf16x8*)((const char*)Als + ra * 64 + pa);
      bhf[i] = *(const bf16x8*)((const char*)Bhs + rb * 64 + pb);
      blf[i] = *(const bf16x8*)((const char*)Bls + rb * 64 + pb);
    }
#pragma unroll
    for (int i = 0; i < 4; ++i)
#pragma unroll
      for (int j = 0; j < 4; ++j) {
        f32x4 t = MFMA_BF16(al[i], bhf[j], acc[i][j]);
        t = MFMA_BF16(ah[i], blf[j], t);
        acc[i][j] = MFMA_BF16(ah[i], bhf[j], t);
      }
  }
  const int rr0 = m0 + moff + ((lane >> 4) << 2);
  const int c0 = n0 + noff + (lane & 15);
#pragma unroll
  for (int j = 0; j < 4; ++j) {
    int col = c0 + j * 16;
    float bias = ob[col];
#pragma unroll
    for (int i = 0; i < 4; ++i)
#pragma unroll
      for (int r = 0; r < 4; ++r)
        out[(size_t)(rr0 + i * 16 + r) * 1024 + col] = acc[i][j][r] + bias;
  }
}

// ---------------- launcher ----------------
extern "C" void kernel_launch(void* const* d_in, const int* in_sizes, int n_in,
                              void* d_out, int out_size, void* d_ws, size_t ws_size,
                              hipStream_t stream) {
  const float* query = (const float*)d_in[0];
  const float* q_w = (const float*)d_in[1];
  const float* q_b = (const float*)d_in[2];
  const float* k_w = (const float*)d_in[3];
  const float* k_b = (const float*)d_in[4];
  const float* v_w = (const float*)d_in[5];
  const float* v_b = (const float*)d_in[6];
  const float* out_w = (const float*)d_in[7];
  const float* out_b = (const float*)d_in[8];
  const float* rel_emb = (const float*)d_in[9];
  const float* grep_w = (const float*)d_in[10];
  const float* grep_b = (const float*)d_in[11];
  const float* grep_a = (const float*)d_in[12];
  float* out = (float*)d_out;

  const size_t MB = 1u << 20;
  char* ws = (char*)d_ws;
  unsigned short* q_bf = (unsigned short*)(ws);            // (B,S,E) bf16, 8 MB
  unsigned short* wq_bf = (unsigned short*)(ws + 8 * MB);
  unsigned short* wk_bf = (unsigned short*)(ws + 10 * MB);
  unsigned short* wv_bf = (unsigned short*)(ws + 12 * MB);
  unsigned short* ow_hi = (unsigned short*)(ws + 14 * MB);
  unsigned short* ow_lo = (unsigned short*)(ws + 16 * MB);
  unsigned short* qhp = (unsigned short*)(ws + 18 * MB);   // (B,H,S,D)
  unsigned short* khp = (unsigned short*)(ws + 26 * MB);   // (B,H,S,D)
  unsigned short* vTp = (unsigned short*)(ws + 34 * MB);   // (B,H,D,S)
  unsigned short* ctxh = (unsigned short*)(ws + 42 * MB);  // (S*B, E)
  unsigned short* ctxl = (unsigned short*)(ws + 50 * MB);
  float* gatep = (float*)(ws + 58 * MB);
  float* biasp = (float*)(ws + 58 * MB + 256 * 1024);

  cvtq_kernel<<<16384, 256, 0, stream>>>(query, q_bf);
  weights_kernel<<<4096, 256, 0, stream>>>(q_w, k_w, v_w, out_w, wq_bf, wk_bf, wv_bf, ow_hi,
                                           ow_lo);
  relbias_kernel<<<8, 256, 0, stream>>>(rel_emb, biasp);
  qkv_gemm_kernel<<<dim3(24, 32), 256, 0, stream>>>(q_bf, wq_bf, wk_bf, wv_bf, q_b, k_b, v_b,
                                                    qhp, khp, vTp);
  gate_kernel<<<256, 256, 0, stream>>>(qhp, grep_w, grep_b, grep_a, gatep);
  attn_kernel<<<dim3(64, 16), 256, 0, stream>>>(qhp, khp, vTp, gatep, biasp, ctxh, ctxl);
  outproj_kernel<<<dim3(8, 32), 256, 0, stream>>>(ctxh, ctxl, ow_hi, ow_lo, out_b, out);
}

// Round 4
// 218.563 us; speedup vs baseline: 2.0770x; 1.0572x over previous
//
#include <hip/hip_runtime.h>
#include <stdint.h>

// Problem dims (fixed): S=1024, B=4, E=1024, H=16, D=64, M=S*B=4096
// scaling = D^-0.5 = 0.125; log2e folded into q-scale and bias table so the
// attention softmax uses raw v_exp_f32 (exp2).

typedef short bf16x8 __attribute__((ext_vector_type(8)));
typedef float f32x4 __attribute__((ext_vector_type(4)));

#define MFMA_BF16(a, b, c) __builtin_amdgcn_mfma_f32_16x16x32_bf16((a), (b), (c), 0, 0, 0)

#define LOG2E 1.44269504088896f
#define LN2 0.693147180559945f

__device__ __forceinline__ unsigned short f2bf(float x) {
  union { float f; unsigned u; } v; v.f = x;
  unsigned r = v.u + 0x7fffu + ((v.u >> 16) & 1u);  // RNE
  return (unsigned short)(r >> 16);
}
__device__ __forceinline__ float bf2f(unsigned short u) {
  union { unsigned u; float f; } v; v.u = ((unsigned)u) << 16;
  return v.f;
}

// async global->LDS 16B: lane's data lands at (wave-uniform base) + lane*16.
__device__ __forceinline__ void gload_lds16(const void* g, void* l) {
  __builtin_amdgcn_global_load_lds(
      (const __attribute__((address_space(1))) unsigned int*)g,
      (__attribute__((address_space(3))) unsigned int*)l, 16, 0, 0);
}

// LDS chunk swizzle for 64B rows (4 chunks of 16B)
__device__ __forceinline__ int swz(int row) { return (row ^ (row >> 2)) & 3; }

// ---------------- fused prep: query cvt/transpose + weight prep ----------------
// query (S,B,E) fp32 -> q_bf (B,S,E) bf16; weights cvt + out_w hi/lo split
__global__ __launch_bounds__(256) void prep_kernel(
    const float* __restrict__ query, const float* __restrict__ q_w,
    const float* __restrict__ k_w, const float* __restrict__ v_w,
    const float* __restrict__ out_w, unsigned short* __restrict__ q_bf,
    unsigned short* __restrict__ wq, unsigned short* __restrict__ wk,
    unsigned short* __restrict__ wv, unsigned short* __restrict__ ohi,
    unsigned short* __restrict__ olo) {
  int i = blockIdx.x * 256 + threadIdx.x;
  if (i < 4194304) {
    int e = i & 1023;
    int sb = i >> 10;
    int s = sb >> 2, b = sb & 3;
    q_bf[((size_t)(b * 1024 + s) << 10) | e] = f2bf(query[i]);
  } else {
    int j = i - 4194304;  // < 1M
    wq[j] = f2bf(q_w[j]);
    wk[j] = f2bf(k_w[j]);
    wv[j] = f2bf(v_w[j]);
    float x = out_w[j];
    unsigned short h = f2bf(x);
    ohi[j] = h;
    olo[j] = f2bf(x - bf2f(h));
  }
}

// ---------------- relative-position bias table (pre-multiplied by log2e) ----------------
__global__ __launch_bounds__(256) void relbias_kernel(const float* __restrict__ rel_emb,
                                                      float* __restrict__ bias_d) {
  int idx = blockIdx.x * 256 + threadIdx.x;
  if (idx >= 2048) return;
  if (idx == 2047) {
#pragma unroll
    for (int h = 0; h < 16; ++h) bias_d[h * 2048 + idx] = 0.f;
    return;
  }
  int rel = idx - 1023;
  int n = rel < 0 ? -rel : rel;
  int ret = rel > 0 ? 16 : 0;
  int bucket;
  if (n < 8) {
    bucket = ret + n;
  } else {
    int large = 8 + (int)(logf((float)n / 8.0f) / logf(16.0f) * 8.0f);
    if (large > 15) large = 15;
    bucket = ret + large;
  }
#pragma unroll
  for (int h = 0; h < 16; ++h)
    bias_d[h * 2048 + idx] = rel_emb[bucket * 16 + h] * LOG2E;
}

// ---------------- fused QKV projection GEMM ----------------
// q is scaled by 0.125*log2e (softmax computed in exp2 domain downstream).
__global__ __launch_bounds__(256, 2) void qkv_gemm_kernel(
    const unsigned short* __restrict__ A, const unsigned short* __restrict__ Wq,
    const unsigned short* __restrict__ Wk, const unsigned short* __restrict__ Wv,
    const float* __restrict__ qb, const float* __restrict__ kb, const float* __restrict__ vb,
    unsigned short* __restrict__ qh,   // (B,H,S,D) scaled q
    unsigned short* __restrict__ kh,   // (B,H,S,D)
    unsigned short* __restrict__ vT)   // (B,H,D,S)
{
  __shared__ __align__(16) unsigned short As[128 * 32];
  __shared__ __align__(16) unsigned short Bs[128 * 32];
  const int tid = threadIdx.x, lane = tid & 63;
  const int wv_ = tid >> 6;
  const int nt = blockIdx.x;
  const int mt = blockIdx.y;
  const int mat = nt >> 3;
  const unsigned short* W = mat == 0 ? Wq : (mat == 1 ? Wk : Wv);
  const int n0 = (nt & 7) * 128;
  const int m0 = mt * 128;
  const int moff = (wv_ & 1) * 64;
  const int noff = (wv_ >> 1) * 64;

  f32x4 acc[4][4] = {};
  const char* Ab = (const char*)A;
  const char* Wb = (const char*)W;

  int st_row[2], st_g[2];
#pragma unroll
  for (int c = 0; c < 2; ++c) {
    int o = c * 4096 + tid * 16;
    int row = o >> 6, p = (o >> 4) & 3;
    st_row[c] = row;
    st_g[c] = p ^ swz(row);
  }

  for (int kt = 0; kt < 32; ++kt) {
    __syncthreads();
#pragma unroll
    for (int c = 0; c < 2; ++c) {
      int o = c * 4096 + tid * 16;
      size_t ga = (size_t)(m0 + st_row[c]) * 2048 + (size_t)kt * 64 + st_g[c] * 16;
      size_t gb = (size_t)(n0 + st_row[c]) * 2048 + (size_t)kt * 64 + st_g[c] * 16;
      gload_lds16(Ab + ga, (char*)As + o);
      gload_lds16(Wb + gb, (char*)Bs + o);
    }
    __syncthreads();

    bf16x8 af[4], bfr[4];
#pragma unroll
    for (int i = 0; i < 4; ++i) {
      int ra = moff + i * 16 + (lane & 15);
      int rb = noff + i * 16 + (lane & 15);
      int q = lane >> 4;
      af[i] = *(const bf16x8*)((const char*)As + ra * 64 + (q ^ swz(ra)) * 16);
      bfr[i] = *(const bf16x8*)((const char*)Bs + rb * 64 + (q ^ swz(rb)) * 16);
    }
#pragma unroll
    for (int i = 0; i < 4; ++i)
#pragma unroll
      for (int j = 0; j < 4; ++j) acc[i][j] = MFMA_BF16(af[i], bfr[j], acc[i][j]);
  }

  const int bidx = m0 >> 10;
  const int s00 = (m0 & 1023) + moff + ((lane >> 4) << 2);
  const int c0 = n0 + noff + (lane & 15);
  if (mat < 2) {
    const float* barr = mat == 0 ? qb : kb;
    unsigned short* dst = mat == 0 ? qh : kh;
    const float scale = mat == 0 ? (0.125f * LOG2E) : 1.0f;
#pragma unroll
    for (int j = 0; j < 4; ++j) {
      int col = c0 + j * 16;
      int hh = col >> 6, dd = col & 63;
      float bias = barr[col];
#pragma unroll
      for (int i = 0; i < 4; ++i)
#pragma unroll
        for (int r = 0; r < 4; ++r) {
          int s = s00 + i * 16 + r;
          dst[((size_t)(bidx * 16 + hh) * 1024 + s) * 64 + dd] =
              f2bf((acc[i][j][r] + bias) * scale);
        }
    }
  } else {
#pragma unroll
    for (int j = 0; j < 4; ++j) {
      int col = c0 + j * 16;
      int hh = col >> 6, dd = col & 63;
      float bias = vb[col];
#pragma unroll
      for (int i = 0; i < 4; ++i) {
        int s = s00 + i * 16;
        ushort4 pk;
        pk.x = f2bf(acc[i][j][0] + bias);
        pk.y = f2bf(acc[i][j][1] + bias);
        pk.z = f2bf(acc[i][j][2] + bias);
        pk.w = f2bf(acc[i][j][3] + bias);
        *(ushort4*)&vT[((size_t)(bidx * 16 + hh) * 64 + dd) * 1024 + s] = pk;
      }
    }
  }
}

// ---------------- gate kernel ----------------
// q was rescaled by log2e; compensate the gate dot with *ln2.
__global__ __launch_bounds__(256) void gate_kernel(const unsigned short* __restrict__ qh,
                                                   const float* __restrict__ grep_w,
                                                   const float* __restrict__ grep_b,
                                                   const float* __restrict__ grep_a,
                                                   float* __restrict__ gate) {
  __shared__ float gw[512];
  __shared__ float gbb[8];
  __shared__ float gaa[16];
  int tid = threadIdx.x;
  for (int i = tid; i < 512; i += 256) gw[i] = grep_w[i];
  if (tid < 8) gbb[tid] = grep_b[tid];
  if (tid < 16) gaa[tid] = grep_a[tid];
  __syncthreads();
  int idx = blockIdx.x * 256 + tid;  // bh*1024 + s
  int h = (idx >> 10) & 15;
  const unsigned short* qrow = qh + (size_t)idx * 64;
  float a[8] = {0.f, 0.f, 0.f, 0.f, 0.f, 0.f, 0.f, 0.f};
#pragma unroll
  for (int c = 0; c < 8; ++c) {
    bf16x8 v = *(const bf16x8*)(qrow + c * 8);
#pragma unroll
    for (int jj = 0; jj < 8; ++jj) {
      float qv = bf2f((unsigned short)v[jj]);
      int d = c * 8 + jj;
#pragma unroll
      for (int e = 0; e < 8; ++e) a[e] += qv * gw[e * 64 + d];
    }
  }
  float sa = (a[0] + a[1] + a[2] + a[3]) * LN2 + gbb[0] + gbb[1] + gbb[2] + gbb[3];
  float sb = (a[4] + a[5] + a[6] + a[7]) * LN2 + gbb[4] + gbb[5] + gbb[6] + gbb[7];
  float siga = 1.f / (1.f + __expf(-sa));
  float sigb = 1.f / (1.f + __expf(-sb));
  gate[idx] = siga * (sigb * gaa[h] - 1.f) + 2.f;
}

// ---------------- flash attention: 128-q blocks, dbuf DMA, static softmax ----------------
// Block = 512 threads (8 waves), each wave owns 16 q-rows. S^T = K Q^T gives
// per-lane scores for ONE q (col=q15) x 16 keys; exp2 directly (logits bounded,
// log2e pre-folded), l accumulated per-lane and quad-reduced once at the end.
// K/V double-buffered via global_load_lds: one barrier per 64-key chunk.
__global__ __launch_bounds__(512, 4) void attn_kernel(
    const unsigned short* __restrict__ qh, const unsigned short* __restrict__ kh,
    const unsigned short* __restrict__ vT, const float* __restrict__ gate,
    const float* __restrict__ bias_d, unsigned short* __restrict__ ctx_hi,
    unsigned short* __restrict__ ctx_lo) {
  // LDS: Ks0 [0,8K) Ks1 [8K,16K) Vs0 [16K,24K) Vs1 [24K,32K) Ps [32K,+18432) bias [51200,+8192)
  // Epilogue reuses [0, 33280) as Ot fp32[128][65].
  __shared__ __align__(16) char smem[59392];
  const int tid = threadIdx.x, lane = tid & 63, w = tid >> 6;
  const int bh = blockIdx.x;  // b*16+h
  const int h = bh & 15;
  const int s0 = blockIdx.y * 128;
  const int sqb = s0 + w * 16;
  const int q15 = lane & 15, quad = lane >> 4;

  float* biasrow = (float*)(smem + 51200);
  unsigned short* pw = (unsigned short*)(smem + 32768) + w * 1152 + q15 * 72;

  ((float4*)biasrow)[tid] = ((const float4*)(bias_d + h * 2048))[tid];

  const char* kbase = (const char*)(kh + (size_t)bh * 65536);
  const char* vbase = (const char*)(vT + (size_t)bh * 65536);

  // staging geometry: 512 threads x 16B = one full 8KB tile per instruction
  const int o = tid * 16;
  const int srow = o >> 7;                       // 0..63 (key row / d row)
  const int sg = ((o >> 4) & 7) ^ (srow & 7);    // source chunk (XOR swizzle)
  const size_t koff = (size_t)srow * 128 + sg * 16;
  const size_t voff = (size_t)srow * 2048 + sg * 16;

  // prologue: stage kc=0 into buffer 0
  gload_lds16(kbase + koff, smem + o);
  gload_lds16(vbase + voff, smem + 16384 + o);

  // Q fragments (B-operand layout: n=q15 -> q row, k=quad*8+j -> d)
  const unsigned short* qbase = qh + ((size_t)bh * 1024 + sqb + q15) * 64 + (quad << 3);
  bf16x8 qf0 = *(const bf16x8*)(qbase);
  bf16x8 qf1 = *(const bf16x8*)(qbase + 32);

  const int sq = sqb + q15;
  const float gate_lane = gate[bh * 1024 + sq];

  float l_run = 0.f;
  f32x4 acc_o[4] = {};

  for (int kc = 0; kc < 16; ++kc) {
    __syncthreads();  // cur buffer's DMA landed; prev buffer free for reuse
    const char* Kc = smem + (kc & 1) * 8192;
    const char* Vc = smem + 16384 + (kc & 1) * 8192;
    if (kc < 15) {  // prefetch next chunk into alternate buffer
      int nb = (kc + 1) & 1;
      gload_lds16(kbase + (size_t)(kc + 1) * 8192 + koff, smem + nb * 8192 + o);
      gload_lds16(vbase + (size_t)(kc + 1) * 128 + voff, smem + 16384 + nb * 8192 + o);
    }

    // ---- S^T = K Q^T : 4 key-tiles x 16 q ----
    f32x4 sacc[4] = {};
#pragma unroll
    for (int t = 0; t < 4; ++t) {
      int key = t * 16 + q15;
#pragma unroll
      for (int dc = 0; dc < 2; ++dc) {
        int c16 = dc * 4 + quad;
        bf16x8 ak = *(const bf16x8*)(Kc + key * 128 + ((c16 ^ (key & 7)) << 4));
        sacc[t] = MFMA_BF16(ak, dc ? qf1 : qf0, sacc[t]);
      }
    }

    // ---- bias + static softmax (exp2 domain; no max subtraction needed) ----
    const int boff = kc * 64 - sq + 1023 + (quad << 2);
    float p[16];
    float ps = 0.f;
#pragma unroll
    for (int t = 0; t < 4; ++t)
#pragma unroll
      for (int r = 0; r < 4; ++r) {
        float v = __builtin_fmaf(gate_lane, biasrow[boff + t * 16 + r], sacc[t][r]);
        float e = __builtin_exp2f(v);
        p[t * 4 + r] = e;
        ps += e;
      }
    l_run += ps;

    // ---- P^T -> Ps[q][key] (wave-private, no barrier) ----
#pragma unroll
    for (int t = 0; t < 4; ++t) {
      ushort4 pk;
      pk.x = f2bf(p[t * 4 + 0]);
      pk.y = f2bf(p[t * 4 + 1]);
      pk.z = f2bf(p[t * 4 + 2]);
      pk.w = f2bf(p[t * 4 + 3]);
      *(ushort4*)(pw + t * 16 + (quad << 2)) = pk;
    }

    // ---- O^T += V^T P^T ----
#pragma unroll
    for (int ch = 0; ch < 2; ++ch) {
      bf16x8 pb = *(const bf16x8*)(pw + ch * 32 + (quad << 3));
#pragma unroll
      for (int t = 0; t < 4; ++t) {
        int d = t * 16 + q15;
        int c16 = ch * 4 + quad;
        bf16x8 av = *(const bf16x8*)(Vc + d * 128 + ((c16 ^ (d & 7)) << 4));
        acc_o[t] = MFMA_BF16(av, pb, acc_o[t]);
      }
    }
  }

  // softmax denominator: quad lanes partition the 1024 keys
  l_run += __shfl_xor(l_run, 16, 64);
  l_run += __shfl_xor(l_run, 32, 64);
  const float inv = 1.0f / l_run;

  // ---- epilogue: O^T -> LDS transpose -> dense 16B ctx stores ----
  __syncthreads();
  float* Ot = (float*)smem;  // [128][65]
  {
    float* ow = Ot + (w * 16 + q15) * 65;
#pragma unroll
    for (int t = 0; t < 4; ++t)
#pragma unroll
      for (int r = 0; r < 4; ++r) ow[t * 16 + (quad << 2) + r] = acc_o[t][r] * inv;
  }
  __syncthreads();
  {
    int row = tid >> 2, dg = tid & 3;  // 128 rows x 4 d-groups of 16
    int s = s0 + row;
    const float* src = Ot + row * 65 + dg * 16;
    unsigned short hibuf[16], lobuf[16];
#pragma unroll
    for (int j = 0; j < 16; ++j) {
      float v = src[j];
      unsigned short hu = f2bf(v);
      hibuf[j] = hu;
      lobuf[j] = f2bf(v - bf2f(hu));
    }
    size_t base = (size_t)(s * 4 + (bh >> 4)) * 1024 + h * 64 + dg * 16;
#pragma unroll
    for (int half = 0; half < 2; ++half) {
      *(uint4*)(ctx_hi + base + half * 8) = *(const uint4*)(hibuf + half * 8);
      *(uint4*)(ctx_lo + base + half * 8) = *(const uint4*)(lobuf + half * 8);
    }
  }
}

// ---------------- output projection, split-bf16, 64x128 tiles, dbuf DMA ----------------
__global__ __launch_bounds__(256, 3) void outproj_kernel(
    const unsigned short* __restrict__ Ahi, const unsigned short* __restrict__ Alo,
    const unsigned short* __restrict__ Bhi, const unsigned short* __restrict__ Blo,
    const float* __restrict__ ob, float* __restrict__ out) {
  // per-buffer: Ah 4K, Al 4K, Bh 8K, Bl 8K = 24K; x2 buffers = 48K
  __shared__ __align__(16) char smem[49152];
  const int tid = threadIdx.x, lane = tid & 63, wv_ = tid >> 6;
  const int q15 = lane & 15, quad = lane >> 4;
  const int n0 = blockIdx.x * 128;  // 8 n-tiles
  const int m0 = blockIdx.y * 64;   // 64 m-tiles
  const int moff = (wv_ & 1) * 32;
  const int noff = (wv_ >> 1) * 64;

  // staging geometry: A tile 4KB (1 chunk/thread), B tile 8KB (2 chunks/thread)
  const int oa = tid * 16;
  const int ra_ = oa >> 6;
  const int ga_ = (((oa >> 4) & 3) ^ swz(ra_)) << 4;
  int rb_[2], gb_[2], obo_[2];
#pragma unroll
  for (int c = 0; c < 2; ++c) {
    int ob2 = c * 4096 + tid * 16;
    obo_[c] = ob2;
    rb_[c] = ob2 >> 6;
    gb_[c] = (((ob2 >> 4) & 3) ^ swz(rb_[c])) << 4;
  }

#define OP_STAGE(kt, buf)                                                        \
  {                                                                              \
    char* bb = smem + (buf)*24576;                                               \
    size_t ga = (size_t)(m0 + ra_) * 2048 + (size_t)(kt)*64 + ga_;               \
    gload_lds16((const char*)Ahi + ga, bb + oa);                                 \
    gload_lds16((const char*)Alo + ga, bb + 4096 + oa);                          \
    _Pragma("unroll") for (int c = 0; c < 2; ++c) {                              \
      size_t gb = (size_t)(n0 + rb_[c]) * 2048 + (size_t)(kt)*64 + gb_[c];       \
      gload_lds16((const char*)Bhi + gb, bb + 8192 + obo_[c]);                   \
      gload_lds16((const char*)Blo + gb, bb + 16384 + obo_[c]);                  \
    }                                                                            \
  }

  f32x4 acc[2][4] = {};
  OP_STAGE(0, 0);
  for (int kt = 0; kt < 32; ++kt) {
    __syncthreads();
    const char* base = smem + (kt & 1) * 24576;
    if (kt < 31) OP_STAGE(kt + 1, (kt + 1) & 1);

    bf16x8 ah[2], al[2], bhf[4], blf[4];
#pragma unroll
    for (int i = 0; i < 2; ++i) {
      int ra = moff + i * 16 + q15;
      int pa = (quad ^ swz(ra)) << 4;
      ah[i] = *(const bf16x8*)(base + ra * 64 + pa);
      al[i] = *(const bf16x8*)(base + 4096 + ra * 64 + pa);
    }
#pragma unroll
    for (int j = 0; j < 4; ++j) {
      int rb = noff + j * 16 + q15;
      int pb = (quad ^ swz(rb)) << 4;
      bhf[j] = *(const bf16x8*)(base + 8192 + rb * 64 + pb);
      blf[j] = *(const bf16x8*)(base + 16384 + rb * 64 + pb);
    }
#pragma unroll
    for (int i = 0; i < 2; ++i)
#pragma unroll
      for (int j = 0; j < 4; ++j) {
        f32x4 t = MFMA_BF16(al[i], bhf[j], acc[i][j]);
        t = MFMA_BF16(ah[i], blf[j], t);
        acc[i][j] = MFMA_BF16(ah[i], bhf[j], t);
      }
  }
#undef OP_STAGE

  const int rr0 = m0 + moff + (quad << 2);
  const int c0 = n0 + noff + q15;
#pragma unroll
  for (int j = 0; j < 4; ++j) {
    int col = c0 + j * 16;
    float bias = ob[col];
#pragma unroll
    for (int i = 0; i < 2; ++i)
#pragma unroll
      for (int r = 0; r < 4; ++r)
        out[(size_t)(rr0 + i * 16 + r) * 1024 + col] = acc[i][j][r] + bias;
  }
}

// ---------------- launcher ----------------
extern "C" void kernel_launch(void* const* d_in, const int* in_sizes, int n_in,
                              void* d_out, int out_size, void* d_ws, size_t ws_size,
                              hipStream_t stream) {
  const float* query = (const float*)d_in[0];
  const float* q_w = (const float*)d_in[1];
  const float* q_b = (const float*)d_in[2];
  const float* k_w = (const float*)d_in[3];
  const float* k_b = (const float*)d_in[4];
  const float* v_w = (const float*)d_in[5];
  const float* v_b = (const float*)d_in[6];
  const float* out_w = (const float*)d_in[7];
  const float* out_b = (const float*)d_in[8];
  const float* rel_emb = (const float*)d_in[9];
  const float* grep_w = (const float*)d_in[10];
  const float* grep_b = (const float*)d_in[11];
  const float* grep_a = (const float*)d_in[12];
  float* out = (float*)d_out;

  const size_t MB = 1u << 20;
  char* ws = (char*)d_ws;
  unsigned short* q_bf = (unsigned short*)(ws);            // (B,S,E) bf16, 8 MB
  unsigned short* wq_bf = (unsigned short*)(ws + 8 * MB);
  unsigned short* wk_bf = (unsigned short*)(ws + 10 * MB);
  unsigned short* wv_bf = (unsigned short*)(ws + 12 * MB);
  unsigned short* ow_hi = (unsigned short*)(ws + 14 * MB);
  unsigned short* ow_lo = (unsigned short*)(ws + 16 * MB);
  unsigned short* qhp = (unsigned short*)(ws + 18 * MB);   // (B,H,S,D)
  unsigned short* khp = (unsigned short*)(ws + 26 * MB);   // (B,H,S,D)
  unsigned short* vTp = (unsigned short*)(ws + 34 * MB);   // (B,H,D,S)
  unsigned short* ctxh = (unsigned short*)(ws + 42 * MB);  // (S*B, E)
  unsigned short* ctxl = (unsigned short*)(ws + 50 * MB);
  float* gatep = (float*)(ws + 58 * MB);
  float* biasp = (float*)(ws + 58 * MB + 256 * 1024);

  prep_kernel<<<20480, 256, 0, stream>>>(query, q_w, k_w, v_w, out_w, q_bf, wq_bf, wk_bf,
                                         wv_bf, ow_hi, ow_lo);
  relbias_kernel<<<8, 256, 0, stream>>>(rel_emb, biasp);
  qkv_gemm_kernel<<<dim3(24, 32), 256, 0, stream>>>(q_bf, wq_bf, wk_bf, wv_bf, q_b, k_b, v_b,
                                                    qhp, khp, vTp);
  gate_kernel<<<256, 256, 0, stream>>>(qhp, grep_w, grep_b, grep_a, gatep);
  attn_kernel<<<dim3(64, 8), 512, 0, stream>>>(qhp, khp, vTp, gatep, biasp, ctxh, ctxl);
  outproj_kernel<<<dim3(8, 64), 256, 0, stream>>>(ctxh, ctxl, ow_hi, ow_lo, out_b, out);
}

// Round 5
// 211.441 us; speedup vs baseline: 2.1470x; 1.0337x over previous
//
#include <hip/hip_runtime.h>
#include <stdint.h>

// Problem dims (fixed): S=1024, B=4, E=1024, H=16, D=64, M=S*B=4096
// scaling = D^-0.5 = 0.125; log2e folded into q-scale and bias table so the
// attention softmax uses raw v_exp_f32 (exp2).

typedef short bf16x8 __attribute__((ext_vector_type(8)));
typedef float f32x4 __attribute__((ext_vector_type(4)));

#define MFMA_BF16(a, b, c) __builtin_amdgcn_mfma_f32_16x16x32_bf16((a), (b), (c), 0, 0, 0)

#define LOG2E 1.44269504088896f
#define LN2 0.693147180559945f

__device__ __forceinline__ unsigned short f2bf(float x) {
  union { float f; unsigned u; } v; v.f = x;
  unsigned r = v.u + 0x7fffu + ((v.u >> 16) & 1u);  // RNE
  return (unsigned short)(r >> 16);
}
__device__ __forceinline__ float bf2f(unsigned short u) {
  union { unsigned u; float f; } v; v.u = ((unsigned)u) << 16;
  return v.f;
}

// async global->LDS 16B: lane's data lands at (wave-uniform base) + lane*16.
__device__ __forceinline__ void gload_lds16(const void* g, void* l) {
  __builtin_amdgcn_global_load_lds(
      (const __attribute__((address_space(1))) unsigned int*)g,
      (__attribute__((address_space(3))) unsigned int*)l, 16, 0, 0);
}

// LDS chunk swizzle for 64B rows (4 chunks of 16B)
__device__ __forceinline__ int swz(int row) { return (row ^ (row >> 2)) & 3; }

// ---------------- fused prep: query cvt/transpose + weight prep + relbias ----------------
__global__ __launch_bounds__(256) void prep_kernel(
    const float* __restrict__ query, const float* __restrict__ q_w,
    const float* __restrict__ k_w, const float* __restrict__ v_w,
    const float* __restrict__ out_w, const float* __restrict__ rel_emb,
    unsigned short* __restrict__ q_bf, unsigned short* __restrict__ wq,
    unsigned short* __restrict__ wk, unsigned short* __restrict__ wv,
    unsigned short* __restrict__ ohi, unsigned short* __restrict__ olo,
    float* __restrict__ bias_d) {
  int i = blockIdx.x * 256 + threadIdx.x;
  if (i < 4194304) {
    int e = i & 1023;
    int sb = i >> 10;
    int s = sb >> 2, b = sb & 3;
    q_bf[((size_t)(b * 1024 + s) << 10) | e] = f2bf(query[i]);
  } else if (i < 5242880) {
    int j = i - 4194304;  // < 1M
    wq[j] = f2bf(q_w[j]);
    wk[j] = f2bf(k_w[j]);
    wv[j] = f2bf(v_w[j]);
    float x = out_w[j];
    unsigned short h = f2bf(x);
    ohi[j] = h;
    olo[j] = f2bf(x - bf2f(h));
  } else {
    int idx = i - 5242880;  // < 2048
    if (idx >= 2048) return;
    if (idx == 2047) {
#pragma unroll
      for (int h = 0; h < 16; ++h) bias_d[h * 2048 + idx] = 0.f;
      return;
    }
    int rel = idx - 1023;
    int n = rel < 0 ? -rel : rel;
    int ret = rel > 0 ? 16 : 0;
    int bucket;
    if (n < 8) {
      bucket = ret + n;
    } else {
      int large = 8 + (int)(logf((float)n / 8.0f) / logf(16.0f) * 8.0f);
      if (large > 15) large = 15;
      bucket = ret + large;
    }
#pragma unroll
    for (int h = 0; h < 16; ++h)
      bias_d[h * 2048 + idx] = rel_emb[bucket * 16 + h] * LOG2E;
  }
}

// ---------------- fused QKV projection GEMM (dbuf DMA, 1 barrier/kt) ----------------
__global__ __launch_bounds__(256, 3) void qkv_gemm_kernel(
    const unsigned short* __restrict__ A, const unsigned short* __restrict__ Wq,
    const unsigned short* __restrict__ Wk, const unsigned short* __restrict__ Wv,
    const float* __restrict__ qb, const float* __restrict__ kb, const float* __restrict__ vb,
    unsigned short* __restrict__ qh,   // (B,H,S,D) scaled q
    unsigned short* __restrict__ kh,   // (B,H,S,D)
    unsigned short* __restrict__ vT)   // (B,H,D,S)
{
  // per-buffer: As 8K + Bs 8K; x2
  __shared__ __align__(16) char smem[32768];
  const int tid = threadIdx.x, lane = tid & 63;
  const int wv_ = tid >> 6;
  const int nt = blockIdx.x;
  const int mt = blockIdx.y;
  const int mat = nt >> 3;
  const unsigned short* W = mat == 0 ? Wq : (mat == 1 ? Wk : Wv);
  const int n0 = (nt & 7) * 128;
  const int m0 = mt * 128;
  const int moff = (wv_ & 1) * 64;
  const int noff = (wv_ >> 1) * 64;

  f32x4 acc[4][4] = {};
  const char* Ab = (const char*)A;
  const char* Wb = (const char*)W;

  int st_row[2], st_g[2];
#pragma unroll
  for (int c = 0; c < 2; ++c) {
    int o = c * 4096 + tid * 16;
    int row = o >> 6, p = (o >> 4) & 3;
    st_row[c] = row;
    st_g[c] = p ^ swz(row);
  }

#define QKV_STAGE(kt, buf)                                                     \
  {                                                                            \
    char* bb = smem + (buf)*16384;                                             \
    _Pragma("unroll") for (int c = 0; c < 2; ++c) {                            \
      int o = c * 4096 + tid * 16;                                             \
      size_t ga = (size_t)(m0 + st_row[c]) * 2048 + (size_t)(kt)*64 + st_g[c] * 16; \
      size_t gb = (size_t)(n0 + st_row[c]) * 2048 + (size_t)(kt)*64 + st_g[c] * 16; \
      gload_lds16(Ab + ga, bb + o);                                            \
      gload_lds16(Wb + gb, bb + 8192 + o);                                     \
    }                                                                          \
  }

  QKV_STAGE(0, 0);
  for (int kt = 0; kt < 32; ++kt) {
    __syncthreads();  // current buffer's DMA landed; previous buffer free
    const char* base = smem + (kt & 1) * 16384;
    if (kt < 31) QKV_STAGE(kt + 1, (kt + 1) & 1);

    bf16x8 af[4], bfr[4];
#pragma unroll
    for (int i = 0; i < 4; ++i) {
      int ra = moff + i * 16 + (lane & 15);
      int rb = noff + i * 16 + (lane & 15);
      int q = lane >> 4;
      af[i] = *(const bf16x8*)(base + ra * 64 + (q ^ swz(ra)) * 16);
      bfr[i] = *(const bf16x8*)(base + 8192 + rb * 64 + (q ^ swz(rb)) * 16);
    }
#pragma unroll
    for (int i = 0; i < 4; ++i)
#pragma unroll
      for (int j = 0; j < 4; ++j) acc[i][j] = MFMA_BF16(af[i], bfr[j], acc[i][j]);
  }
#undef QKV_STAGE

  const int bidx = m0 >> 10;
  const int s00 = (m0 & 1023) + moff + ((lane >> 4) << 2);
  const int c0 = n0 + noff + (lane & 15);
  if (mat < 2) {
    const float* barr = mat == 0 ? qb : kb;
    unsigned short* dst = mat == 0 ? qh : kh;
    const float scale = mat == 0 ? (0.125f * LOG2E) : 1.0f;
#pragma unroll
    for (int j = 0; j < 4; ++j) {
      int col = c0 + j * 16;
      int hh = col >> 6, dd = col & 63;
      float bias = barr[col];
#pragma unroll
      for (int i = 0; i < 4; ++i)
#pragma unroll
        for (int r = 0; r < 4; ++r) {
          int s = s00 + i * 16 + r;
          dst[((size_t)(bidx * 16 + hh) * 1024 + s) * 64 + dd] =
              f2bf((acc[i][j][r] + bias) * scale);
        }
    }
  } else {
#pragma unroll
    for (int j = 0; j < 4; ++j) {
      int col = c0 + j * 16;
      int hh = col >> 6, dd = col & 63;
      float bias = vb[col];
#pragma unroll
      for (int i = 0; i < 4; ++i) {
        int s = s00 + i * 16;
        ushort4 pk;
        pk.x = f2bf(acc[i][j][0] + bias);
        pk.y = f2bf(acc[i][j][1] + bias);
        pk.z = f2bf(acc[i][j][2] + bias);
        pk.w = f2bf(acc[i][j][3] + bias);
        *(ushort4*)&vT[((size_t)(bidx * 16 + hh) * 64 + dd) * 1024 + s] = pk;
      }
    }
  }
}

// ---------------- gate kernel ----------------
// q was rescaled by log2e; compensate the gate dot with *ln2.
__global__ __launch_bounds__(256) void gate_kernel(const unsigned short* __restrict__ qh,
                                                   const float* __restrict__ grep_w,
                                                   const float* __restrict__ grep_b,
                                                   const float* __restrict__ grep_a,
                                                   float* __restrict__ gate) {
  __shared__ float gw[512];
  __shared__ float gbb[8];
  __shared__ float gaa[16];
  int tid = threadIdx.x;
  for (int i = tid; i < 512; i += 256) gw[i] = grep_w[i];
  if (tid < 8) gbb[tid] = grep_b[tid];
  if (tid < 16) gaa[tid] = grep_a[tid];
  __syncthreads();
  int idx = blockIdx.x * 256 + tid;  // bh*1024 + s
  int h = (idx >> 10) & 15;
  const unsigned short* qrow = qh + (size_t)idx * 64;
  float a[8] = {0.f, 0.f, 0.f, 0.f, 0.f, 0.f, 0.f, 0.f};
#pragma unroll
  for (int c = 0; c < 8; ++c) {
    bf16x8 v = *(const bf16x8*)(qrow + c * 8);
#pragma unroll
    for (int jj = 0; jj < 8; ++jj) {
      float qv = bf2f((unsigned short)v[jj]);
      int d = c * 8 + jj;
#pragma unroll
      for (int e = 0; e < 8; ++e) a[e] += qv * gw[e * 64 + d];
    }
  }
  float sa = (a[0] + a[1] + a[2] + a[3]) * LN2 + gbb[0] + gbb[1] + gbb[2] + gbb[3];
  float sb = (a[4] + a[5] + a[6] + a[7]) * LN2 + gbb[4] + gbb[5] + gbb[6] + gbb[7];
  float siga = 1.f / (1.f + __expf(-sa));
  float sigb = 1.f / (1.f + __expf(-sb));
  gate[idx] = siga * (sigb * gaa[h] - 1.f) + 2.f;
}

// ---------------- flash attention: 128-q blocks, dbuf DMA, static softmax ----------------
// LDS trimmed to 52.5KB -> 3 blocks/CU: bias as block-local 1152-float window,
// Ps stride 64 with pair-index XOR swizzle (conflict-free per quarter-wave).
__global__ __launch_bounds__(512, 6) void attn_kernel(
    const unsigned short* __restrict__ qh, const unsigned short* __restrict__ kh,
    const unsigned short* __restrict__ vT, const float* __restrict__ gate,
    const float* __restrict__ bias_d, unsigned short* __restrict__ ctx_hi,
    unsigned short* __restrict__ ctx_lo) {
  // map: K dbuf [0,16K) V dbuf [16K,32K) Ps [32K,48K) biasw [49152,53760)
  // epilogue reuses [0,33280) as Ot fp32[128][65]
  __shared__ __align__(16) char smem[53760];
  const int tid = threadIdx.x, lane = tid & 63, w = tid >> 6;
  const int bh = blockIdx.x;  // b*16+h
  const int h = bh & 15;
  const int s0 = blockIdx.y * 128;
  const int sqb = s0 + w * 16;
  const int q15 = lane & 15, quad = lane >> 4, q7 = lane & 7;

  float* biasw = (float*)(smem + 49152);  // window: delta in [-(s0+127), 1023-s0]
  if (tid < 288)
    ((float4*)biasw)[tid] = ((const float4*)(bias_d + h * 2048 + (896 - s0)))[tid];

  const char* kbase = (const char*)(kh + (size_t)bh * 65536);
  const char* vbase = (const char*)(vT + (size_t)bh * 65536);

  // staging geometry: 512 threads x 16B = full 8KB tile per instruction
  const int o = tid * 16;
  const int srow = o >> 7;
  const int sg = ((o >> 4) & 7) ^ (srow & 7);
  const size_t koff = (size_t)srow * 128 + sg * 16;
  const size_t voff = (size_t)srow * 2048 + sg * 16;

  gload_lds16(kbase + koff, smem + o);
  gload_lds16(vbase + voff, smem + 16384 + o);

  // Q fragments (B-operand layout: n=q15 -> q row, k=quad*8+j -> d)
  const unsigned short* qbase = qh + ((size_t)bh * 1024 + sqb + q15) * 64 + (quad << 3);
  bf16x8 qf0 = *(const bf16x8*)(qbase);
  bf16x8 qf1 = *(const bf16x8*)(qbase + 32);

  const int sq = sqb + q15;
  const float gate_lane = gate[bh * 1024 + sq];

  // wave-private P^T row for this lane's q (stride 64 shorts, XOR-swizzled pairs)
  unsigned short* psrow = (unsigned short*)(smem + 32768 + w * 2048) + q15 * 64;

  float l_run = 0.f;
  f32x4 acc_o[4] = {};

  for (int kc = 0; kc < 16; ++kc) {
    __syncthreads();  // current buffer's DMA landed; previous buffer free
    const char* Kc = smem + (kc & 1) * 8192;
    const char* Vc = smem + 16384 + (kc & 1) * 8192;
    if (kc < 15) {
      int nb = (kc + 1) & 1;
      gload_lds16(kbase + (size_t)(kc + 1) * 8192 + koff, smem + nb * 8192 + o);
      gload_lds16(vbase + (size_t)(kc + 1) * 128 + voff, smem + 16384 + nb * 8192 + o);
    }

    // ---- S^T = K Q^T, bias + exp2, pack into Ps (per key-tile t) ----
    const int boff = kc * 64 - sq + s0 + 127 + (quad << 2);
    float ps = 0.f;
#pragma unroll
    for (int t = 0; t < 4; ++t) {
      f32x4 sacc = {};
      int key = t * 16 + q15;
#pragma unroll
      for (int dc = 0; dc < 2; ++dc) {
        int c16 = dc * 4 + quad;
        bf16x8 ak = *(const bf16x8*)(Kc + key * 128 + ((c16 ^ (key & 7)) << 4));
        sacc = MFMA_BF16(ak, dc ? qf1 : qf0, sacc);
      }
      float p0 = __builtin_exp2f(__builtin_fmaf(gate_lane, biasw[boff + t * 16 + 0], sacc[0]));
      float p1 = __builtin_exp2f(__builtin_fmaf(gate_lane, biasw[boff + t * 16 + 1], sacc[1]));
      float p2 = __builtin_exp2f(__builtin_fmaf(gate_lane, biasw[boff + t * 16 + 2], sacc[2]));
      float p3 = __builtin_exp2f(__builtin_fmaf(gate_lane, biasw[boff + t * 16 + 3], sacc[3]));
      ps += (p0 + p1) + (p2 + p3);
      ushort4 pk;
      pk.x = f2bf(p0); pk.y = f2bf(p1); pk.z = f2bf(p2); pk.w = f2bf(p3);
      int c = t * 4 + quad;                 // logical 8B chunk in row
      int pc = (c >> 1) ^ q7;               // XOR-swizzled 16B pair
      *(ushort4*)(psrow + pc * 8 + (c & 1) * 4) = pk;
    }
    l_run += ps;

    // ---- O^T += V^T P^T ----
#pragma unroll
    for (int ch = 0; ch < 2; ++ch) {
      int j = (ch * 4 + quad) ^ q7;
      bf16x8 pb = *(const bf16x8*)(psrow + j * 8);
#pragma unroll
      for (int t = 0; t < 4; ++t) {
        int d = t * 16 + q15;
        int c16 = ch * 4 + quad;
        bf16x8 av = *(const bf16x8*)(Vc + d * 128 + ((c16 ^ (d & 7)) << 4));
        acc_o[t] = MFMA_BF16(av, pb, acc_o[t]);
      }
    }
  }

  // softmax denominator: quad lanes partition the 1024 keys
  l_run += __shfl_xor(l_run, 16, 64);
  l_run += __shfl_xor(l_run, 32, 64);
  const float inv = 1.0f / l_run;

  // ---- epilogue: O^T -> LDS transpose -> dense 16B ctx stores ----
  __syncthreads();
  float* Ot = (float*)smem;  // [128][65]
  {
    float* ow = Ot + (w * 16 + q15) * 65;
#pragma unroll
    for (int t = 0; t < 4; ++t)
#pragma unroll
      for (int r = 0; r < 4; ++r) ow[t * 16 + (quad << 2) + r] = acc_o[t][r] * inv;
  }
  __syncthreads();
  {
    int row = tid >> 2, dg = tid & 3;  // 128 rows x 4 d-groups of 16
    int s = s0 + row;
    const float* src = Ot + row * 65 + dg * 16;
    unsigned short hibuf[16], lobuf[16];
#pragma unroll
    for (int j = 0; j < 16; ++j) {
      float v = src[j];
      unsigned short hu = f2bf(v);
      hibuf[j] = hu;
      lobuf[j] = f2bf(v - bf2f(hu));
    }
    size_t base = (size_t)(s * 4 + (bh >> 4)) * 1024 + h * 64 + dg * 16;
#pragma unroll
    for (int half = 0; half < 2; ++half) {
      *(uint4*)(ctx_hi + base + half * 8) = *(const uint4*)(hibuf + half * 8);
      *(uint4*)(ctx_lo + base + half * 8) = *(const uint4*)(lobuf + half * 8);
    }
  }
}

// ---------------- output projection, split-bf16, 64x128 tiles, dbuf DMA ----------------
__global__ __launch_bounds__(256, 3) void outproj_kernel(
    const unsigned short* __restrict__ Ahi, const unsigned short* __restrict__ Alo,
    const unsigned short* __restrict__ Bhi, const unsigned short* __restrict__ Blo,
    const float* __restrict__ ob, float* __restrict__ out) {
  __shared__ __align__(16) char smem[49152];
  const int tid = threadIdx.x, lane = tid & 63, wv_ = tid >> 6;
  const int q15 = lane & 15, quad = lane >> 4;
  const int n0 = blockIdx.x * 128;
  const int m0 = blockIdx.y * 64;
  const int moff = (wv_ & 1) * 32;
  const int noff = (wv_ >> 1) * 64;

  const int oa = tid * 16;
  const int ra_ = oa >> 6;
  const int ga_ = (((oa >> 4) & 3) ^ swz(ra_)) << 4;
  int rb_[2], gb_[2], obo_[2];
#pragma unroll
  for (int c = 0; c < 2; ++c) {
    int ob2 = c * 4096 + tid * 16;
    obo_[c] = ob2;
    rb_[c] = ob2 >> 6;
    gb_[c] = (((ob2 >> 4) & 3) ^ swz(rb_[c])) << 4;
  }

#define OP_STAGE(kt, buf)                                                        \
  {                                                                              \
    char* bb = smem + (buf)*24576;                                               \
    size_t ga = (size_t)(m0 + ra_) * 2048 + (size_t)(kt)*64 + ga_;               \
    gload_lds16((const char*)Ahi + ga, bb + oa);                                 \
    gload_lds16((const char*)Alo + ga, bb + 4096 + oa);                          \
    _Pragma("unroll") for (int c = 0; c < 2; ++c) {                              \
      size_t gb = (size_t)(n0 + rb_[c]) * 2048 + (size_t)(kt)*64 + gb_[c];       \
      gload_lds16((const char*)Bhi + gb, bb + 8192 + obo_[c]);                   \
      gload_lds16((const char*)Blo + gb, bb + 16384 + obo_[c]);                  \
    }                                                                            \
  }

  f32x4 acc[2][4] = {};
  OP_STAGE(0, 0);
  for (int kt = 0; kt < 32; ++kt) {
    __syncthreads();
    const char* base = smem + (kt & 1) * 24576;
    if (kt < 31) OP_STAGE(kt + 1, (kt + 1) & 1);

    bf16x8 ah[2], al[2], bhf[4], blf[4];
#pragma unroll
    for (int i = 0; i < 2; ++i) {
      int ra = moff + i * 16 + q15;
      int pa = (quad ^ swz(ra)) << 4;
      ah[i] = *(const bf16x8*)(base + ra * 64 + pa);
      al[i] = *(const bf16x8*)(base + 4096 + ra * 64 + pa);
    }
#pragma unroll
    for (int j = 0; j < 4; ++j) {
      int rb = noff + j * 16 + q15;
      int pb = (quad ^ swz(rb)) << 4;
      bhf[j] = *(const bf16x8*)(base + 8192 + rb * 64 + pb);
      blf[j] = *(const bf16x8*)(base + 16384 + rb * 64 + pb);
    }
#pragma unroll
    for (int i = 0; i < 2; ++i)
#pragma unroll
      for (int j = 0; j < 4; ++j) {
        f32x4 t = MFMA_BF16(al[i], bhf[j], acc[i][j]);
        t = MFMA_BF16(ah[i], blf[j], t);
        acc[i][j] = MFMA_BF16(ah[i], bhf[j], t);
      }
  }
#undef OP_STAGE

  const int rr0 = m0 + moff + (quad << 2);
  const int c0 = n0 + noff + q15;
#pragma unroll
  for (int j = 0; j < 4; ++j) {
    int col = c0 + j * 16;
    float bias = ob[col];
#pragma unroll
    for (int i = 0; i < 2; ++i)
#pragma unroll
      for (int r = 0; r < 4; ++r)
        out[(size_t)(rr0 + i * 16 + r) * 1024 + col] = acc[i][j][r] + bias;
  }
}

// ---------------- launcher ----------------
extern "C" void kernel_launch(void* const* d_in, const int* in_sizes, int n_in,
                              void* d_out, int out_size, void* d_ws, size_t ws_size,
                              hipStream_t stream) {
  const float* query = (const float*)d_in[0];
  const float* q_w = (const float*)d_in[1];
  const float* q_b = (const float*)d_in[2];
  const float* k_w = (const float*)d_in[3];
  const float* k_b = (const float*)d_in[4];
  const float* v_w = (const float*)d_in[5];
  const float* v_b = (const float*)d_in[6];
  const float* out_w = (const float*)d_in[7];
  const float* out_b = (const float*)d_in[8];
  const float* rel_emb = (const float*)d_in[9];
  const float* grep_w = (const float*)d_in[10];
  const float* grep_b = (const float*)d_in[11];
  const float* grep_a = (const float*)d_in[12];
  float* out = (float*)d_out;

  const size_t MB = 1u << 20;
  char* ws = (char*)d_ws;
  unsigned short* q_bf = (unsigned short*)(ws);            // (B,S,E) bf16, 8 MB
  unsigned short* wq_bf = (unsigned short*)(ws + 8 * MB);
  unsigned short* wk_bf = (unsigned short*)(ws + 10 * MB);
  unsigned short* wv_bf = (unsigned short*)(ws + 12 * MB);
  unsigned short* ow_hi = (unsigned short*)(ws + 14 * MB);
  unsigned short* ow_lo = (unsigned short*)(ws + 16 * MB);
  unsigned short* qhp = (unsigned short*)(ws + 18 * MB);   // (B,H,S,D)
  unsigned short* khp = (unsigned short*)(ws + 26 * MB);   // (B,H,S,D)
  unsigned short* vTp = (unsigned short*)(ws + 34 * MB);   // (B,H,D,S)
  unsigned short* ctxh = (unsigned short*)(ws + 42 * MB);  // (S*B, E)
  unsigned short* ctxl = (unsigned short*)(ws + 50 * MB);
  float* gatep = (float*)(ws + 58 * MB);
  float* biasp = (float*)(ws + 58 * MB + 256 * 1024);

  prep_kernel<<<20488, 256, 0, stream>>>(query, q_w, k_w, v_w, out_w, rel_emb, q_bf, wq_bf,
                                         wk_bf, wv_bf, ow_hi, ow_lo, biasp);
  qkv_gemm_kernel<<<dim3(24, 32), 256, 0, stream>>>(q_bf, wq_bf, wk_bf, wv_bf, q_b, k_b, v_b,
                                                    qhp, khp, vTp);
  gate_kernel<<<256, 256, 0, stream>>>(qhp, grep_w, grep_b, grep_a, gatep);
  attn_kernel<<<dim3(64, 8), 512, 0, stream>>>(qhp, khp, vTp, gatep, biasp, ctxh, ctxl);
  outproj_kernel<<<dim3(8, 64), 256, 0, stream>>>(ctxh, ctxl, ow_hi, ow_lo, out_b, out);
}

// Round 7
// 206.897 us; speedup vs baseline: 2.1941x; 1.0220x over previous
//
#include <hip/hip_runtime.h>
#include <stdint.h>

// Problem dims (fixed): S=1024, B=4, E=1024, H=16, D=64, M=S*B=4096
// scaling = D^-0.5 = 0.125; log2e folded into q-scale and bias table so the
// attention softmax uses raw exp2.

typedef short bf16x8 __attribute__((ext_vector_type(8)));
typedef _Float16 f16x8 __attribute__((ext_vector_type(8)));
typedef float f32x4 __attribute__((ext_vector_type(4)));
typedef float f32x16 __attribute__((ext_vector_type(16)));

#define MFMA_BF16(a, b, c) __builtin_amdgcn_mfma_f32_16x16x32_bf16((a), (b), (c), 0, 0, 0)
#define MFMA_F16(a, b, c) __builtin_amdgcn_mfma_f32_16x16x32_f16((a), (b), (c), 0, 0, 0)
#define MFMA32_BF16(a, b, c) __builtin_amdgcn_mfma_f32_32x32x16_bf16((a), (b), (c), 0, 0, 0)

#define LOG2E 1.44269504088896f
#define LN2 0.693147180559945f

__device__ __forceinline__ unsigned short f2bf(float x) {
  union { float f; unsigned u; } v; v.f = x;
  unsigned r = v.u + 0x7fffu + ((v.u >> 16) & 1u);  // RNE
  return (unsigned short)(r >> 16);
}
__device__ __forceinline__ float bf2f(unsigned short u) {
  union { unsigned u; float f; } v; v.u = ((unsigned)u) << 16;
  return v.f;
}
__device__ __forceinline__ unsigned short f2h(float x) {  // RNE via v_cvt_f16_f32
  union { _Float16 h; unsigned short u; } v; v.h = (_Float16)x;
  return v.u;
}
__device__ __forceinline__ float u32lo_bf(unsigned u) {
  union { unsigned u; float f; } v; v.u = u << 16;
  return v.f;
}
__device__ __forceinline__ float u32hi_bf(unsigned u) {
  union { unsigned u; float f; } v; v.u = u & 0xffff0000u;
  return v.f;
}

// async global->LDS 16B: lane's data lands at (wave-uniform base) + lane*16.
__device__ __forceinline__ void gload_lds16(const void* g, void* l) {
  __builtin_amdgcn_global_load_lds(
      (const __attribute__((address_space(1))) unsigned int*)g,
      (__attribute__((address_space(3))) unsigned int*)l, 16, 0, 0);
}

// LDS chunk swizzle for 64B rows (4 chunks of 16B)
__device__ __forceinline__ int swz(int row) { return (row ^ (row >> 2)) & 3; }

// ---------------- fused prep: query cvt/transpose + weight prep + relbias ----------------
__global__ __launch_bounds__(256) void prep_kernel(
    const float* __restrict__ query, const float* __restrict__ q_w,
    const float* __restrict__ k_w, const float* __restrict__ v_w,
    const float* __restrict__ out_w, const float* __restrict__ rel_emb,
    unsigned short* __restrict__ q_bf, unsigned short* __restrict__ wq,
    unsigned short* __restrict__ wk, unsigned short* __restrict__ wv,
    unsigned short* __restrict__ ow_h,       // f16 out_w
    unsigned short* __restrict__ bias_hd) {  // bf16, 16 x 2056 (last 9 zero-padded)
  int i = blockIdx.x * 256 + threadIdx.x;
  if (i < 4194304) {
    int e = i & 1023;
    int sb = i >> 10;
    int s = sb >> 2, b = sb & 3;
    q_bf[((size_t)(b * 1024 + s) << 10) | e] = f2bf(query[i]);
  } else if (i < 5242880) {
    int j = i - 4194304;  // < 1M
    wq[j] = f2bf(q_w[j]);
    wk[j] = f2bf(k_w[j]);
    wv[j] = f2bf(v_w[j]);
    ow_h[j] = f2h(out_w[j]);
  } else {
    int idx = i - 5242880;
    if (idx >= 2056) return;
    if (idx >= 2047) {
#pragma unroll
      for (int h = 0; h < 16; ++h) bias_hd[h * 2056 + idx] = 0;
      return;
    }
    int rel = idx - 1023;
    int n = rel < 0 ? -rel : rel;
    int ret = rel > 0 ? 16 : 0;
    int bucket;
    if (n < 8) {
      bucket = ret + n;
    } else {
      int large = 8 + (int)(logf((float)n / 8.0f) / logf(16.0f) * 8.0f);
      if (large > 15) large = 15;
      bucket = ret + large;
    }
#pragma unroll
    for (int h = 0; h < 16; ++h)
      bias_hd[h * 2056 + idx] = f2bf(rel_emb[bucket * 16 + h] * LOG2E);
  }
}

// ---------------- fused QKV projection GEMM (dbuf DMA, 1 barrier/kt) ----------------
__global__ __launch_bounds__(256, 3) void qkv_gemm_kernel(
    const unsigned short* __restrict__ A, const unsigned short* __restrict__ Wq,
    const unsigned short* __restrict__ Wk, const unsigned short* __restrict__ Wv,
    const float* __restrict__ qb, const float* __restrict__ kb, const float* __restrict__ vb,
    unsigned short* __restrict__ qh,   // (B,H,S,D) scaled q
    unsigned short* __restrict__ kh,   // (B,H,S,D)
    unsigned short* __restrict__ vT)   // (B,H,D,S)
{
  __shared__ __align__(16) char smem[32768];
  const int tid = threadIdx.x, lane = tid & 63;
  const int wv_ = tid >> 6;
  const int nt = blockIdx.x;
  const int mt = blockIdx.y;
  const int mat = nt >> 3;
  const unsigned short* W = mat == 0 ? Wq : (mat == 1 ? Wk : Wv);
  const int n0 = (nt & 7) * 128;
  const int m0 = mt * 128;
  const int moff = (wv_ & 1) * 64;
  const int noff = (wv_ >> 1) * 64;

  f32x4 acc[4][4] = {};
  const char* Ab = (const char*)A;
  const char* Wb = (const char*)W;

  int st_row[2], st_g[2];
#pragma unroll
  for (int c = 0; c < 2; ++c) {
    int o = c * 4096 + tid * 16;
    int row = o >> 6, p = (o >> 4) & 3;
    st_row[c] = row;
    st_g[c] = p ^ swz(row);
  }

#define QKV_STAGE(kt, buf)                                                     \
  {                                                                            \
    char* bb = smem + (buf)*16384;                                             \
    _Pragma("unroll") for (int c = 0; c < 2; ++c) {                            \
      int o = c * 4096 + tid * 16;                                             \
      size_t ga = (size_t)(m0 + st_row[c]) * 2048 + (size_t)(kt)*64 + st_g[c] * 16; \
      size_t gb = (size_t)(n0 + st_row[c]) * 2048 + (size_t)(kt)*64 + st_g[c] * 16; \
      gload_lds16(Ab + ga, bb + o);                                            \
      gload_lds16(Wb + gb, bb + 8192 + o);                                     \
    }                                                                          \
  }

  QKV_STAGE(0, 0);
  for (int kt = 0; kt < 32; ++kt) {
    __syncthreads();
    const char* base = smem + (kt & 1) * 16384;
    if (kt < 31) QKV_STAGE(kt + 1, (kt + 1) & 1);

    bf16x8 af[4], bfr[4];
#pragma unroll
    for (int i = 0; i < 4; ++i) {
      int ra = moff + i * 16 + (lane & 15);
      int rb = noff + i * 16 + (lane & 15);
      int q = lane >> 4;
      af[i] = *(const bf16x8*)(base + ra * 64 + (q ^ swz(ra)) * 16);
      bfr[i] = *(const bf16x8*)(base + 8192 + rb * 64 + (q ^ swz(rb)) * 16);
    }
#pragma unroll
    for (int i = 0; i < 4; ++i)
#pragma unroll
      for (int j = 0; j < 4; ++j) acc[i][j] = MFMA_BF16(af[i], bfr[j], acc[i][j]);
  }
#undef QKV_STAGE

  const int bidx = m0 >> 10;
  const int s00 = (m0 & 1023) + moff + ((lane >> 4) << 2);
  const int c0 = n0 + noff + (lane & 15);
  if (mat < 2) {
    const float* barr = mat == 0 ? qb : kb;
    unsigned short* dst = mat == 0 ? qh : kh;
    const float scale = mat == 0 ? (0.125f * LOG2E) : 1.0f;
#pragma unroll
    for (int j = 0; j < 4; ++j) {
      int col = c0 + j * 16;
      int hh = col >> 6, dd = col & 63;
      float bias = barr[col];
#pragma unroll
      for (int i = 0; i < 4; ++i)
#pragma unroll
        for (int r = 0; r < 4; ++r) {
          int s = s00 + i * 16 + r;
          dst[((size_t)(bidx * 16 + hh) * 1024 + s) * 64 + dd] =
              f2bf((acc[i][j][r] + bias) * scale);
        }
    }
  } else {
#pragma unroll
    for (int j = 0; j < 4; ++j) {
      int col = c0 + j * 16;
      int hh = col >> 6, dd = col & 63;
      float bias = vb[col];
#pragma unroll
      for (int i = 0; i < 4; ++i) {
        int s = s00 + i * 16;
        ushort4 pk;
        pk.x = f2bf(acc[i][j][0] + bias);
        pk.y = f2bf(acc[i][j][1] + bias);
        pk.z = f2bf(acc[i][j][2] + bias);
        pk.w = f2bf(acc[i][j][3] + bias);
        *(ushort4*)&vT[((size_t)(bidx * 16 + hh) * 64 + dd) * 1024 + s] = pk;
      }
    }
  }
}

// ---------------- gate kernel ----------------
__global__ __launch_bounds__(256) void gate_kernel(const unsigned short* __restrict__ qh,
                                                   const float* __restrict__ grep_w,
                                                   const float* __restrict__ grep_b,
                                                   const float* __restrict__ grep_a,
                                                   float* __restrict__ gate) {
  __shared__ float gw[512];
  __shared__ float gbb[8];
  __shared__ float gaa[16];
  int tid = threadIdx.x;
  for (int i = tid; i < 512; i += 256) gw[i] = grep_w[i];
  if (tid < 8) gbb[tid] = grep_b[tid];
  if (tid < 16) gaa[tid] = grep_a[tid];
  __syncthreads();
  int idx = blockIdx.x * 256 + tid;  // bh*1024 + s
  int h = (idx >> 10) & 15;
  const unsigned short* qrow = qh + (size_t)idx * 64;
  float a[8] = {0.f, 0.f, 0.f, 0.f, 0.f, 0.f, 0.f, 0.f};
#pragma unroll
  for (int c = 0; c < 8; ++c) {
    bf16x8 v = *(const bf16x8*)(qrow + c * 8);
#pragma unroll
    for (int jj = 0; jj < 8; ++jj) {
      float qv = bf2f((unsigned short)v[jj]);
      int d = c * 8 + jj;
#pragma unroll
      for (int e = 0; e < 8; ++e) a[e] += qv * gw[e * 64 + d];
    }
  }
  float sa = (a[0] + a[1] + a[2] + a[3]) * LN2 + gbb[0] + gbb[1] + gbb[2] + gbb[3];
  float sb = (a[4] + a[5] + a[6] + a[7]) * LN2 + gbb[4] + gbb[5] + gbb[6] + gbb[7];
  float siga = 1.f / (1.f + __expf(-sa));
  float sigb = 1.f / (1.f + __expf(-sb));
  gate[idx] = siga * (sigb * gaa[h] - 1.f) + 2.f;
}

// ---------------- flash attention v3: 32x32 MFMA, wave-q=32, 256 threads ----------------
// S^T = K Q^T on mfma_32x32x16: C col = q (lane&31), rows = keys in pattern
// (reg&3)+8*(reg>>2)+4*(lane>>5). 32 scores/lane for ONE q -> static softmax is
// fully in-lane; l reduced once at end via shfl_xor(32). Bias in bf16 with dual
// parity-shifted LDS copies: each 4-score run = two aligned u32 reads. P^T lives
// in wave-private Ps rows (144B stride, XOR-swizzled 16B chunks) feeding the
// PV B-operand directly. K/V dbuf via global_load_lds, 1 barrier per 64 keys.
__global__ __launch_bounds__(256, 2) void attn_kernel(
    const unsigned short* __restrict__ qh, const unsigned short* __restrict__ kh,
    const unsigned short* __restrict__ vT, const float* __restrict__ gate,
    const unsigned short* __restrict__ bias_hd, unsigned short* __restrict__ ctx) {
  // LDS: K dbuf [0,16K) V dbuf [16K,32K) Ps [32768,51200) bias c0 [51200,+2304) c1 [53504,+2304)
  // epilogue reuses [0,34816) as Ot fp32[128][68]
  __shared__ __align__(16) char smem[55808];
  const int tid = threadIdx.x, lane = tid & 63, w = tid >> 6;
  const int bh = blockIdx.x;  // b*16+h
  const int h = bh & 15;
  const int qs0 = blockIdx.y * 128;
  const int q31 = lane & 31, hb = lane >> 5, q7 = q31 & 7;
  const int sq = qs0 + w * 32 + q31;

  // bias windows: W[i] = bias[h][896-qs0+i] (bf16), copy1 shifted by +1
  unsigned short* bc0 = (unsigned short*)(smem + 51200);
  unsigned short* bc1 = (unsigned short*)(smem + 53504);
  {
    const unsigned short* gb = bias_hd + h * 2056 + (896 - qs0);
    for (int i = tid; i < 1152; i += 256) {
      bc0[i] = gb[i];
      bc1[i] = gb[i + 1];
    }
  }

  const char* kbase = (const char*)(kh + (size_t)bh * 65536);
  const char* vbase = (const char*)(vT + (size_t)bh * 65536);

  // staging: 256 thr x 2 chunks x 16B = 8KB tile
  const int o1 = tid * 16, o2 = o1 + 4096;
  const int r1 = o1 >> 7, r2 = o2 >> 7;
  const int g1 = ((o1 >> 4) & 7) ^ (r1 & 7);
  const int g2 = ((o2 >> 4) & 7) ^ (r2 & 7);
  const size_t k1 = (size_t)r1 * 128 + g1 * 16, k2 = (size_t)r2 * 128 + g2 * 16;
  const size_t v1 = (size_t)r1 * 2048 + g1 * 16, v2 = (size_t)r2 * 2048 + g2 * 16;

  gload_lds16(kbase + k1, smem + o1);
  gload_lds16(kbase + k2, smem + o2);
  gload_lds16(vbase + v1, smem + 16384 + o1);
  gload_lds16(vbase + v2, smem + 16384 + o2);

  // Q B-frags: B[k=d][n=q]: n=q31, k = hb*8 + j within each 16-d chunk
  const unsigned short* qrow = qh + ((size_t)bh * 1024 + sq) * 64 + hb * 8;
  bf16x8 qf[4];
#pragma unroll
  for (int dc = 0; dc < 4; ++dc) qf[dc] = *(const bf16x8*)(qrow + dc * 16);

  const float gate_lane = gate[bh * 1024 + sq];

  // bias parity select (par == (qs0+127-sq)&1, lane-fixed)
  const int par = (127 - w * 32 - q31) & 1;
  const unsigned int* bp = (const unsigned int*)(par ? bc1 : bc0);
  const int bbase0 = (qs0 + 127 - sq - par) >> 1;  // even numerator, >= 0

  // per-q P^T row; FIX R6: include wave offset (w*32+q31), not q31 alone
  char* psrow = smem + 32768 + (w * 32 + q31) * 144;

  float l_run = 0.f;
  f32x16 accO0 = {}, accO1 = {};

  for (int kc = 0; kc < 16; ++kc) {
    __syncthreads();  // current buffer's DMA landed; previous buffer free
    const char* Kc = smem + (kc & 1) * 8192;
    const char* Vc = smem + 16384 + (kc & 1) * 8192;
    if (kc < 15) {
      int nb = (kc + 1) & 1;
      gload_lds16(kbase + (size_t)(kc + 1) * 8192 + k1, smem + nb * 8192 + o1);
      gload_lds16(kbase + (size_t)(kc + 1) * 8192 + k2, smem + nb * 8192 + o2);
      gload_lds16(vbase + (size_t)(kc + 1) * 128 + v1, smem + 16384 + nb * 8192 + o1);
      gload_lds16(vbase + (size_t)(kc + 1) * 128 + v2, smem + 16384 + nb * 8192 + o2);
    }

    // ---- S^T = K Q^T : two 32-key tiles x 32 q, k over d=64 in 4 chunks ----
    f32x16 sacA = {}, sacB = {};
#pragma unroll
    for (int ks = 0; ks < 4; ++ks) {
      int ch = ((ks * 2 + hb) ^ q7) << 4;  // (32+q31)&7 == q31&7
      bf16x8 k0 = *(const bf16x8*)(Kc + q31 * 128 + ch);
      bf16x8 kk1 = *(const bf16x8*)(Kc + (32 + q31) * 128 + ch);
      sacA = MFMA32_BF16(k0, qf[ks], sacA);
      sacB = MFMA32_BF16(kk1, qf[ks], sacB);
    }

    // ---- bias + exp2 + pack P (per 4-score run) ----
    float ps = 0.f;
#pragma unroll
    for (int kt = 0; kt < 2; ++kt) {
#pragma unroll
      for (int rg = 0; rg < 4; ++rg) {
        int runoff = kt * 32 + rg * 8 + hb * 4;  // even
        int idx = bbase0 + ((kc * 64 + runoff) >> 1);
        unsigned int u0 = bp[idx], u1 = bp[idx + 1];
        float s0v = (kt ? sacB : sacA)[rg * 4 + 0];
        float s1v = (kt ? sacB : sacA)[rg * 4 + 1];
        float s2v = (kt ? sacB : sacA)[rg * 4 + 2];
        float s3v = (kt ? sacB : sacA)[rg * 4 + 3];
        float p0 = __builtin_exp2f(__builtin_fmaf(gate_lane, u32lo_bf(u0), s0v));
        float p1 = __builtin_exp2f(__builtin_fmaf(gate_lane, u32hi_bf(u0), s1v));
        float p2 = __builtin_exp2f(__builtin_fmaf(gate_lane, u32lo_bf(u1), s2v));
        float p3 = __builtin_exp2f(__builtin_fmaf(gate_lane, u32hi_bf(u1), s3v));
        ps += (p0 + p1) + (p2 + p3);
        ushort4 pk;
        pk.x = f2bf(p0); pk.y = f2bf(p1); pk.z = f2bf(p2); pk.w = f2bf(p3);
        int c = kt * 4 + rg;  // canonical 16B chunk
        *(ushort4*)(psrow + ((c ^ q7) << 4) + hb * 8) = pk;
      }
    }
    l_run += ps;

    // ---- O^T += V^T P^T : 2 d-tiles x 32 q, k over 64 keys in 4 chunks ----
#pragma unroll
    for (int ks = 0; ks < 4; ++ks) {
      int cc = (ks * 2 + hb) ^ q7;
      bf16x8 pb = *(const bf16x8*)(psrow + (cc << 4));
      int ch = cc << 4;  // V rows share (row&7)==q31&7 for both tiles
      bf16x8 v0f = *(const bf16x8*)(Vc + q31 * 128 + ch);
      bf16x8 v1f = *(const bf16x8*)(Vc + (32 + q31) * 128 + ch);
      accO0 = MFMA32_BF16(v0f, pb, accO0);
      accO1 = MFMA32_BF16(v1f, pb, accO1);
    }
  }

  // denominator: hb halves partition keys mod 8
  l_run += __shfl_xor(l_run, 32, 64);
  const float inv = 1.0f / l_run;

  // ---- epilogue: O^T -> LDS transpose -> dense f16 ctx stores ----
  __syncthreads();
  float* Ot = (float*)smem;  // [128][68]
  {
    float* ow = Ot + (w * 32 + q31) * 68;
#pragma unroll
    for (int rr = 0; rr < 16; ++rr) {
      int d = (rr & 3) + 8 * (rr >> 2) + 4 * hb;
      ow[d] = accO0[rr] * inv;
      ow[32 + d] = accO1[rr] * inv;
    }
  }
  __syncthreads();
  {
    int row = tid >> 1, dg = tid & 1;  // 128 rows x 2 halves of 32 d
    int s = qs0 + row;
    const float* src = Ot + row * 68 + dg * 32;
    unsigned short hbuf[32];
#pragma unroll
    for (int j = 0; j < 32; ++j) hbuf[j] = f2h(src[j]);
    size_t base = (size_t)(s * 4 + (bh >> 4)) * 1024 + h * 64 + dg * 32;
#pragma unroll
    for (int qd = 0; qd < 4; ++qd)
      *(uint4*)(ctx + base + qd * 8) = *(const uint4*)(hbuf + qd * 8);
  }
}

// ---------------- output projection: single f16 GEMM, 64x128 tiles, dbuf DMA ----------------
__global__ __launch_bounds__(256, 3) void outproj_kernel(
    const unsigned short* __restrict__ Af,  // ctx f16 (4096,1024)
    const unsigned short* __restrict__ Bf,  // out_w f16 (1024,1024)
    const float* __restrict__ ob, float* __restrict__ out) {
  // per-buffer: A 4K + B 8K = 12K; x2 = 24K
  __shared__ __align__(16) char smem[24576];
  const int tid = threadIdx.x, lane = tid & 63, wv_ = tid >> 6;
  const int q15 = lane & 15, quad = lane >> 4;
  const int n0 = blockIdx.x * 128;
  const int m0 = blockIdx.y * 64;
  const int moff = (wv_ & 1) * 32;
  const int noff = (wv_ >> 1) * 64;

  const int oa = tid * 16;
  const int ra_ = oa >> 6;
  const int ga_ = (((oa >> 4) & 3) ^ swz(ra_)) << 4;
  int rb_[2], gb_[2], obo_[2];
#pragma unroll
  for (int c = 0; c < 2; ++c) {
    int ob2 = c * 4096 + tid * 16;
    obo_[c] = ob2;
    rb_[c] = ob2 >> 6;
    gb_[c] = (((ob2 >> 4) & 3) ^ swz(rb_[c])) << 4;
  }

#define OP_STAGE(kt, buf)                                                        \
  {                                                                              \
    char* bb = smem + (buf)*12288;                                               \
    size_t ga = (size_t)(m0 + ra_) * 2048 + (size_t)(kt)*64 + ga_;               \
    gload_lds16((const char*)Af + ga, bb + oa);                                  \
    _Pragma("unroll") for (int c = 0; c < 2; ++c) {                              \
      size_t gb = (size_t)(n0 + rb_[c]) * 2048 + (size_t)(kt)*64 + gb_[c];       \
      gload_lds16((const char*)Bf + gb, bb + 4096 + obo_[c]);                    \
    }                                                                            \
  }

  f32x4 acc[2][4] = {};
  OP_STAGE(0, 0);
  for (int kt = 0; kt < 32; ++kt) {
    __syncthreads();
    const char* base = smem + (kt & 1) * 12288;
    if (kt < 31) OP_STAGE(kt + 1, (kt + 1) & 1);

    f16x8 ah[2], bhf[4];
#pragma unroll
    for (int i = 0; i < 2; ++i) {
      int ra = moff + i * 16 + q15;
      ah[i] = *(const f16x8*)(base + ra * 64 + ((quad ^ swz(ra)) << 4));
    }
#pragma unroll
    for (int j = 0; j < 4; ++j) {
      int rb = noff + j * 16 + q15;
      bhf[j] = *(const f16x8*)(base + 4096 + rb * 64 + ((quad ^ swz(rb)) << 4));
    }
#pragma unroll
    for (int i = 0; i < 2; ++i)
#pragma unroll
      for (int j = 0; j < 4; ++j) acc[i][j] = MFMA_F16(ah[i], bhf[j], acc[i][j]);
  }
#undef OP_STAGE

  const int rr0 = m0 + moff + (quad << 2);
  const int c0 = n0 + noff + q15;
#pragma unroll
  for (int j = 0; j < 4; ++j) {
    int col = c0 + j * 16;
    float bias = ob[col];
#pragma unroll
    for (int i = 0; i < 2; ++i)
#pragma unroll
      for (int r = 0; r < 4; ++r)
        out[(size_t)(rr0 + i * 16 + r) * 1024 + col] = acc[i][j][r] + bias;
  }
}

// ---------------- launcher ----------------
extern "C" void kernel_launch(void* const* d_in, const int* in_sizes, int n_in,
                              void* d_out, int out_size, void* d_ws, size_t ws_size,
                              hipStream_t stream) {
  const float* query = (const float*)d_in[0];
  const float* q_w = (const float*)d_in[1];
  const float* q_b = (const float*)d_in[2];
  const float* k_w = (const float*)d_in[3];
  const float* k_b = (const float*)d_in[4];
  const float* v_w = (const float*)d_in[5];
  const float* v_b = (const float*)d_in[6];
  const float* out_w = (const float*)d_in[7];
  const float* out_b = (const float*)d_in[8];
  const float* rel_emb = (const float*)d_in[9];
  const float* grep_w = (const float*)d_in[10];
  const float* grep_b = (const float*)d_in[11];
  const float* grep_a = (const float*)d_in[12];
  float* out = (float*)d_out;

  const size_t MB = 1u << 20;
  char* ws = (char*)d_ws;
  unsigned short* q_bf = (unsigned short*)(ws);            // (B,S,E) bf16, 8 MB
  unsigned short* wq_bf = (unsigned short*)(ws + 8 * MB);
  unsigned short* wk_bf = (unsigned short*)(ws + 10 * MB);
  unsigned short* wv_bf = (unsigned short*)(ws + 12 * MB);
  unsigned short* ow_h = (unsigned short*)(ws + 14 * MB);  // f16
  unsigned short* qhp = (unsigned short*)(ws + 16 * MB);   // (B,H,S,D)
  unsigned short* khp = (unsigned short*)(ws + 24 * MB);   // (B,H,S,D)
  unsigned short* vTp = (unsigned short*)(ws + 32 * MB);   // (B,H,D,S)
  unsigned short* ctxp = (unsigned short*)(ws + 40 * MB);  // (S*B,E) f16
  float* gatep = (float*)(ws + 48 * MB);
  unsigned short* biasp = (unsigned short*)(ws + 48 * MB + 256 * 1024);  // bf16 16x2056

  prep_kernel<<<20489, 256, 0, stream>>>(query, q_w, k_w, v_w, out_w, rel_emb, q_bf, wq_bf,
                                         wk_bf, wv_bf, ow_h, biasp);
  qkv_gemm_kernel<<<dim3(24, 32), 256, 0, stream>>>(q_bf, wq_bf, wk_bf, wv_bf, q_b, k_b, v_b,
                                                    qhp, khp, vTp);
  gate_kernel<<<256, 256, 0, stream>>>(qhp, grep_w, grep_b, grep_a, gatep);
  attn_kernel<<<dim3(64, 8), 256, 0, stream>>>(qhp, khp, vTp, gatep, biasp, ctxp);
  outproj_kernel<<<dim3(8, 64), 256, 0, stream>>>(ctxp, ow_h, out_b, out);
}

// Round 8
// 200.000 us; speedup vs baseline: 2.2698x; 1.0345x over previous
//
#include <hip/hip_runtime.h>
#include <stdint.h>

// Problem dims (fixed): S=1024, B=4, E=1024, H=16, D=64, M=S*B=4096
// scaling = D^-0.5 = 0.125; log2e folded into q-scale and bias table so the
// attention softmax uses raw exp2.

typedef short bf16x8 __attribute__((ext_vector_type(8)));
typedef _Float16 f16x8 __attribute__((ext_vector_type(8)));
typedef float f32x4 __attribute__((ext_vector_type(4)));
typedef float f32x16 __attribute__((ext_vector_type(16)));

#define MFMA_BF16(a, b, c) __builtin_amdgcn_mfma_f32_16x16x32_bf16((a), (b), (c), 0, 0, 0)
#define MFMA_F16(a, b, c) __builtin_amdgcn_mfma_f32_16x16x32_f16((a), (b), (c), 0, 0, 0)
#define MFMA32_BF16(a, b, c) __builtin_amdgcn_mfma_f32_32x32x16_bf16((a), (b), (c), 0, 0, 0)

#define LOG2E 1.44269504088896f
#define LN2 0.693147180559945f

__device__ __forceinline__ unsigned short f2bf(float x) {
  union { float f; unsigned u; } v; v.f = x;
  unsigned r = v.u + 0x7fffu + ((v.u >> 16) & 1u);  // RNE
  return (unsigned short)(r >> 16);
}
__device__ __forceinline__ float bf2f(unsigned short u) {
  union { unsigned u; float f; } v; v.u = ((unsigned)u) << 16;
  return v.f;
}
__device__ __forceinline__ unsigned short f2h(float x) {  // RNE via v_cvt_f16_f32
  union { _Float16 h; unsigned short u; } v; v.h = (_Float16)x;
  return v.u;
}
__device__ __forceinline__ float u32lo_bf(unsigned u) {
  union { unsigned u; float f; } v; v.u = u << 16;
  return v.f;
}
__device__ __forceinline__ float u32hi_bf(unsigned u) {
  union { unsigned u; float f; } v; v.u = u & 0xffff0000u;
  return v.f;
}

// async global->LDS 16B: lane's data lands at (wave-uniform base) + lane*16.
__device__ __forceinline__ void gload_lds16(const void* g, void* l) {
  __builtin_amdgcn_global_load_lds(
      (const __attribute__((address_space(1))) unsigned int*)g,
      (__attribute__((address_space(3))) unsigned int*)l, 16, 0, 0);
}

// LDS chunk swizzle for 64B rows (4 chunks of 16B)
__device__ __forceinline__ int swz(int row) { return (row ^ (row >> 2)) & 3; }

// ---------------- fused prep: query cvt/transpose + weight prep + relbias ----------------
__global__ __launch_bounds__(256) void prep_kernel(
    const float* __restrict__ query, const float* __restrict__ q_w,
    const float* __restrict__ k_w, const float* __restrict__ v_w,
    const float* __restrict__ out_w, const float* __restrict__ rel_emb,
    unsigned short* __restrict__ q_bf, unsigned short* __restrict__ wq,
    unsigned short* __restrict__ wk, unsigned short* __restrict__ wv,
    unsigned short* __restrict__ ow_h,       // f16 out_w
    unsigned short* __restrict__ bias_hd) {  // bf16, 16 x 2056 (last 9 zero-padded)
  int i = blockIdx.x * 256 + threadIdx.x;
  if (i < 4194304) {
    int e = i & 1023;
    int sb = i >> 10;
    int s = sb >> 2, b = sb & 3;
    q_bf[((size_t)(b * 1024 + s) << 10) | e] = f2bf(query[i]);
  } else if (i < 5242880) {
    int j = i - 4194304;  // < 1M
    wq[j] = f2bf(q_w[j]);
    wk[j] = f2bf(k_w[j]);
    wv[j] = f2bf(v_w[j]);
    ow_h[j] = f2h(out_w[j]);
  } else {
    int idx = i - 5242880;
    if (idx >= 2056) return;
    if (idx >= 2047) {
#pragma unroll
      for (int h = 0; h < 16; ++h) bias_hd[h * 2056 + idx] = 0;
      return;
    }
    int rel = idx - 1023;
    int n = rel < 0 ? -rel : rel;
    int ret = rel > 0 ? 16 : 0;
    int bucket;
    if (n < 8) {
      bucket = ret + n;
    } else {
      int large = 8 + (int)(logf((float)n / 8.0f) / logf(16.0f) * 8.0f);
      if (large > 15) large = 15;
      bucket = ret + large;
    }
#pragma unroll
    for (int h = 0; h < 16; ++h)
      bias_hd[h * 2056 + idx] = f2bf(rel_emb[bucket * 16 + h] * LOG2E);
  }
}

// ---------------- fused QKV projection GEMM (dbuf DMA, 1 barrier/kt) ----------------
__global__ __launch_bounds__(256, 3) void qkv_gemm_kernel(
    const unsigned short* __restrict__ A, const unsigned short* __restrict__ Wq,
    const unsigned short* __restrict__ Wk, const unsigned short* __restrict__ Wv,
    const float* __restrict__ qb, const float* __restrict__ kb, const float* __restrict__ vb,
    unsigned short* __restrict__ qh,   // (B,H,S,D) scaled q
    unsigned short* __restrict__ kh,   // (B,H,S,D)
    unsigned short* __restrict__ vT)   // (B,H,D,S)
{
  __shared__ __align__(16) char smem[32768];
  const int tid = threadIdx.x, lane = tid & 63;
  const int wv_ = tid >> 6;
  const int nt = blockIdx.x;
  const int mt = blockIdx.y;
  const int mat = nt >> 3;
  const unsigned short* W = mat == 0 ? Wq : (mat == 1 ? Wk : Wv);
  const int n0 = (nt & 7) * 128;
  const int m0 = mt * 128;
  const int moff = (wv_ & 1) * 64;
  const int noff = (wv_ >> 1) * 64;

  f32x4 acc[4][4] = {};
  const char* Ab = (const char*)A;
  const char* Wb = (const char*)W;

  int st_row[2], st_g[2];
#pragma unroll
  for (int c = 0; c < 2; ++c) {
    int o = c * 4096 + tid * 16;
    int row = o >> 6, p = (o >> 4) & 3;
    st_row[c] = row;
    st_g[c] = p ^ swz(row);
  }

#define QKV_STAGE(kt, buf)                                                     \
  {                                                                            \
    char* bb = smem + (buf)*16384;                                             \
    _Pragma("unroll") for (int c = 0; c < 2; ++c) {                            \
      int o = c * 4096 + tid * 16;                                             \
      size_t ga = (size_t)(m0 + st_row[c]) * 2048 + (size_t)(kt)*64 + st_g[c] * 16; \
      size_t gb = (size_t)(n0 + st_row[c]) * 2048 + (size_t)(kt)*64 + st_g[c] * 16; \
      gload_lds16(Ab + ga, bb + o);                                            \
      gload_lds16(Wb + gb, bb + 8192 + o);                                     \
    }                                                                          \
  }

  QKV_STAGE(0, 0);
  for (int kt = 0; kt < 32; ++kt) {
    __syncthreads();
    const char* base = smem + (kt & 1) * 16384;
    if (kt < 31) QKV_STAGE(kt + 1, (kt + 1) & 1);

    bf16x8 af[4], bfr[4];
#pragma unroll
    for (int i = 0; i < 4; ++i) {
      int ra = moff + i * 16 + (lane & 15);
      int rb = noff + i * 16 + (lane & 15);
      int q = lane >> 4;
      af[i] = *(const bf16x8*)(base + ra * 64 + (q ^ swz(ra)) * 16);
      bfr[i] = *(const bf16x8*)(base + 8192 + rb * 64 + (q ^ swz(rb)) * 16);
    }
#pragma unroll
    for (int i = 0; i < 4; ++i)
#pragma unroll
      for (int j = 0; j < 4; ++j) acc[i][j] = MFMA_BF16(af[i], bfr[j], acc[i][j]);
  }
#undef QKV_STAGE

  const int bidx = m0 >> 10;
  const int s00 = (m0 & 1023) + moff + ((lane >> 4) << 2);
  const int c0 = n0 + noff + (lane & 15);
  if (mat < 2) {
    const float* barr = mat == 0 ? qb : kb;
    unsigned short* dst = mat == 0 ? qh : kh;
    const float scale = mat == 0 ? (0.125f * LOG2E) : 1.0f;
#pragma unroll
    for (int j = 0; j < 4; ++j) {
      int col = c0 + j * 16;
      int hh = col >> 6, dd = col & 63;
      float bias = barr[col];
#pragma unroll
      for (int i = 0; i < 4; ++i)
#pragma unroll
        for (int r = 0; r < 4; ++r) {
          int s = s00 + i * 16 + r;
          dst[((size_t)(bidx * 16 + hh) * 1024 + s) * 64 + dd] =
              f2bf((acc[i][j][r] + bias) * scale);
        }
    }
  } else {
#pragma unroll
    for (int j = 0; j < 4; ++j) {
      int col = c0 + j * 16;
      int hh = col >> 6, dd = col & 63;
      float bias = vb[col];
#pragma unroll
      for (int i = 0; i < 4; ++i) {
        int s = s00 + i * 16;
        ushort4 pk;
        pk.x = f2bf(acc[i][j][0] + bias);
        pk.y = f2bf(acc[i][j][1] + bias);
        pk.z = f2bf(acc[i][j][2] + bias);
        pk.w = f2bf(acc[i][j][3] + bias);
        *(ushort4*)&vT[((size_t)(bidx * 16 + hh) * 64 + dd) * 1024 + s] = pk;
      }
    }
  }
}

// ---------------- gate kernel ----------------
__global__ __launch_bounds__(256) void gate_kernel(const unsigned short* __restrict__ qh,
                                                   const float* __restrict__ grep_w,
                                                   const float* __restrict__ grep_b,
                                                   const float* __restrict__ grep_a,
                                                   float* __restrict__ gate) {
  __shared__ float gw[512];
  __shared__ float gbb[8];
  __shared__ float gaa[16];
  int tid = threadIdx.x;
  for (int i = tid; i < 512; i += 256) gw[i] = grep_w[i];
  if (tid < 8) gbb[tid] = grep_b[tid];
  if (tid < 16) gaa[tid] = grep_a[tid];
  __syncthreads();
  int idx = blockIdx.x * 256 + tid;  // bh*1024 + s
  int h = (idx >> 10) & 15;
  const unsigned short* qrow = qh + (size_t)idx * 64;
  float a[8] = {0.f, 0.f, 0.f, 0.f, 0.f, 0.f, 0.f, 0.f};
#pragma unroll
  for (int c = 0; c < 8; ++c) {
    bf16x8 v = *(const bf16x8*)(qrow + c * 8);
#pragma unroll
    for (int jj = 0; jj < 8; ++jj) {
      float qv = bf2f((unsigned short)v[jj]);
      int d = c * 8 + jj;
#pragma unroll
      for (int e = 0; e < 8; ++e) a[e] += qv * gw[e * 64 + d];
    }
  }
  float sa = (a[0] + a[1] + a[2] + a[3]) * LN2 + gbb[0] + gbb[1] + gbb[2] + gbb[3];
  float sb = (a[4] + a[5] + a[6] + a[7]) * LN2 + gbb[4] + gbb[5] + gbb[6] + gbb[7];
  float siga = 1.f / (1.f + __expf(-sa));
  float sigb = 1.f / (1.f + __expf(-sb));
  gate[idx] = siga * (sigb * gaa[h] - 1.f) + 2.f;
}

// ---------------- flash attention v3.1: 32x32 MFMA, wave-q=32, 256 threads ----------------
// R8 FIX: Ps row stride 144B -> 128B (bank-aligned rows + pure-XOR chunk
// placement). 144B = 4 banks mod 32 made bank = 4*(q7 + (c^q7)) — additive
// composition collapses to 2 banks for c=7 (32-way conflict, 13.4M counted).
// With 128B rows, bank = 4*(c^q7): quarter-wave 2-way = free.
__global__ __launch_bounds__(256, 2) void attn_kernel(
    const unsigned short* __restrict__ qh, const unsigned short* __restrict__ kh,
    const unsigned short* __restrict__ vT, const float* __restrict__ gate,
    const unsigned short* __restrict__ bias_hd, unsigned short* __restrict__ ctx) {
  // LDS: K dbuf [0,16K) V dbuf [16K,32K) Ps [32768,49152) bias c0 [49152,+2304) c1 [51456,+2304)
  // epilogue reuses [0,34816) as Ot fp32[128][68]
  __shared__ __align__(16) char smem[53760];
  const int tid = threadIdx.x, lane = tid & 63, w = tid >> 6;
  const int bh = blockIdx.x;  // b*16+h
  const int h = bh & 15;
  const int qs0 = blockIdx.y * 128;
  const int q31 = lane & 31, hb = lane >> 5, q7 = q31 & 7;
  const int sq = qs0 + w * 32 + q31;

  // bias windows: W[i] = bias[h][896-qs0+i] (bf16), copy1 shifted by +1
  unsigned short* bc0 = (unsigned short*)(smem + 49152);
  unsigned short* bc1 = (unsigned short*)(smem + 51456);
  {
    const unsigned short* gb = bias_hd + h * 2056 + (896 - qs0);
    for (int i = tid; i < 1152; i += 256) {
      bc0[i] = gb[i];
      bc1[i] = gb[i + 1];
    }
  }

  const char* kbase = (const char*)(kh + (size_t)bh * 65536);
  const char* vbase = (const char*)(vT + (size_t)bh * 65536);

  // staging: 256 thr x 2 chunks x 16B = 8KB tile
  const int o1 = tid * 16, o2 = o1 + 4096;
  const int r1 = o1 >> 7, r2 = o2 >> 7;
  const int g1 = ((o1 >> 4) & 7) ^ (r1 & 7);
  const int g2 = ((o2 >> 4) & 7) ^ (r2 & 7);
  const size_t k1 = (size_t)r1 * 128 + g1 * 16, k2 = (size_t)r2 * 128 + g2 * 16;
  const size_t v1 = (size_t)r1 * 2048 + g1 * 16, v2 = (size_t)r2 * 2048 + g2 * 16;

  gload_lds16(kbase + k1, smem + o1);
  gload_lds16(kbase + k2, smem + o2);
  gload_lds16(vbase + v1, smem + 16384 + o1);
  gload_lds16(vbase + v2, smem + 16384 + o2);

  // Q B-frags: B[k=d][n=q]: n=q31, k = hb*8 + j within each 16-d chunk
  const unsigned short* qrow = qh + ((size_t)bh * 1024 + sq) * 64 + hb * 8;
  bf16x8 qf[4];
#pragma unroll
  for (int dc = 0; dc < 4; ++dc) qf[dc] = *(const bf16x8*)(qrow + dc * 16);

  const float gate_lane = gate[bh * 1024 + sq];

  // bias parity select (par == (qs0+127-sq)&1, lane-fixed)
  const int par = (127 - w * 32 - q31) & 1;
  const unsigned int* bp = (const unsigned int*)(par ? bc1 : bc0);
  const int bbase0 = (qs0 + 127 - sq - par) >> 1;  // even numerator, >= 0

  // per-q P^T row: 128B stride (bank-aligned), pure-XOR chunk placement
  char* psrow = smem + 32768 + (w * 32 + q31) * 128;

  float l_run = 0.f;
  f32x16 accO0 = {}, accO1 = {};

  for (int kc = 0; kc < 16; ++kc) {
    __syncthreads();  // current buffer's DMA landed; previous buffer free
    const char* Kc = smem + (kc & 1) * 8192;
    const char* Vc = smem + 16384 + (kc & 1) * 8192;
    if (kc < 15) {
      int nb = (kc + 1) & 1;
      gload_lds16(kbase + (size_t)(kc + 1) * 8192 + k1, smem + nb * 8192 + o1);
      gload_lds16(kbase + (size_t)(kc + 1) * 8192 + k2, smem + nb * 8192 + o2);
      gload_lds16(vbase + (size_t)(kc + 1) * 128 + v1, smem + 16384 + nb * 8192 + o1);
      gload_lds16(vbase + (size_t)(kc + 1) * 128 + v2, smem + 16384 + nb * 8192 + o2);
    }

    // ---- S^T = K Q^T : two 32-key tiles x 32 q, k over d=64 in 4 chunks ----
    f32x16 sacA = {}, sacB = {};
#pragma unroll
    for (int ks = 0; ks < 4; ++ks) {
      int ch = ((ks * 2 + hb) ^ q7) << 4;  // (32+q31)&7 == q31&7
      bf16x8 k0 = *(const bf16x8*)(Kc + q31 * 128 + ch);
      bf16x8 kk1 = *(const bf16x8*)(Kc + (32 + q31) * 128 + ch);
      sacA = MFMA32_BF16(k0, qf[ks], sacA);
      sacB = MFMA32_BF16(kk1, qf[ks], sacB);
    }

    // ---- bias + exp2 + pack P (per 4-score run) ----
    float ps = 0.f;
#pragma unroll
    for (int kt = 0; kt < 2; ++kt) {
#pragma unroll
      for (int rg = 0; rg < 4; ++rg) {
        int runoff = kt * 32 + rg * 8 + hb * 4;  // even
        int idx = bbase0 + ((kc * 64 + runoff) >> 1);
        unsigned int u0 = bp[idx], u1 = bp[idx + 1];
        float s0v = (kt ? sacB : sacA)[rg * 4 + 0];
        float s1v = (kt ? sacB : sacA)[rg * 4 + 1];
        float s2v = (kt ? sacB : sacA)[rg * 4 + 2];
        float s3v = (kt ? sacB : sacA)[rg * 4 + 3];
        float p0 = __builtin_exp2f(__builtin_fmaf(gate_lane, u32lo_bf(u0), s0v));
        float p1 = __builtin_exp2f(__builtin_fmaf(gate_lane, u32hi_bf(u0), s1v));
        float p2 = __builtin_exp2f(__builtin_fmaf(gate_lane, u32lo_bf(u1), s2v));
        float p3 = __builtin_exp2f(__builtin_fmaf(gate_lane, u32hi_bf(u1), s3v));
        ps += (p0 + p1) + (p2 + p3);
        ushort4 pk;
        pk.x = f2bf(p0); pk.y = f2bf(p1); pk.z = f2bf(p2); pk.w = f2bf(p3);
        int c = kt * 4 + rg;  // canonical 16B chunk
        *(ushort4*)(psrow + ((c ^ q7) << 4) + hb * 8) = pk;
      }
    }
    l_run += ps;

    // ---- O^T += V^T P^T : 2 d-tiles x 32 q, k over 64 keys in 4 chunks ----
#pragma unroll
    for (int ks = 0; ks < 4; ++ks) {
      int cc = (ks * 2 + hb) ^ q7;
      bf16x8 pb = *(const bf16x8*)(psrow + (cc << 4));
      int ch = cc << 4;  // V rows share (row&7)==q31&7 for both tiles
      bf16x8 v0f = *(const bf16x8*)(Vc + q31 * 128 + ch);
      bf16x8 v1f = *(const bf16x8*)(Vc + (32 + q31) * 128 + ch);
      accO0 = MFMA32_BF16(v0f, pb, accO0);
      accO1 = MFMA32_BF16(v1f, pb, accO1);
    }
  }

  // denominator: hb halves partition keys mod 8
  l_run += __shfl_xor(l_run, 32, 64);
  const float inv = 1.0f / l_run;

  // ---- epilogue: O^T -> LDS transpose -> dense f16 ctx stores ----
  __syncthreads();
  float* Ot = (float*)smem;  // [128][68]
  {
    float* ow = Ot + (w * 32 + q31) * 68;
#pragma unroll
    for (int rr = 0; rr < 16; ++rr) {
      int d = (rr & 3) + 8 * (rr >> 2) + 4 * hb;
      ow[d] = accO0[rr] * inv;
      ow[32 + d] = accO1[rr] * inv;
    }
  }
  __syncthreads();
  {
    int row = tid >> 1, dg = tid & 1;  // 128 rows x 2 halves of 32 d
    int s = qs0 + row;
    const float* src = Ot + row * 68 + dg * 32;
    unsigned short hbuf[32];
#pragma unroll
    for (int j = 0; j < 32; ++j) hbuf[j] = f2h(src[j]);
    size_t base = (size_t)(s * 4 + (bh >> 4)) * 1024 + h * 64 + dg * 32;
#pragma unroll
    for (int qd = 0; qd < 4; ++qd)
      *(uint4*)(ctx + base + qd * 8) = *(const uint4*)(hbuf + qd * 8);
  }
}

// ---------------- output projection: single f16 GEMM, 64x128 tiles, dbuf DMA ----------------
__global__ __launch_bounds__(256, 3) void outproj_kernel(
    const unsigned short* __restrict__ Af,  // ctx f16 (4096,1024)
    const unsigned short* __restrict__ Bf,  // out_w f16 (1024,1024)
    const float* __restrict__ ob, float* __restrict__ out) {
  // per-buffer: A 4K + B 8K = 12K; x2 = 24K
  __shared__ __align__(16) char smem[24576];
  const int tid = threadIdx.x, lane = tid & 63, wv_ = tid >> 6;
  const int q15 = lane & 15, quad = lane >> 4;
  const int n0 = blockIdx.x * 128;
  const int m0 = blockIdx.y * 64;
  const int moff = (wv_ & 1) * 32;
  const int noff = (wv_ >> 1) * 64;

  const int oa = tid * 16;
  const int ra_ = oa >> 6;
  const int ga_ = (((oa >> 4) & 3) ^ swz(ra_)) << 4;
  int rb_[2], gb_[2], obo_[2];
#pragma unroll
  for (int c = 0; c < 2; ++c) {
    int ob2 = c * 4096 + tid * 16;
    obo_[c] = ob2;
    rb_[c] = ob2 >> 6;
    gb_[c] = (((ob2 >> 4) & 3) ^ swz(rb_[c])) << 4;
  }

#define OP_STAGE(kt, buf)                                                        \
  {                                                                              \
    char* bb = smem + (buf)*12288;                                               \
    size_t ga = (size_t)(m0 + ra_) * 2048 + (size_t)(kt)*64 + ga_;               \
    gload_lds16((const char*)Af + ga, bb + oa);                                  \
    _Pragma("unroll") for (int c = 0; c < 2; ++c) {                              \
      size_t gb = (size_t)(n0 + rb_[c]) * 2048 + (size_t)(kt)*64 + gb_[c];       \
      gload_lds16((const char*)Bf + gb, bb + 4096 + obo_[c]);                    \
    }                                                                            \
  }

  f32x4 acc[2][4] = {};
  OP_STAGE(0, 0);
  for (int kt = 0; kt < 32; ++kt) {
    __syncthreads();
    const char* base = smem + (kt & 1) * 12288;
    if (kt < 31) OP_STAGE(kt + 1, (kt + 1) & 1);

    f16x8 ah[2], bhf[4];
#pragma unroll
    for (int i = 0; i < 2; ++i) {
      int ra = moff + i * 16 + q15;
      ah[i] = *(const f16x8*)(base + ra * 64 + ((quad ^ swz(ra)) << 4));
    }
#pragma unroll
    for (int j = 0; j < 4; ++j) {
      int rb = noff + j * 16 + q15;
      bhf[j] = *(const f16x8*)(base + 4096 + rb * 64 + ((quad ^ swz(rb)) << 4));
    }
#pragma unroll
    for (int i = 0; i < 2; ++i)
#pragma unroll
      for (int j = 0; j < 4; ++j) acc[i][j] = MFMA_F16(ah[i], bhf[j], acc[i][j]);
  }
#undef OP_STAGE

  const int rr0 = m0 + moff + (quad << 2);
  const int c0 = n0 + noff + q15;
#pragma unroll
  for (int j = 0; j < 4; ++j) {
    int col = c0 + j * 16;
    float bias = ob[col];
#pragma unroll
    for (int i = 0; i < 2; ++i)
#pragma unroll
      for (int r = 0; r < 4; ++r)
        out[(size_t)(rr0 + i * 16 + r) * 1024 + col] = acc[i][j][r] + bias;
  }
}

// ---------------- launcher ----------------
extern "C" void kernel_launch(void* const* d_in, const int* in_sizes, int n_in,
                              void* d_out, int out_size, void* d_ws, size_t ws_size,
                              hipStream_t stream) {
  const float* query = (const float*)d_in[0];
  const float* q_w = (const float*)d_in[1];
  const float* q_b = (const float*)d_in[2];
  const float* k_w = (const float*)d_in[3];
  const float* k_b = (const float*)d_in[4];
  const float* v_w = (const float*)d_in[5];
  const float* v_b = (const float*)d_in[6];
  const float* out_w = (const float*)d_in[7];
  const float* out_b = (const float*)d_in[8];
  const float* rel_emb = (const float*)d_in[9];
  const float* grep_w = (const float*)d_in[10];
  const float* grep_b = (const float*)d_in[11];
  const float* grep_a = (const float*)d_in[12];
  float* out = (float*)d_out;

  const size_t MB = 1u << 20;
  char* ws = (char*)d_ws;
  unsigned short* q_bf = (unsigned short*)(ws);            // (B,S,E) bf16, 8 MB
  unsigned short* wq_bf = (unsigned short*)(ws + 8 * MB);
  unsigned short* wk_bf = (unsigned short*)(ws + 10 * MB);
  unsigned short* wv_bf = (unsigned short*)(ws + 12 * MB);
  unsigned short* ow_h = (unsigned short*)(ws + 14 * MB);  // f16
  unsigned short* qhp = (unsigned short*)(ws + 16 * MB);   // (B,H,S,D)
  unsigned short* khp = (unsigned short*)(ws + 24 * MB);   // (B,H,S,D)
  unsigned short* vTp = (unsigned short*)(ws + 32 * MB);   // (B,H,D,S)
  unsigned short* ctxp = (unsigned short*)(ws + 40 * MB);  // (S*B,E) f16
  float* gatep = (float*)(ws + 48 * MB);
  unsigned short* biasp = (unsigned short*)(ws + 48 * MB + 256 * 1024);  // bf16 16x2056

  prep_kernel<<<20489, 256, 0, stream>>>(query, q_w, k_w, v_w, out_w, rel_emb, q_bf, wq_bf,
                                         wk_bf, wv_bf, ow_h, biasp);
  qkv_gemm_kernel<<<dim3(24, 32), 256, 0, stream>>>(q_bf, wq_bf, wk_bf, wv_bf, q_b, k_b, v_b,
                                                    qhp, khp, vTp);
  gate_kernel<<<256, 256, 0, stream>>>(qhp, grep_w, grep_b, grep_a, gatep);
  attn_kernel<<<dim3(64, 8), 256, 0, stream>>>(qhp, khp, vTp, gatep, biasp, ctxp);
  outproj_kernel<<<dim3(8, 64), 256, 0, stream>>>(ctxp, ow_h, out_b, out);
}

// Round 9
// 193.140 us; speedup vs baseline: 2.3504x; 1.0355x over previous
//
#include <hip/hip_runtime.h>
#include <stdint.h>

// Problem dims (fixed): S=1024, B=4, E=1024, H=16, D=64, M=S*B=4096
// scaling = D^-0.5 = 0.125; log2e folded into q-scale and bias table so the
// attention softmax uses raw exp2.

typedef short bf16x8 __attribute__((ext_vector_type(8)));
typedef _Float16 f16x8 __attribute__((ext_vector_type(8)));
typedef float f32x4 __attribute__((ext_vector_type(4)));
typedef float f32x16 __attribute__((ext_vector_type(16)));

#define MFMA_BF16(a, b, c) __builtin_amdgcn_mfma_f32_16x16x32_bf16((a), (b), (c), 0, 0, 0)
#define MFMA_F16(a, b, c) __builtin_amdgcn_mfma_f32_16x16x32_f16((a), (b), (c), 0, 0, 0)
#define MFMA32_BF16(a, b, c) __builtin_amdgcn_mfma_f32_32x32x16_bf16((a), (b), (c), 0, 0, 0)

#define LOG2E 1.44269504088896f
#define LN2 0.693147180559945f

__device__ __forceinline__ unsigned short f2bf(float x) {
  union { float f; unsigned u; } v; v.f = x;
  unsigned r = v.u + 0x7fffu + ((v.u >> 16) & 1u);  // RNE
  return (unsigned short)(r >> 16);
}
__device__ __forceinline__ float bf2f(unsigned short u) {
  union { unsigned u; float f; } v; v.u = ((unsigned)u) << 16;
  return v.f;
}
__device__ __forceinline__ unsigned short f2h(float x) {  // RNE via v_cvt_f16_f32
  union { _Float16 h; unsigned short u; } v; v.h = (_Float16)x;
  return v.u;
}
__device__ __forceinline__ float u32lo_bf(unsigned u) {
  union { unsigned u; float f; } v; v.u = u << 16;
  return v.f;
}
__device__ __forceinline__ float u32hi_bf(unsigned u) {
  union { unsigned u; float f; } v; v.u = u & 0xffff0000u;
  return v.f;
}

// async global->LDS 16B: lane's data lands at (wave-uniform base) + lane*16.
__device__ __forceinline__ void gload_lds16(const void* g, void* l) {
  __builtin_amdgcn_global_load_lds(
      (const __attribute__((address_space(1))) unsigned int*)g,
      (__attribute__((address_space(3))) unsigned int*)l, 16, 0, 0);
}

// LDS chunk swizzle for 64B rows (4 chunks of 16B)
__device__ __forceinline__ int swz(int row) { return (row ^ (row >> 2)) & 3; }

// ---------------- fused prep: query cvt/transpose + weight prep + relbias ----------------
__global__ __launch_bounds__(256) void prep_kernel(
    const float* __restrict__ query, const float* __restrict__ q_w,
    const float* __restrict__ k_w, const float* __restrict__ v_w,
    const float* __restrict__ out_w, const float* __restrict__ rel_emb,
    unsigned short* __restrict__ q_bf, unsigned short* __restrict__ wq,
    unsigned short* __restrict__ wk, unsigned short* __restrict__ wv,
    unsigned short* __restrict__ ow_h,       // f16 out_w
    unsigned short* __restrict__ bias_hd) {  // bf16, 16 x 2056 (last 9 zero-padded)
  int i = blockIdx.x * 256 + threadIdx.x;
  if (i < 4194304) {
    int e = i & 1023;
    int sb = i >> 10;
    int s = sb >> 2, b = sb & 3;
    q_bf[((size_t)(b * 1024 + s) << 10) | e] = f2bf(query[i]);
  } else if (i < 5242880) {
    int j = i - 4194304;  // < 1M
    wq[j] = f2bf(q_w[j]);
    wk[j] = f2bf(k_w[j]);
    wv[j] = f2bf(v_w[j]);
    ow_h[j] = f2h(out_w[j]);
  } else {
    int idx = i - 5242880;
    if (idx >= 2056) return;
    if (idx >= 2047) {
#pragma unroll
      for (int h = 0; h < 16; ++h) bias_hd[h * 2056 + idx] = 0;
      return;
    }
    int rel = idx - 1023;
    int n = rel < 0 ? -rel : rel;
    int ret = rel > 0 ? 16 : 0;
    int bucket;
    if (n < 8) {
      bucket = ret + n;
    } else {
      int large = 8 + (int)(logf((float)n / 8.0f) / logf(16.0f) * 8.0f);
      if (large > 15) large = 15;
      bucket = ret + large;
    }
#pragma unroll
    for (int h = 0; h < 16; ++h)
      bias_hd[h * 2056 + idx] = f2bf(rel_emb[bucket * 16 + h] * LOG2E);
  }
}

// ---------------- fused QKV projection GEMM (dbuf DMA, 1 barrier/kt) ----------------
__global__ __launch_bounds__(256, 3) void qkv_gemm_kernel(
    const unsigned short* __restrict__ A, const unsigned short* __restrict__ Wq,
    const unsigned short* __restrict__ Wk, const unsigned short* __restrict__ Wv,
    const float* __restrict__ qb, const float* __restrict__ kb, const float* __restrict__ vb,
    unsigned short* __restrict__ qh,   // (B,H,S,D) scaled q
    unsigned short* __restrict__ kh,   // (B,H,S,D)
    unsigned short* __restrict__ vT)   // (B,H,D,S)
{
  __shared__ __align__(16) char smem[32768];
  const int tid = threadIdx.x, lane = tid & 63;
  const int wv_ = tid >> 6;
  const int nt = blockIdx.x;
  const int mt = blockIdx.y;
  const int mat = nt >> 3;
  const unsigned short* W = mat == 0 ? Wq : (mat == 1 ? Wk : Wv);
  const int n0 = (nt & 7) * 128;
  const int m0 = mt * 128;
  const int moff = (wv_ & 1) * 64;
  const int noff = (wv_ >> 1) * 64;

  f32x4 acc[4][4] = {};
  const char* Ab = (const char*)A;
  const char* Wb = (const char*)W;

  int st_row[2], st_g[2];
#pragma unroll
  for (int c = 0; c < 2; ++c) {
    int o = c * 4096 + tid * 16;
    int row = o >> 6, p = (o >> 4) & 3;
    st_row[c] = row;
    st_g[c] = p ^ swz(row);
  }

#define QKV_STAGE(kt, buf)                                                     \
  {                                                                            \
    char* bb = smem + (buf)*16384;                                             \
    _Pragma("unroll") for (int c = 0; c < 2; ++c) {                            \
      int o = c * 4096 + tid * 16;                                             \
      size_t ga = (size_t)(m0 + st_row[c]) * 2048 + (size_t)(kt)*64 + st_g[c] * 16; \
      size_t gb = (size_t)(n0 + st_row[c]) * 2048 + (size_t)(kt)*64 + st_g[c] * 16; \
      gload_lds16(Ab + ga, bb + o);                                            \
      gload_lds16(Wb + gb, bb + 8192 + o);                                     \
    }                                                                          \
  }

  QKV_STAGE(0, 0);
  for (int kt = 0; kt < 32; ++kt) {
    __syncthreads();
    const char* base = smem + (kt & 1) * 16384;
    if (kt < 31) QKV_STAGE(kt + 1, (kt + 1) & 1);

    bf16x8 af[4], bfr[4];
#pragma unroll
    for (int i = 0; i < 4; ++i) {
      int ra = moff + i * 16 + (lane & 15);
      int rb = noff + i * 16 + (lane & 15);
      int q = lane >> 4;
      af[i] = *(const bf16x8*)(base + ra * 64 + (q ^ swz(ra)) * 16);
      bfr[i] = *(const bf16x8*)(base + 8192 + rb * 64 + (q ^ swz(rb)) * 16);
    }
#pragma unroll
    for (int i = 0; i < 4; ++i)
#pragma unroll
      for (int j = 0; j < 4; ++j) acc[i][j] = MFMA_BF16(af[i], bfr[j], acc[i][j]);
  }
#undef QKV_STAGE

  const int bidx = m0 >> 10;
  const int s00 = (m0 & 1023) + moff + ((lane >> 4) << 2);
  const int c0 = n0 + noff + (lane & 15);
  if (mat < 2) {
    const float* barr = mat == 0 ? qb : kb;
    unsigned short* dst = mat == 0 ? qh : kh;
    const float scale = mat == 0 ? (0.125f * LOG2E) : 1.0f;
#pragma unroll
    for (int j = 0; j < 4; ++j) {
      int col = c0 + j * 16;
      int hh = col >> 6, dd = col & 63;
      float bias = barr[col];
#pragma unroll
      for (int i = 0; i < 4; ++i)
#pragma unroll
        for (int r = 0; r < 4; ++r) {
          int s = s00 + i * 16 + r;
          dst[((size_t)(bidx * 16 + hh) * 1024 + s) * 64 + dd] =
              f2bf((acc[i][j][r] + bias) * scale);
        }
    }
  } else {
#pragma unroll
    for (int j = 0; j < 4; ++j) {
      int col = c0 + j * 16;
      int hh = col >> 6, dd = col & 63;
      float bias = vb[col];
#pragma unroll
      for (int i = 0; i < 4; ++i) {
        int s = s00 + i * 16;
        ushort4 pk;
        pk.x = f2bf(acc[i][j][0] + bias);
        pk.y = f2bf(acc[i][j][1] + bias);
        pk.z = f2bf(acc[i][j][2] + bias);
        pk.w = f2bf(acc[i][j][3] + bias);
        *(ushort4*)&vT[((size_t)(bidx * 16 + hh) * 64 + dd) * 1024 + s] = pk;
      }
    }
  }
}

// ---------------- gate kernel ----------------
__global__ __launch_bounds__(256) void gate_kernel(const unsigned short* __restrict__ qh,
                                                   const float* __restrict__ grep_w,
                                                   const float* __restrict__ grep_b,
                                                   const float* __restrict__ grep_a,
                                                   float* __restrict__ gate) {
  __shared__ float gw[512];
  __shared__ float gbb[8];
  __shared__ float gaa[16];
  int tid = threadIdx.x;
  for (int i = tid; i < 512; i += 256) gw[i] = grep_w[i];
  if (tid < 8) gbb[tid] = grep_b[tid];
  if (tid < 16) gaa[tid] = grep_a[tid];
  __syncthreads();
  int idx = blockIdx.x * 256 + tid;  // bh*1024 + s
  int h = (idx >> 10) & 15;
  const unsigned short* qrow = qh + (size_t)idx * 64;
  float a[8] = {0.f, 0.f, 0.f, 0.f, 0.f, 0.f, 0.f, 0.f};
#pragma unroll
  for (int c = 0; c < 8; ++c) {
    bf16x8 v = *(const bf16x8*)(qrow + c * 8);
#pragma unroll
    for (int jj = 0; jj < 8; ++jj) {
      float qv = bf2f((unsigned short)v[jj]);
      int d = c * 8 + jj;
#pragma unroll
      for (int e = 0; e < 8; ++e) a[e] += qv * gw[e * 64 + d];
    }
  }
  float sa = (a[0] + a[1] + a[2] + a[3]) * LN2 + gbb[0] + gbb[1] + gbb[2] + gbb[3];
  float sb = (a[4] + a[5] + a[6] + a[7]) * LN2 + gbb[4] + gbb[5] + gbb[6] + gbb[7];
  float siga = 1.f / (1.f + __expf(-sa));
  float sigb = 1.f / (1.f + __expf(-sb));
  gate[idx] = siga * (sigb * gaa[h] - 1.f) + 2.f;
}

// ---------------- flash attention v4: 32x32 MFMA, key-split wave pairs ----------------
// 512 threads = 8 waves = 4 q-tiles x 2 key-halves. Wave (qt,khalf) computes
// S^T = K Q^T for 32 q x its 32-key half per 64-key chunk (16 scores/lane on
// mfma_32x32x16: col=q31, row=(reg&3)+8*(reg>>2)+4*hb). Static softmax (exp2,
// log2e pre-folded) is additive across the key split: O and l are plain sums,
// combined once in the epilogue (kh0 writes raw, kh1 adds+normalizes; l rides
// Ot's slack column). Ps rows: 128B stride, 4 data chunks XOR-spread over 8
// slots -> bank-aligned pure-XOR, 2-way max (free). 16 waves/CU (2 blocks).
__global__ __launch_bounds__(512, 4) void attn_kernel(
    const unsigned short* __restrict__ qh, const unsigned short* __restrict__ kh,
    const unsigned short* __restrict__ vT, const float* __restrict__ gate,
    const unsigned short* __restrict__ bias_hd, unsigned short* __restrict__ ctx) {
  // LDS: K dbuf [0,16K) V dbuf [16K,32K) Ps [32K,64K) bias c0 [65536,+2304) c1 [67840,+2304)
  // epilogue reuses [0,34816) as Ot fp32[128][68] (col 64 = l partial)
  __shared__ __align__(16) char smem[70144];
  const int tid = threadIdx.x, lane = tid & 63, w = tid >> 6;
  const int qt = w >> 1, khalf = w & 1;
  const int bh = blockIdx.x;  // b*16+h
  const int h = bh & 15;
  const int qs0 = blockIdx.y * 128;
  const int q31 = lane & 31, hb = lane >> 5, q7 = q31 & 7;
  const int sq = qs0 + qt * 32 + q31;

  // bias windows: W[i] = bias[h][896-qs0+i] (bf16), copy1 shifted by +1
  unsigned short* bc0 = (unsigned short*)(smem + 65536);
  unsigned short* bc1 = (unsigned short*)(smem + 67840);
  {
    const unsigned short* gb = bias_hd + h * 2056 + (896 - qs0);
    for (int i = tid; i < 1152; i += 512) {
      bc0[i] = gb[i];
      bc1[i] = gb[i + 1];
    }
  }

  const char* kbase = (const char*)(kh + (size_t)bh * 65536);
  const char* vbase = (const char*)(vT + (size_t)bh * 65536);

  // staging: 512 threads x 16B = one full 8KB tile per instruction
  const int o = tid * 16;
  const int srow = o >> 7;
  const int sg = ((o >> 4) & 7) ^ (srow & 7);
  const size_t koff = (size_t)srow * 128 + sg * 16;
  const size_t voff = (size_t)srow * 2048 + sg * 16;

  gload_lds16(kbase + koff, smem + o);
  gload_lds16(vbase + voff, smem + 16384 + o);

  // Q B-frags: B[k=d][n=q]: n=q31, k = hb*8 + j within each 16-d chunk
  const unsigned short* qrow = qh + ((size_t)bh * 1024 + sq) * 64 + hb * 8;
  bf16x8 qf[4];
#pragma unroll
  for (int dc = 0; dc < 4; ++dc) qf[dc] = *(const bf16x8*)(qrow + dc * 16);

  const float gate_lane = gate[bh * 1024 + sq];

  // bias parity select (qt*32 even -> par depends only on q31)
  const int par = (127 - q31) & 1;
  const unsigned int* bp = (const unsigned int*)(par ? bc1 : bc0);
  const int bbase0 = (qs0 + 127 - sq - par) >> 1;  // even numerator, >= 0

  // per-q P^T row: 128B stride, 4 data chunks XOR-spread over 8 slots
  char* psrow = smem + 32768 + (w * 32 + q31) * 128;

  float l_run = 0.f;
  f32x16 accO0 = {}, accO1 = {};

  for (int kc = 0; kc < 16; ++kc) {
    __syncthreads();  // current buffer's DMA landed; previous buffer free
    const char* Kc = smem + (kc & 1) * 8192;
    const char* Vc = smem + 16384 + (kc & 1) * 8192;
    if (kc < 15) {
      int nb = (kc + 1) & 1;
      gload_lds16(kbase + (size_t)(kc + 1) * 8192 + koff, smem + nb * 8192 + o);
      gload_lds16(vbase + (size_t)(kc + 1) * 128 + voff, smem + 16384 + nb * 8192 + o);
    }

    // ---- S^T = K Q^T : wave's 32-key half x 32 q, k over d=64 in 4 chunks ----
    f32x16 sac = {};
    const char* Krow = Kc + (khalf * 32 + q31) * 128;  // (khalf*32+q31)&7 == q7
#pragma unroll
    for (int ks = 0; ks < 4; ++ks) {
      bf16x8 kf = *(const bf16x8*)(Krow + (((ks * 2 + hb) ^ q7) << 4));
      sac = MFMA32_BF16(kf, qf[ks], sac);
    }

    // ---- bias + exp2 + pack P (4 runs of 4 consecutive keys) ----
    float ps = 0.f;
#pragma unroll
    for (int rg = 0; rg < 4; ++rg) {
      int idx = bbase0 + ((kc * 64 + khalf * 32 + rg * 8 + hb * 4) >> 1);
      unsigned u0 = bp[idx], u1 = bp[idx + 1];
      float p0 = __builtin_exp2f(__builtin_fmaf(gate_lane, u32lo_bf(u0), sac[rg * 4 + 0]));
      float p1 = __builtin_exp2f(__builtin_fmaf(gate_lane, u32hi_bf(u0), sac[rg * 4 + 1]));
      float p2 = __builtin_exp2f(__builtin_fmaf(gate_lane, u32lo_bf(u1), sac[rg * 4 + 2]));
      float p3 = __builtin_exp2f(__builtin_fmaf(gate_lane, u32hi_bf(u1), sac[rg * 4 + 3]));
      ps += (p0 + p1) + (p2 + p3);
      ushort4 pk;
      pk.x = f2bf(p0); pk.y = f2bf(p1); pk.z = f2bf(p2); pk.w = f2bf(p3);
      *(ushort4*)(psrow + ((rg ^ q7) << 4) + hb * 8) = pk;  // chunk rg, half hb
    }
    l_run += ps;

    // ---- O^T += V^T P^T over the wave's 32 keys (2 k-chunks of 16) ----
#pragma unroll
    for (int mf = 0; mf < 2; ++mf) {
      bf16x8 pb = *(const bf16x8*)(psrow + (((mf * 2 + hb) ^ q7) << 4));
      int vch = ((khalf * 4 + mf * 2 + hb) ^ q7) << 4;
      bf16x8 v0f = *(const bf16x8*)(Vc + q31 * 128 + vch);
      bf16x8 v1f = *(const bf16x8*)(Vc + (32 + q31) * 128 + vch);
      accO0 = MFMA32_BF16(v0f, pb, accO0);
      accO1 = MFMA32_BF16(v1f, pb, accO1);
    }
  }

  // combine hb halves (keys interleave mod 8 within the wave's half)
  l_run += __shfl_xor(l_run, 32, 64);

  // ---- epilogue: cross-wave combine + transpose + dense f16 stores ----
  __syncthreads();  // all frag reads done; smem[0,35K) reusable as Ot
  float* Ot = (float*)smem;  // [128][68], col 64 holds kh0's l
  float* ow = Ot + (qt * 32 + q31) * 68;
  if (khalf == 0) {
#pragma unroll
    for (int rr = 0; rr < 16; ++rr) {
      int d = (rr & 3) + 8 * (rr >> 2) + 4 * hb;
      ow[d] = accO0[rr];
      ow[32 + d] = accO1[rr];
    }
    if (hb == 0) ow[64] = l_run;
  }
  __syncthreads();
  if (khalf == 1) {
    float inv = 1.0f / (ow[64] + l_run);
#pragma unroll
    for (int rr = 0; rr < 16; ++rr) {
      int d = (rr & 3) + 8 * (rr >> 2) + 4 * hb;
      ow[d] = (ow[d] + accO0[rr]) * inv;
      ow[32 + d] = (ow[32 + d] + accO1[rr]) * inv;
    }
  }
  __syncthreads();
  {
    int row = tid >> 2, dg = tid & 3;  // 128 rows x 4 d-groups of 16
    int s = qs0 + row;
    const float* src = Ot + row * 68 + dg * 16;
    unsigned short hbuf[16];
#pragma unroll
    for (int j = 0; j < 16; ++j) hbuf[j] = f2h(src[j]);
    size_t base = (size_t)(s * 4 + (bh >> 4)) * 1024 + h * 64 + dg * 16;
    *(uint4*)(ctx + base) = *(const uint4*)(hbuf);
    *(uint4*)(ctx + base + 8) = *(const uint4*)(hbuf + 8);
  }
}

// ---------------- output projection: single f16 GEMM, 64x128 tiles, dbuf DMA ----------------
__global__ __launch_bounds__(256, 3) void outproj_kernel(
    const unsigned short* __restrict__ Af,  // ctx f16 (4096,1024)
    const unsigned short* __restrict__ Bf,  // out_w f16 (1024,1024)
    const float* __restrict__ ob, float* __restrict__ out) {
  // per-buffer: A 4K + B 8K = 12K; x2 = 24K
  __shared__ __align__(16) char smem[24576];
  const int tid = threadIdx.x, lane = tid & 63, wv_ = tid >> 6;
  const int q15 = lane & 15, quad = lane >> 4;
  const int n0 = blockIdx.x * 128;
  const int m0 = blockIdx.y * 64;
  const int moff = (wv_ & 1) * 32;
  const int noff = (wv_ >> 1) * 64;

  const int oa = tid * 16;
  const int ra_ = oa >> 6;
  const int ga_ = (((oa >> 4) & 3) ^ swz(ra_)) << 4;
  int rb_[2], gb_[2], obo_[2];
#pragma unroll
  for (int c = 0; c < 2; ++c) {
    int ob2 = c * 4096 + tid * 16;
    obo_[c] = ob2;
    rb_[c] = ob2 >> 6;
    gb_[c] = (((ob2 >> 4) & 3) ^ swz(rb_[c])) << 4;
  }

#define OP_STAGE(kt, buf)                                                        \
  {                                                                              \
    char* bb = smem + (buf)*12288;                                               \
    size_t ga = (size_t)(m0 + ra_) * 2048 + (size_t)(kt)*64 + ga_;               \
    gload_lds16((const char*)Af + ga, bb + oa);                                  \
    _Pragma("unroll") for (int c = 0; c < 2; ++c) {                              \
      size_t gb = (size_t)(n0 + rb_[c]) * 2048 + (size_t)(kt)*64 + gb_[c];       \
      gload_lds16((const char*)Bf + gb, bb + 4096 + obo_[c]);                    \
    }                                                                            \
  }

  f32x4 acc[2][4] = {};
  OP_STAGE(0, 0);
  for (int kt = 0; kt < 32; ++kt) {
    __syncthreads();
    const char* base = smem + (kt & 1) * 12288;
    if (kt < 31) OP_STAGE(kt + 1, (kt + 1) & 1);

    f16x8 ah[2], bhf[4];
#pragma unroll
    for (int i = 0; i < 2; ++i) {
      int ra = moff + i * 16 + q15;
      ah[i] = *(const f16x8*)(base + ra * 64 + ((quad ^ swz(ra)) << 4));
    }
#pragma unroll
    for (int j = 0; j < 4; ++j) {
      int rb = noff + j * 16 + q15;
      bhf[j] = *(const f16x8*)(base + 4096 + rb * 64 + ((quad ^ swz(rb)) << 4));
    }
#pragma unroll
    for (int i = 0; i < 2; ++i)
#pragma unroll
      for (int j = 0; j < 4; ++j) acc[i][j] = MFMA_F16(ah[i], bhf[j], acc[i][j]);
  }
#undef OP_STAGE

  const int rr0 = m0 + moff + (quad << 2);
  const int c0 = n0 + noff + q15;
#pragma unroll
  for (int j = 0; j < 4; ++j) {
    int col = c0 + j * 16;
    float bias = ob[col];
#pragma unroll
    for (int i = 0; i < 2; ++i)
#pragma unroll
      for (int r = 0; r < 4; ++r)
        out[(size_t)(rr0 + i * 16 + r) * 1024 + col] = acc[i][j][r] + bias;
  }
}

// ---------------- launcher ----------------
extern "C" void kernel_launch(void* const* d_in, const int* in_sizes, int n_in,
                              void* d_out, int out_size, void* d_ws, size_t ws_size,
                              hipStream_t stream) {
  const float* query = (const float*)d_in[0];
  const float* q_w = (const float*)d_in[1];
  const float* q_b = (const float*)d_in[2];
  const float* k_w = (const float*)d_in[3];
  const float* k_b = (const float*)d_in[4];
  const float* v_w = (const float*)d_in[5];
  const float* v_b = (const float*)d_in[6];
  const float* out_w = (const float*)d_in[7];
  const float* out_b = (const float*)d_in[8];
  const float* rel_emb = (const float*)d_in[9];
  const float* grep_w = (const float*)d_in[10];
  const float* grep_b = (const float*)d_in[11];
  const float* grep_a = (const float*)d_in[12];
  float* out = (float*)d_out;

  const size_t MB = 1u << 20;
  char* ws = (char*)d_ws;
  unsigned short* q_bf = (unsigned short*)(ws);            // (B,S,E) bf16, 8 MB
  unsigned short* wq_bf = (unsigned short*)(ws + 8 * MB);
  unsigned short* wk_bf = (unsigned short*)(ws + 10 * MB);
  unsigned short* wv_bf = (unsigned short*)(ws + 12 * MB);
  unsigned short* ow_h = (unsigned short*)(ws + 14 * MB);  // f16
  unsigned short* qhp = (unsigned short*)(ws + 16 * MB);   // (B,H,S,D)
  unsigned short* khp = (unsigned short*)(ws + 24 * MB);   // (B,H,S,D)
  unsigned short* vTp = (unsigned short*)(ws + 32 * MB);   // (B,H,D,S)
  unsigned short* ctxp = (unsigned short*)(ws + 40 * MB);  // (S*B,E) f16
  float* gatep = (float*)(ws + 48 * MB);
  unsigned short* biasp = (unsigned short*)(ws + 48 * MB + 256 * 1024);  // bf16 16x2056

  prep_kernel<<<20489, 256, 0, stream>>>(query, q_w, k_w, v_w, out_w, rel_emb, q_bf, wq_bf,
                                         wk_bf, wv_bf, ow_h, biasp);
  qkv_gemm_kernel<<<dim3(24, 32), 256, 0, stream>>>(q_bf, wq_bf, wk_bf, wv_bf, q_b, k_b, v_b,
                                                    qhp, khp, vTp);
  gate_kernel<<<256, 256, 0, stream>>>(qhp, grep_w, grep_b, grep_a, gatep);
  attn_kernel<<<dim3(64, 8), 512, 0, stream>>>(qhp, khp, vTp, gatep, biasp, ctxp);
  outproj_kernel<<<dim3(8, 64), 256, 0, stream>>>(ctxp, ow_h, out_b, out);
}

// Round 10
// 191.919 us; speedup vs baseline: 2.3654x; 1.0064x over previous
//
#include <hip/hip_runtime.h>
#include <hip/hip_bf16.h>
#include <stdint.h>

// Problem dims (fixed): S=1024, B=4, E=1024, H=16, D=64, M=S*B=4096
// scaling = D^-0.5 = 0.125; log2e folded into q-scale and bias table so the
// attention softmax uses raw exp2.

typedef short bf16x8 __attribute__((ext_vector_type(8)));
typedef _Float16 f16x8 __attribute__((ext_vector_type(8)));
typedef float f32x4 __attribute__((ext_vector_type(4)));
typedef float f32x16 __attribute__((ext_vector_type(16)));

#define MFMA_BF16(a, b, c) __builtin_amdgcn_mfma_f32_16x16x32_bf16((a), (b), (c), 0, 0, 0)
#define MFMA_F16(a, b, c) __builtin_amdgcn_mfma_f32_16x16x32_f16((a), (b), (c), 0, 0, 0)
#define MFMA32_BF16(a, b, c) __builtin_amdgcn_mfma_f32_32x32x16_bf16((a), (b), (c), 0, 0, 0)

#define LOG2E 1.44269504088896f
#define LN2 0.693147180559945f

__device__ __forceinline__ unsigned short f2bf(float x) {
  union { float f; unsigned u; } v; v.f = x;
  unsigned r = v.u + 0x7fffu + ((v.u >> 16) & 1u);  // RNE
  return (unsigned short)(r >> 16);
}
__device__ __forceinline__ float bf2f(unsigned short u) {
  union { unsigned u; float f; } v; v.u = ((unsigned)u) << 16;
  return v.f;
}
__device__ __forceinline__ unsigned short f2h(float x) {  // RNE via v_cvt_f16_f32
  union { _Float16 h; unsigned short u; } v; v.h = (_Float16)x;
  return v.u;
}
__device__ __forceinline__ float u32lo_bf(unsigned u) {
  union { unsigned u; float f; } v; v.u = u << 16;
  return v.f;
}
__device__ __forceinline__ float u32hi_bf(unsigned u) {
  union { unsigned u; float f; } v; v.u = u & 0xffff0000u;
  return v.f;
}
// pack 2 fp32 -> 2 bf16 (RNE) in one u32 (v_cvt_pk_bf16_f32 on gfx950)
__device__ __forceinline__ unsigned pk_bf2(float a, float b) {
  union { __hip_bfloat162 h2; unsigned u; } v;
  v.h2 = __float22bfloat162_rn(float2{a, b});
  return v.u;
}

// async global->LDS 16B: lane's data lands at (wave-uniform base) + lane*16.
__device__ __forceinline__ void gload_lds16(const void* g, void* l) {
  __builtin_amdgcn_global_load_lds(
      (const __attribute__((address_space(1))) unsigned int*)g,
      (__attribute__((address_space(3))) unsigned int*)l, 16, 0, 0);
}

// LDS chunk swizzle for 64B rows (4 chunks of 16B)
__device__ __forceinline__ int swz(int row) { return (row ^ (row >> 2)) & 3; }

// ---------------- fused prep: query cvt/transpose + weight prep + relbias ----------------
__global__ __launch_bounds__(256) void prep_kernel(
    const float* __restrict__ query, const float* __restrict__ q_w,
    const float* __restrict__ k_w, const float* __restrict__ v_w,
    const float* __restrict__ out_w, const float* __restrict__ rel_emb,
    unsigned short* __restrict__ q_bf, unsigned short* __restrict__ wq,
    unsigned short* __restrict__ wk, unsigned short* __restrict__ wv,
    unsigned short* __restrict__ ow_h,       // f16 out_w
    unsigned short* __restrict__ bias_hd) {  // bf16, 16 x 2056 (last 9 zero-padded)
  int i = blockIdx.x * 256 + threadIdx.x;
  if (i < 4194304) {
    int e = i & 1023;
    int sb = i >> 10;
    int s = sb >> 2, b = sb & 3;
    q_bf[((size_t)(b * 1024 + s) << 10) | e] = f2bf(query[i]);
  } else if (i < 5242880) {
    int j = i - 4194304;  // < 1M
    wq[j] = f2bf(q_w[j]);
    wk[j] = f2bf(k_w[j]);
    wv[j] = f2bf(v_w[j]);
    ow_h[j] = f2h(out_w[j]);
  } else {
    int idx = i - 5242880;
    if (idx >= 2056) return;
    if (idx >= 2047) {
#pragma unroll
      for (int h = 0; h < 16; ++h) bias_hd[h * 2056 + idx] = 0;
      return;
    }
    int rel = idx - 1023;
    int n = rel < 0 ? -rel : rel;
    int ret = rel > 0 ? 16 : 0;
    int bucket;
    if (n < 8) {
      bucket = ret + n;
    } else {
      int large = 8 + (int)(logf((float)n / 8.0f) / logf(16.0f) * 8.0f);
      if (large > 15) large = 15;
      bucket = ret + large;
    }
#pragma unroll
    for (int h = 0; h < 16; ++h)
      bias_hd[h * 2056 + idx] = f2bf(rel_emb[bucket * 16 + h] * LOG2E);
  }
}

// ---------------- fused QKV projection GEMM (dbuf DMA, 1 barrier/kt) ----------------
__global__ __launch_bounds__(256, 3) void qkv_gemm_kernel(
    const unsigned short* __restrict__ A, const unsigned short* __restrict__ Wq,
    const unsigned short* __restrict__ Wk, const unsigned short* __restrict__ Wv,
    const float* __restrict__ qb, const float* __restrict__ kb, const float* __restrict__ vb,
    unsigned short* __restrict__ qh,   // (B,H,S,D) scaled q
    unsigned short* __restrict__ kh,   // (B,H,S,D)
    unsigned short* __restrict__ vT)   // (B,H,D,S)
{
  __shared__ __align__(16) char smem[32768];
  const int tid = threadIdx.x, lane = tid & 63;
  const int wv_ = tid >> 6;
  const int nt = blockIdx.x;
  const int mt = blockIdx.y;
  const int mat = nt >> 3;
  const unsigned short* W = mat == 0 ? Wq : (mat == 1 ? Wk : Wv);
  const int n0 = (nt & 7) * 128;
  const int m0 = mt * 128;
  const int moff = (wv_ & 1) * 64;
  const int noff = (wv_ >> 1) * 64;

  f32x4 acc[4][4] = {};
  const char* Ab = (const char*)A;
  const char* Wb = (const char*)W;

  int st_row[2], st_g[2];
#pragma unroll
  for (int c = 0; c < 2; ++c) {
    int o = c * 4096 + tid * 16;
    int row = o >> 6, p = (o >> 4) & 3;
    st_row[c] = row;
    st_g[c] = p ^ swz(row);
  }

#define QKV_STAGE(kt, buf)                                                     \
  {                                                                            \
    char* bb = smem + (buf)*16384;                                             \
    _Pragma("unroll") for (int c = 0; c < 2; ++c) {                            \
      int o = c * 4096 + tid * 16;                                             \
      size_t ga = (size_t)(m0 + st_row[c]) * 2048 + (size_t)(kt)*64 + st_g[c] * 16; \
      size_t gb = (size_t)(n0 + st_row[c]) * 2048 + (size_t)(kt)*64 + st_g[c] * 16; \
      gload_lds16(Ab + ga, bb + o);                                            \
      gload_lds16(Wb + gb, bb + 8192 + o);                                     \
    }                                                                          \
  }

  QKV_STAGE(0, 0);
  for (int kt = 0; kt < 32; ++kt) {
    __syncthreads();
    const char* base = smem + (kt & 1) * 16384;
    if (kt < 31) QKV_STAGE(kt + 1, (kt + 1) & 1);

    bf16x8 af[4], bfr[4];
#pragma unroll
    for (int i = 0; i < 4; ++i) {
      int ra = moff + i * 16 + (lane & 15);
      int rb = noff + i * 16 + (lane & 15);
      int q = lane >> 4;
      af[i] = *(const bf16x8*)(base + ra * 64 + (q ^ swz(ra)) * 16);
      bfr[i] = *(const bf16x8*)(base + 8192 + rb * 64 + (q ^ swz(rb)) * 16);
    }
#pragma unroll
    for (int i = 0; i < 4; ++i)
#pragma unroll
      for (int j = 0; j < 4; ++j) acc[i][j] = MFMA_BF16(af[i], bfr[j], acc[i][j]);
  }
#undef QKV_STAGE

  const int bidx = m0 >> 10;
  const int s00 = (m0 & 1023) + moff + ((lane >> 4) << 2);
  const int c0 = n0 + noff + (lane & 15);
  if (mat < 2) {
    const float* barr = mat == 0 ? qb : kb;
    unsigned short* dst = mat == 0 ? qh : kh;
    const float scale = mat == 0 ? (0.125f * LOG2E) : 1.0f;
#pragma unroll
    for (int j = 0; j < 4; ++j) {
      int col = c0 + j * 16;
      int hh = col >> 6, dd = col & 63;
      float bias = barr[col];
#pragma unroll
      for (int i = 0; i < 4; ++i)
#pragma unroll
        for (int r = 0; r < 4; ++r) {
          int s = s00 + i * 16 + r;
          dst[((size_t)(bidx * 16 + hh) * 1024 + s) * 64 + dd] =
              f2bf((acc[i][j][r] + bias) * scale);
        }
    }
  } else {
#pragma unroll
    for (int j = 0; j < 4; ++j) {
      int col = c0 + j * 16;
      int hh = col >> 6, dd = col & 63;
      float bias = vb[col];
#pragma unroll
      for (int i = 0; i < 4; ++i) {
        int s = s00 + i * 16;
        ushort4 pk;
        pk.x = f2bf(acc[i][j][0] + bias);
        pk.y = f2bf(acc[i][j][1] + bias);
        pk.z = f2bf(acc[i][j][2] + bias);
        pk.w = f2bf(acc[i][j][3] + bias);
        *(ushort4*)&vT[((size_t)(bidx * 16 + hh) * 64 + dd) * 1024 + s] = pk;
      }
    }
  }
}

// ---------------- gate kernel ----------------
__global__ __launch_bounds__(256) void gate_kernel(const unsigned short* __restrict__ qh,
                                                   const float* __restrict__ grep_w,
                                                   const float* __restrict__ grep_b,
                                                   const float* __restrict__ grep_a,
                                                   float* __restrict__ gate) {
  __shared__ float gw[512];
  __shared__ float gbb[8];
  __shared__ float gaa[16];
  int tid = threadIdx.x;
  for (int i = tid; i < 512; i += 256) gw[i] = grep_w[i];
  if (tid < 8) gbb[tid] = grep_b[tid];
  if (tid < 16) gaa[tid] = grep_a[tid];
  __syncthreads();
  int idx = blockIdx.x * 256 + tid;  // bh*1024 + s
  int h = (idx >> 10) & 15;
  const unsigned short* qrow = qh + (size_t)idx * 64;
  float a[8] = {0.f, 0.f, 0.f, 0.f, 0.f, 0.f, 0.f, 0.f};
#pragma unroll
  for (int c = 0; c < 8; ++c) {
    bf16x8 v = *(const bf16x8*)(qrow + c * 8);
#pragma unroll
    for (int jj = 0; jj < 8; ++jj) {
      float qv = bf2f((unsigned short)v[jj]);
      int d = c * 8 + jj;
#pragma unroll
      for (int e = 0; e < 8; ++e) a[e] += qv * gw[e * 64 + d];
    }
  }
  float sa = (a[0] + a[1] + a[2] + a[3]) * LN2 + gbb[0] + gbb[1] + gbb[2] + gbb[3];
  float sb = (a[4] + a[5] + a[6] + a[7]) * LN2 + gbb[4] + gbb[5] + gbb[6] + gbb[7];
  float siga = 1.f / (1.f + __expf(-sa));
  float sigb = 1.f / (1.f + __expf(-sb));
  gate[idx] = siga * (sigb * gaa[h] - 1.f) + 2.f;
}

// ---------------- flash attention v5: key-split wave pairs, register P transform ----
// R10: Ps LDS round-trip removed. P^T C->B transform done in-register: lane
// (q31,hb) holds keys {8rg+4hb+r}; PV B chunk m needs keys 16m+8hb+j — a
// half-wave exchange of 2 pair-regs per chunk via __shfl_xor(..,32)
// (ds_bpermute, conflict-free) + selects. Frees 32KB LDS -> 37.9KB/block ->
// 4 blocks/CU (32 waves). Epilogue Ot stride 68 -> 65 floats (bank=(q31+d)%32:
// writes conflict-free, scalar reads 2-way=free). P packed via
// v_cvt_pk_bf16_f32.
__global__ __launch_bounds__(512, 4) void attn_kernel(
    const unsigned short* __restrict__ qh, const unsigned short* __restrict__ kh,
    const unsigned short* __restrict__ vT, const float* __restrict__ gate,
    const unsigned short* __restrict__ bias_hd, unsigned short* __restrict__ ctx) {
  // LDS: K dbuf [0,16K) V dbuf [16K,32K) bias c0 [33280,+2304) c1 [35584,+2304)
  // epilogue reuses [0,33280) as Ot fp32[128][65] (col 64 = l partial)
  __shared__ __align__(16) char smem[37888];
  const int tid = threadIdx.x, lane = tid & 63, w = tid >> 6;
  const int qt = w >> 1, khalf = w & 1;
  const int bh = blockIdx.x;  // b*16+h
  const int h = bh & 15;
  const int qs0 = blockIdx.y * 128;
  const int q31 = lane & 31, hb = lane >> 5, q7 = q31 & 7;
  const int sq = qs0 + qt * 32 + q31;

  // bias windows: W[i] = bias[h][896-qs0+i] (bf16), copy1 shifted by +1
  unsigned short* bc0 = (unsigned short*)(smem + 33280);
  unsigned short* bc1 = (unsigned short*)(smem + 35584);
  {
    const unsigned short* gb = bias_hd + h * 2056 + (896 - qs0);
    for (int i = tid; i < 1152; i += 512) {
      bc0[i] = gb[i];
      bc1[i] = gb[i + 1];
    }
  }

  const char* kbase = (const char*)(kh + (size_t)bh * 65536);
  const char* vbase = (const char*)(vT + (size_t)bh * 65536);

  // staging: 512 threads x 16B = one full 8KB tile per instruction
  const int o = tid * 16;
  const int srow = o >> 7;
  const int sg = ((o >> 4) & 7) ^ (srow & 7);
  const size_t koff = (size_t)srow * 128 + sg * 16;
  const size_t voff = (size_t)srow * 2048 + sg * 16;

  gload_lds16(kbase + koff, smem + o);
  gload_lds16(vbase + voff, smem + 16384 + o);

  // Q B-frags: B[k=d][n=q]: n=q31, k = hb*8 + j within each 16-d chunk
  const unsigned short* qrow = qh + ((size_t)bh * 1024 + sq) * 64 + hb * 8;
  bf16x8 qf[4];
#pragma unroll
  for (int dc = 0; dc < 4; ++dc) qf[dc] = *(const bf16x8*)(qrow + dc * 16);

  const float gate_lane = gate[bh * 1024 + sq];

  // bias parity select (qt*32 even -> par depends only on q31)
  const int par = (127 - q31) & 1;
  const unsigned int* bp = (const unsigned int*)(par ? bc1 : bc0);
  const int bbase0 = (qs0 + 127 - sq - par) >> 1;  // even numerator, >= 0

  float l_run = 0.f;
  f32x16 accO0 = {}, accO1 = {};

  for (int kc = 0; kc < 16; ++kc) {
    __syncthreads();  // current buffer's DMA landed; previous buffer free
    const char* Kc = smem + (kc & 1) * 8192;
    const char* Vc = smem + 16384 + (kc & 1) * 8192;
    if (kc < 15) {
      int nb = (kc + 1) & 1;
      gload_lds16(kbase + (size_t)(kc + 1) * 8192 + koff, smem + nb * 8192 + o);
      gload_lds16(vbase + (size_t)(kc + 1) * 128 + voff, smem + 16384 + nb * 8192 + o);
    }

    // ---- S^T = K Q^T : wave's 32-key half x 32 q, k over d=64 in 4 chunks ----
    f32x16 sac = {};
    const char* Krow = Kc + (khalf * 32 + q31) * 128;  // (khalf*32+q31)&7 == q7
#pragma unroll
    for (int ks = 0; ks < 4; ++ks) {
      bf16x8 kf = *(const bf16x8*)(Krow + (((ks * 2 + hb) ^ q7) << 4));
      sac = MFMA32_BF16(kf, qf[ks], sac);
    }

    // ---- bias + exp2 + pack P pairs (lane keys: 8rg+4hb+r within half) ----
    float ps = 0.f;
    unsigned pu[8];
#pragma unroll
    for (int rg = 0; rg < 4; ++rg) {
      int idx = bbase0 + ((kc * 64 + khalf * 32 + rg * 8 + hb * 4) >> 1);
      unsigned u0 = bp[idx], u1 = bp[idx + 1];
      float p0 = __builtin_exp2f(__builtin_fmaf(gate_lane, u32lo_bf(u0), sac[rg * 4 + 0]));
      float p1 = __builtin_exp2f(__builtin_fmaf(gate_lane, u32hi_bf(u0), sac[rg * 4 + 1]));
      float p2 = __builtin_exp2f(__builtin_fmaf(gate_lane, u32lo_bf(u1), sac[rg * 4 + 2]));
      float p3 = __builtin_exp2f(__builtin_fmaf(gate_lane, u32hi_bf(u1), sac[rg * 4 + 3]));
      ps += (p0 + p1) + (p2 + p3);
      pu[2 * rg] = pk_bf2(p0, p1);
      pu[2 * rg + 1] = pk_bf2(p2, p3);
    }
    l_run += ps;

    // ---- C->B transform: half-wave exchange (keys 16m+8hb'+j per chunk) ----
    unsigned s0a = hb ? pu[0] : pu[2], s0b = hb ? pu[1] : pu[3];
    unsigned s1a = hb ? pu[4] : pu[6], s1b = hb ? pu[5] : pu[7];
    unsigned r0a = __shfl_xor((int)s0a, 32, 64);
    unsigned r0b = __shfl_xor((int)s0b, 32, 64);
    unsigned r1a = __shfl_xor((int)s1a, 32, 64);
    unsigned r1b = __shfl_xor((int)s1b, 32, 64);
    union PB { unsigned u[4]; bf16x8 v; } b0, b1;
    b0.u[0] = hb ? r0a : pu[0];
    b0.u[1] = hb ? r0b : pu[1];
    b0.u[2] = hb ? pu[2] : r0a;
    b0.u[3] = hb ? pu[3] : r0b;
    b1.u[0] = hb ? r1a : pu[4];
    b1.u[1] = hb ? r1b : pu[5];
    b1.u[2] = hb ? pu[6] : r1a;
    b1.u[3] = hb ? pu[7] : r1b;

    // ---- O^T += V^T P^T over the wave's 32 keys (2 k-chunks of 16) ----
#pragma unroll
    for (int mf = 0; mf < 2; ++mf) {
      bf16x8 pb = mf ? b1.v : b0.v;
      int vch = ((khalf * 4 + mf * 2 + hb) ^ q7) << 4;
      bf16x8 v0f = *(const bf16x8*)(Vc + q31 * 128 + vch);
      bf16x8 v1f = *(const bf16x8*)(Vc + (32 + q31) * 128 + vch);
      accO0 = MFMA32_BF16(v0f, pb, accO0);
      accO1 = MFMA32_BF16(v1f, pb, accO1);
    }
  }

  // combine hb halves (keys interleave mod 8 within the wave's half)
  l_run += __shfl_xor(l_run, 32, 64);

  // ---- epilogue: cross-wave combine + transpose + dense f16 stores ----
  __syncthreads();  // all frag reads done; smem[0,33280) reusable as Ot
  float* Ot = (float*)smem;  // [128][65], col 64 holds kh0's l
  float* ow = Ot + (qt * 32 + q31) * 65;
  if (khalf == 0) {
#pragma unroll
    for (int rr = 0; rr < 16; ++rr) {
      int d = (rr & 3) + 8 * (rr >> 2) + 4 * hb;
      ow[d] = accO0[rr];
      ow[32 + d] = accO1[rr];
    }
    if (hb == 0) ow[64] = l_run;
  }
  __syncthreads();
  if (khalf == 1) {
    float inv = 1.0f / (ow[64] + l_run);
#pragma unroll
    for (int rr = 0; rr < 16; ++rr) {
      int d = (rr & 3) + 8 * (rr >> 2) + 4 * hb;
      ow[d] = (ow[d] + accO0[rr]) * inv;
      ow[32 + d] = (ow[32 + d] + accO1[rr]) * inv;
    }
  }
  __syncthreads();
  {
    int row = tid >> 2, dg = tid & 3;  // 128 rows x 4 d-groups of 16
    int s = qs0 + row;
    const float* src = Ot + row * 65 + dg * 16;
    unsigned short hbuf[16];
#pragma unroll
    for (int j = 0; j < 16; ++j) hbuf[j] = f2h(src[j]);
    size_t base = (size_t)(s * 4 + (bh >> 4)) * 1024 + h * 64 + dg * 16;
    *(uint4*)(ctx + base) = *(const uint4*)(hbuf);
    *(uint4*)(ctx + base + 8) = *(const uint4*)(hbuf + 8);
  }
}

// ---------------- output projection: single f16 GEMM, 64x128 tiles, dbuf DMA ----------------
__global__ __launch_bounds__(256, 3) void outproj_kernel(
    const unsigned short* __restrict__ Af,  // ctx f16 (4096,1024)
    const unsigned short* __restrict__ Bf,  // out_w f16 (1024,1024)
    const float* __restrict__ ob, float* __restrict__ out) {
  // per-buffer: A 4K + B 8K = 12K; x2 = 24K
  __shared__ __align__(16) char smem[24576];
  const int tid = threadIdx.x, lane = tid & 63, wv_ = tid >> 6;
  const int q15 = lane & 15, quad = lane >> 4;
  const int n0 = blockIdx.x * 128;
  const int m0 = blockIdx.y * 64;
  const int moff = (wv_ & 1) * 32;
  const int noff = (wv_ >> 1) * 64;

  const int oa = tid * 16;
  const int ra_ = oa >> 6;
  const int ga_ = (((oa >> 4) & 3) ^ swz(ra_)) << 4;
  int rb_[2], gb_[2], obo_[2];
#pragma unroll
  for (int c = 0; c < 2; ++c) {
    int ob2 = c * 4096 + tid * 16;
    obo_[c] = ob2;
    rb_[c] = ob2 >> 6;
    gb_[c] = (((ob2 >> 4) & 3) ^ swz(rb_[c])) << 4;
  }

#define OP_STAGE(kt, buf)                                                        \
  {                                                                              \
    char* bb = smem + (buf)*12288;                                               \
    size_t ga = (size_t)(m0 + ra_) * 2048 + (size_t)(kt)*64 + ga_;               \
    gload_lds16((const char*)Af + ga, bb + oa);                                  \
    _Pragma("unroll") for (int c = 0; c < 2; ++c) {                              \
      size_t gb = (size_t)(n0 + rb_[c]) * 2048 + (size_t)(kt)*64 + gb_[c];       \
      gload_lds16((const char*)Bf + gb, bb + 4096 + obo_[c]);                    \
    }                                                                            \
  }

  f32x4 acc[2][4] = {};
  OP_STAGE(0, 0);
  for (int kt = 0; kt < 32; ++kt) {
    __syncthreads();
    const char* base = smem + (kt & 1) * 12288;
    if (kt < 31) OP_STAGE(kt + 1, (kt + 1) & 1);

    f16x8 ah[2], bhf[4];
#pragma unroll
    for (int i = 0; i < 2; ++i) {
      int ra = moff + i * 16 + q15;
      ah[i] = *(const f16x8*)(base + ra * 64 + ((quad ^ swz(ra)) << 4));
    }
#pragma unroll
    for (int j = 0; j < 4; ++j) {
      int rb = noff + j * 16 + q15;
      bhf[j] = *(const f16x8*)(base + 4096 + rb * 64 + ((quad ^ swz(rb)) << 4));
    }
#pragma unroll
    for (int i = 0; i < 2; ++i)
#pragma unroll
      for (int j = 0; j < 4; ++j) acc[i][j] = MFMA_F16(ah[i], bhf[j], acc[i][j]);
  }
#undef OP_STAGE

  const int rr0 = m0 + moff + (quad << 2);
  const int c0 = n0 + noff + q15;
#pragma unroll
  for (int j = 0; j < 4; ++j) {
    int col = c0 + j * 16;
    float bias = ob[col];
#pragma unroll
    for (int i = 0; i < 2; ++i)
#pragma unroll
      for (int r = 0; r < 4; ++r)
        out[(size_t)(rr0 + i * 16 + r) * 1024 + col] = acc[i][j][r] + bias;
  }
}

// ---------------- launcher ----------------
extern "C" void kernel_launch(void* const* d_in, const int* in_sizes, int n_in,
                              void* d_out, int out_size, void* d_ws, size_t ws_size,
                              hipStream_t stream) {
  const float* query = (const float*)d_in[0];
  const float* q_w = (const float*)d_in[1];
  const float* q_b = (const float*)d_in[2];
  const float* k_w = (const float*)d_in[3];
  const float* k_b = (const float*)d_in[4];
  const float* v_w = (const float*)d_in[5];
  const float* v_b = (const float*)d_in[6];
  const float* out_w = (const float*)d_in[7];
  const float* out_b = (const float*)d_in[8];
  const float* rel_emb = (const float*)d_in[9];
  const float* grep_w = (const float*)d_in[10];
  const float* grep_b = (const float*)d_in[11];
  const float* grep_a = (const float*)d_in[12];
  float* out = (float*)d_out;

  const size_t MB = 1u << 20;
  char* ws = (char*)d_ws;
  unsigned short* q_bf = (unsigned short*)(ws);            // (B,S,E) bf16, 8 MB
  unsigned short* wq_bf = (unsigned short*)(ws + 8 * MB);
  unsigned short* wk_bf = (unsigned short*)(ws + 10 * MB);
  unsigned short* wv_bf = (unsigned short*)(ws + 12 * MB);
  unsigned short* ow_h = (unsigned short*)(ws + 14 * MB);  // f16
  unsigned short* qhp = (unsigned short*)(ws + 16 * MB);   // (B,H,S,D)
  unsigned short* khp = (unsigned short*)(ws + 24 * MB);   // (B,H,S,D)
  unsigned short* vTp = (unsigned short*)(ws + 32 * MB);   // (B,H,D,S)
  unsigned short* ctxp = (unsigned short*)(ws + 40 * MB);  // (S*B,E) f16
  float* gatep = (float*)(ws + 48 * MB);
  unsigned short* biasp = (unsigned short*)(ws + 48 * MB + 256 * 1024);  // bf16 16x2056

  prep_kernel<<<20489, 256, 0, stream>>>(query, q_w, k_w, v_w, out_w, rel_emb, q_bf, wq_bf,
                                         wk_bf, wv_bf, ow_h, biasp);
  qkv_gemm_kernel<<<dim3(24, 32), 256, 0, stream>>>(q_bf, wq_bf, wk_bf, wv_bf, q_b, k_b, v_b,
                                                    qhp, khp, vTp);
  gate_kernel<<<256, 256, 0, stream>>>(qhp, grep_w, grep_b, grep_a, gatep);
  attn_kernel<<<dim3(64, 8), 512, 0, stream>>>(qhp, khp, vTp, gatep, biasp, ctxp);
  outproj_kernel<<<dim3(8, 64), 256, 0, stream>>>(ctxp, ow_h, out_b, out);
}